// Round 2
// baseline (3449.616 us; speedup 1.0000x reference)
//
#include <hip/hip_runtime.h>
#include <hip/hip_fp16.h>
#include <math.h>

#define HW 65536            // 256*256
#define CHW 4194304         // 64*HW
#define BCHW 16777216       // 4*CHW
#define HW2 262144          // 512*512

__device__ __forceinline__ float ldf(const float* p) { return *p; }
__device__ __forceinline__ float ldf(const __half* p) { return __half2float(*p); }

// ---------------------------------------------------------------- ternarize
struct TernDesc { const float* src; float* dst; int n; };
struct TernArgs { TernDesc d[21]; };

__global__ __launch_bounds__(256) void ternarize_kernel(TernArgs args) {
    __shared__ float red[256];
    __shared__ float bc[2];
    TernDesc td = args.d[blockIdx.x];
    const int n = td.n;
    const int t = threadIdx.x;
    float s = 0.f;
    for (int i = t; i < n; i += 256) s += fabsf(td.src[i]);
    red[t] = s; __syncthreads();
    for (int k = 128; k > 0; k >>= 1) { if (t < k) red[t] += red[t + k]; __syncthreads(); }
    if (t == 0) bc[0] = 0.75f * red[0] / (float)n;
    __syncthreads();
    const float delta = bc[0];
    float s1 = 0.f, c1 = 0.f;
    for (int i = t; i < n; i += 256) {
        float a = fabsf(td.src[i]);
        if (a > delta) { s1 += a; c1 += 1.f; }
    }
    __syncthreads();
    red[t] = s1; __syncthreads();
    for (int k = 128; k > 0; k >>= 1) { if (t < k) red[t] += red[t + k]; __syncthreads(); }
    float sum1 = red[0];
    __syncthreads();
    red[t] = c1; __syncthreads();
    for (int k = 128; k > 0; k >>= 1) { if (t < k) red[t] += red[t + k]; __syncthreads(); }
    if (t == 0) bc[1] = sum1 / fmaxf(red[0], 1.f);
    __syncthreads();
    const float alpha = bc[1];
    for (int i = t; i < n; i += 256) {
        float w = td.src[i];
        td.dst[i] = (fabsf(w) > delta) ? ((w > 0.f) ? alpha : -alpha) : 0.f;
    }
}

// ---------------------------------------------------------------- shallow 3x3 conv (3->64) + relu (fp32 out)
__global__ __launch_bounds__(256) void shallow_kernel(const float* __restrict__ x,
                                                      const float* __restrict__ qw,
                                                      const float* __restrict__ bias,
                                                      float* __restrict__ feat) {
    __shared__ float wsm[1728];
    __shared__ float bsm[64];
    const int t = threadIdx.y * 16 + threadIdx.x;
    for (int i = t; i < 1728; i += 256) wsm[i] = qw[i];
    if (t < 64) bsm[t] = bias[t];
    __syncthreads();
    const int b = blockIdx.z;
    const int h = blockIdx.y * 16 + threadIdx.y;
    const int w = blockIdx.x * 16 + threadIdx.x;
    const float* xb = x + (size_t)b * 3 * HW;
    float patch[27];
#pragma unroll
    for (int ci = 0; ci < 3; ci++)
#pragma unroll
        for (int dy = 0; dy < 3; dy++)
#pragma unroll
            for (int dx = 0; dx < 3; dx++) {
                int hh = h + dy - 1, ww = w + dx - 1;
                patch[ci * 9 + dy * 3 + dx] =
                    (hh >= 0 && hh < 256 && ww >= 0 && ww < 256) ? xb[ci * HW + hh * 256 + ww] : 0.f;
            }
    float* fb = feat + (size_t)b * CHW + h * 256 + w;
    for (int co = 0; co < 64; co++) {
        const float* wp = &wsm[co * 27];
        float acc = bsm[co];
#pragma unroll
        for (int k = 0; k < 27; k++) acc = fmaf(patch[k], wp[k], acc);
        fb[(size_t)co * HW] = fmaxf(acc, 0.f);
    }
}

// ---------------------------------------------------------------- texture state + router + argmax (fp32 feat)
__global__ __launch_bounds__(256) void router_kernel(const float* __restrict__ feat,
                                                     const float* __restrict__ qdw,
                                                     const float* __restrict__ dwb,
                                                     const float* __restrict__ qpw,
                                                     const float* __restrict__ pwbias,
                                                     const float* __restrict__ rw,
                                                     const float* __restrict__ rbias,
                                                     int* __restrict__ top) {
    __shared__ float tile[324];
    __shared__ float wdw[576];
    __shared__ float bdw[64];
    __shared__ float wpw[512];
    __shared__ float bpw[8];
    __shared__ float wr[32];
    __shared__ float br[4];
    const int t = threadIdx.y * 16 + threadIdx.x;
    for (int i = t; i < 576; i += 256) wdw[i] = qdw[i];
    for (int i = t; i < 512; i += 256) wpw[i] = qpw[i];
    if (t < 64) bdw[t] = dwb[t];
    if (t < 8) bpw[t] = pwbias[t];
    if (t < 32) wr[t] = rw[t];
    if (t < 4) br[t] = rbias[t];
    const int b = blockIdx.z;
    const int h0 = blockIdx.y * 16, w0 = blockIdx.x * 16;
    const float* fb = feat + (size_t)b * CHW;
    float tex[8] = {0, 0, 0, 0, 0, 0, 0, 0};
    for (int c = 0; c < 64; c++) {
        __syncthreads();
        for (int i = t; i < 324; i += 256) {
            int ty = i / 18, tx = i - ty * 18;
            int hh = h0 + ty - 1, ww = w0 + tx - 1;
            tile[i] = (hh >= 0 && hh < 256 && ww >= 0 && ww < 256) ? fb[(size_t)c * HW + hh * 256 + ww] : 0.f;
        }
        __syncthreads();
        const float* wp = &wdw[c * 9];
        const float* tl = &tile[threadIdx.y * 18 + threadIdx.x];
        float a = bdw[c];
        a = fmaf(tl[0],  wp[0], a); a = fmaf(tl[1],  wp[1], a); a = fmaf(tl[2],  wp[2], a);
        a = fmaf(tl[18], wp[3], a); a = fmaf(tl[19], wp[4], a); a = fmaf(tl[20], wp[5], a);
        a = fmaf(tl[36], wp[6], a); a = fmaf(tl[37], wp[7], a); a = fmaf(tl[38], wp[8], a);
        const float tc = fmaxf(a, 0.f);
#pragma unroll
        for (int j = 0; j < 8; j++) tex[j] = fmaf(wpw[j * 64 + c], tc, tex[j]);
    }
    float tj[8];
#pragma unroll
    for (int j = 0; j < 8; j++) tj[j] = 1.f / (1.f + expf(-(tex[j] + bpw[j])));
    float best = -1e30f; int bi = 0;
    for (int e = 0; e < 4; e++) {
        float l = br[e];
#pragma unroll
        for (int j = 0; j < 8; j++) l = fmaf(wr[e * 8 + j], tj[j], l);
        if (l > best) { best = l; bi = e; }   // first max (jnp.argmax)
    }
    top[(size_t)b * HW + (h0 + threadIdx.y) * 256 + (w0 + threadIdx.x)] = bi;
}

// ---------------------------------------------------------------- fused depthwise3x3+relu + pointwise 64x64 (+channel sums)
template <typename TIN>
__global__ __launch_bounds__(256) void expert_block_kernel(const TIN* __restrict__ in,
                                                           const float* __restrict__ qdw,
                                                           const float* __restrict__ dwb,
                                                           const float* __restrict__ qpw,
                                                           const float* __restrict__ pwb,
                                                           __half* __restrict__ out,
                                                           float* __restrict__ chansum) {
    __shared__ float tile[6400];                 // [c][10][10]
    __shared__ __align__(16) float tmp[4096];    // [ci][p]  (p = 8x8 pixel)
    __shared__ float wT[4160];                   // transposed pw weights, stride 65
    __shared__ float wdw[576];
    __shared__ float bdw[64];
    __shared__ float bpw[64];
    const int t = threadIdx.x;
    const int b = blockIdx.z;
    const int h0 = blockIdx.y * 8, w0 = blockIdx.x * 8;

    for (int i = t; i < 576; i += 256) wdw[i] = qdw[i];
    if (t < 64) { bdw[t] = dwb[t]; bpw[t] = pwb[t]; }
    for (int i = t; i < 4096; i += 256) wT[(i & 63) * 65 + (i >> 6)] = qpw[i];

    const TIN* ib = in + (size_t)b * CHW;
    for (int i = t; i < 6400; i += 256) {
        int c = i / 100, r = i - c * 100;
        int ty = r / 10, tx = r - ty * 10;
        int hh = h0 + ty - 1, ww = w0 + tx - 1;
        tile[i] = (hh >= 0 && hh < 256 && ww >= 0 && ww < 256) ? ldf(&ib[(size_t)c * HW + hh * 256 + ww]) : 0.f;
    }
    __syncthreads();

    {   // depthwise: thread -> pixel p=t&63, channel chunk (t>>6)*16
        const int p = t & 63, py = p >> 3, px = p & 7;
        const int cb = (t >> 6) << 4;
#pragma unroll
        for (int k = 0; k < 16; k++) {
            const int c = cb + k;
            const float* tl = &tile[c * 100 + py * 10 + px];
            const float* wp = &wdw[c * 9];
            float a = bdw[c];
            a = fmaf(tl[0],  wp[0], a); a = fmaf(tl[1],  wp[1], a); a = fmaf(tl[2],  wp[2], a);
            a = fmaf(tl[10], wp[3], a); a = fmaf(tl[11], wp[4], a); a = fmaf(tl[12], wp[5], a);
            a = fmaf(tl[20], wp[6], a); a = fmaf(tl[21], wp[7], a); a = fmaf(tl[22], wp[8], a);
            tmp[c * 64 + p] = fmaxf(a, 0.f);
        }
    }
    __syncthreads();

    // pointwise: thread -> pixels {4pg..4pg+3}, couts {4cg..4cg+3}
    const int pg = t & 15, cg = t >> 4;
    const int co0 = cg * 4;
    float acc[4][4];
#pragma unroll
    for (int k = 0; k < 4; k++) {
        const float bv = bpw[co0 + k];
#pragma unroll
        for (int j = 0; j < 4; j++) acc[k][j] = bv;
    }
#pragma unroll 8
    for (int ci = 0; ci < 64; ci++) {
        const float4 tv = *(const float4*)&tmp[ci * 64 + pg * 4];
        const float* wrow = &wT[ci * 65 + co0];
        const float wv0 = wrow[0], wv1 = wrow[1], wv2 = wrow[2], wv3 = wrow[3];
        acc[0][0] = fmaf(wv0, tv.x, acc[0][0]); acc[0][1] = fmaf(wv0, tv.y, acc[0][1]);
        acc[0][2] = fmaf(wv0, tv.z, acc[0][2]); acc[0][3] = fmaf(wv0, tv.w, acc[0][3]);
        acc[1][0] = fmaf(wv1, tv.x, acc[1][0]); acc[1][1] = fmaf(wv1, tv.y, acc[1][1]);
        acc[1][2] = fmaf(wv1, tv.z, acc[1][2]); acc[1][3] = fmaf(wv1, tv.w, acc[1][3]);
        acc[2][0] = fmaf(wv2, tv.x, acc[2][0]); acc[2][1] = fmaf(wv2, tv.y, acc[2][1]);
        acc[2][2] = fmaf(wv2, tv.z, acc[2][2]); acc[2][3] = fmaf(wv2, tv.w, acc[2][3]);
        acc[3][0] = fmaf(wv3, tv.x, acc[3][0]); acc[3][1] = fmaf(wv3, tv.y, acc[3][1]);
        acc[3][2] = fmaf(wv3, tv.z, acc[3][2]); acc[3][3] = fmaf(wv3, tv.w, acc[3][3]);
    }
    const int py0 = pg >> 1, px0 = (pg & 1) * 4;
    __half* orow = out + (size_t)b * CHW + (h0 + py0) * 256 + (w0 + px0);
#pragma unroll
    for (int k = 0; k < 4; k++) {
        const int co = co0 + k;
        union { ushort4 u4; __half h[4]; } pk;
        pk.h[0] = __float2half(acc[k][0]); pk.h[1] = __float2half(acc[k][1]);
        pk.h[2] = __float2half(acc[k][2]); pk.h[3] = __float2half(acc[k][3]);
        *(ushort4*)&orow[(size_t)co * HW] = pk.u4;
        float csum = acc[k][0] + acc[k][1] + acc[k][2] + acc[k][3];
        csum += __shfl_down(csum, 8, 16);
        csum += __shfl_down(csum, 4, 16);
        csum += __shfl_down(csum, 2, 16);
        csum += __shfl_down(csum, 1, 16);
        if (pg == 0) atomicAdd(&chansum[b * 64 + co], csum);
    }
}

// ---------------------------------------------------------------- channel attention (tiny)
__global__ __launch_bounds__(256) void attention_kernel(const float* __restrict__ chansum,
                                                        const float* __restrict__ fc1,
                                                        const float* __restrict__ fc2,
                                                        float* __restrict__ y) {
    __shared__ float mean_s[256];
    __shared__ float hid[64];
    const int t = threadIdx.x;
    const int b = t >> 6, c = t & 63;
    mean_s[t] = chansum[t] * (1.f / 65536.f);
    __syncthreads();
    if (t < 64) {
        const int b2 = t >> 4, j = t & 15;
        float a = 0.f;
        for (int ci = 0; ci < 64; ci++) a = fmaf(fc1[j * 64 + ci], mean_s[b2 * 64 + ci], a);
        hid[t] = fmaxf(a, 0.f);
    }
    __syncthreads();
    float a = 0.f;
#pragma unroll
    for (int j = 0; j < 16; j++) a = fmaf(fc2[c * 16 + j], hid[b * 16 + j], a);
    y[t] = 1.f / (1.f + expf(-a));
}

// ---------------------------------------------------------------- A = A*y + feat  (in-place, half A, fp32 feat)
__global__ __launch_bounds__(256) void apply_kernel(__half* __restrict__ A,
                                                    const float* __restrict__ yv,
                                                    const float* __restrict__ F) {
    const int i8 = blockIdx.x * 256 + threadIdx.x;   // 8-half chunk index, exact grid
    const int ei = i8 << 3;
    const float y = yv[ei >> 16];                    // b*64+c
    float4 av = ((const float4*)A)[i8];
    const __half2* ah = (const __half2*)&av;
    const float4 f0 = ((const float4*)F)[i8 * 2];
    const float4 f1 = ((const float4*)F)[i8 * 2 + 1];
    const float fo[8] = {f0.x, f0.y, f0.z, f0.w, f1.x, f1.y, f1.z, f1.w};
    __half2 outv[4];
#pragma unroll
    for (int j = 0; j < 4; j++) {
        const float2 a2 = __half22float2(ah[j]);
        outv[j] = __floats2half2_rn(fmaf(a2.x, y, fo[2 * j]), fmaf(a2.y, y, fo[2 * j + 1]));
    }
    ((float4*)A)[i8] = *(float4*)outv;
}

// ---------------------------------------------------------------- routed select: M = B*y + A where top==e
__global__ __launch_bounds__(256) void select_kernel(const __half* __restrict__ Bv,
                                                     const float* __restrict__ yv,
                                                     const __half* __restrict__ A,
                                                     const int* __restrict__ top,
                                                     __half* __restrict__ M, int e) {
    const int i8 = blockIdx.x * 256 + threadIdx.x;   // 8-half chunk, exact grid
    const int ei = i8 << 3;
    const int bc = ei >> 16;
    const int b = bc >> 6;
    const int hw = ei & (HW - 1);
    const int* tp = top + (size_t)b * HW + hw;
    const int4 t0 = ((const int4*)tp)[0];
    const int4 t1 = ((const int4*)tp)[1];
    const int tt[8] = {t0.x, t0.y, t0.z, t0.w, t1.x, t1.y, t1.z, t1.w};
    bool any = false;
#pragma unroll
    for (int j = 0; j < 8; j++) any |= (tt[j] == e);
    if (!any) return;
    const float y = yv[bc];
    float4 bv4 = ((const float4*)Bv)[i8];
    float4 av4 = ((const float4*)A)[i8];
    const __half2* bh = (const __half2*)&bv4;
    const __half2* ah = (const __half2*)&av4;
#pragma unroll
    for (int j = 0; j < 4; j++) {
        const float2 b2 = __half22float2(bh[j]);
        const float2 a2 = __half22float2(ah[j]);
        if (tt[2 * j]     == e) M[ei + 2 * j]     = __float2half(fmaf(b2.x, y, a2.x));
        if (tt[2 * j + 1] == e) M[ei + 2 * j + 1] = __float2half(fmaf(b2.y, y, a2.y));
    }
}

// ---------------------------------------------------------------- bilinear x2 upsample (jax.image.resize semantics)
__device__ __forceinline__ float bilin_up(const float* __restrict__ xb, int h, int w, int r1, int r2) {
    int hlo, hhi; float wrr;
    if (r1 == 0) { hlo = h - 1; hhi = h;     wrr = 0.25f; }
    else         { hlo = h;     hhi = h + 1; wrr = 0.75f; }
    if (hlo < 0)   { hlo = 0;   wrr = 0.f; }
    if (hhi > 255) { hhi = 255; wrr = 1.f; }
    int wlo, whi; float wcc;
    if (r2 == 0) { wlo = w - 1; whi = w;     wcc = 0.25f; }
    else         { wlo = w;     whi = w + 1; wcc = 0.75f; }
    if (wlo < 0)   { wlo = 0;   wcc = 0.f; }
    if (whi > 255) { whi = 255; wcc = 1.f; }
    const float a = xb[hlo * 256 + wlo] * wcc + xb[hlo * 256 + whi] * (1.f - wcc);
    const float b = xb[hhi * 256 + wlo] * wcc + xb[hhi * 256 + whi] * (1.f - wcc);
    return a * wrr + b * (1.f - wrr);
}

// ---------------------------------------------------------------- recon 3x3 (64->12) + pixel shuffle + x_up add
__global__ __launch_bounds__(256) void recon_kernel(const __half* __restrict__ moe,
                                                    const float* __restrict__ rw,
                                                    const float* __restrict__ rbias,
                                                    const float* __restrict__ x,
                                                    float* __restrict__ sr) {
    __shared__ float tile[324];
    __shared__ float wsm[6912];
    __shared__ float bsm[12];
    const int t = threadIdx.y * 16 + threadIdx.x;
    for (int i = t; i < 6912; i += 256) wsm[i] = rw[i];
    if (t < 12) bsm[t] = rbias[t];
    const int b = blockIdx.z;
    const int h0 = blockIdx.y * 16, w0 = blockIdx.x * 16;
    const int h = h0 + threadIdx.y, w = w0 + threadIdx.x;
    const __half* mb = moe + (size_t)b * CHW;
    float acc[12];
#pragma unroll
    for (int o = 0; o < 12; o++) acc[o] = 0.f;
    for (int ci = 0; ci < 64; ci++) {
        __syncthreads();
        for (int i = t; i < 324; i += 256) {
            int ty = i / 18, tx = i - ty * 18;
            int hh = h0 + ty - 1, ww = w0 + tx - 1;
            tile[i] = (hh >= 0 && hh < 256 && ww >= 0 && ww < 256)
                        ? __half2float(mb[(size_t)ci * HW + hh * 256 + ww]) : 0.f;
        }
        __syncthreads();
        float tp[9];
#pragma unroll
        for (int dy = 0; dy < 3; dy++)
#pragma unroll
            for (int dx = 0; dx < 3; dx++)
                tp[dy * 3 + dx] = tile[(threadIdx.y + dy) * 18 + threadIdx.x + dx];
        const float* wc = &wsm[ci * 9];
#pragma unroll
        for (int o = 0; o < 12; o++) {
            const float* wo = wc + o * 576;
            float a = acc[o];
#pragma unroll
            for (int k = 0; k < 9; k++) a = fmaf(tp[k], wo[k], a);
            acc[o] = a;
        }
    }
#pragma unroll
    for (int o = 0; o < 12; o++) {
        const int c = o >> 2, r1 = (o >> 1) & 1, r2 = o & 1;
        const float* xb = x + ((size_t)b * 3 + c) * HW;
        const float xu = bilin_up(xb, h, w, r1, r2);
        const int i2 = 2 * h + r1, j2 = 2 * w + r2;
        sr[((size_t)b * 3 + c) * HW2 + i2 * 512 + j2] = acc[o] + bsm[o] + xu;
    }
}

// ---------------------------------------------------------------- 3x3 conv on [4][3][512][512] (refinement)
__global__ __launch_bounds__(256) void ref_conv_kernel(const float* __restrict__ in,
                                                       const float* __restrict__ qw,
                                                       const float* __restrict__ bb,
                                                       const float* __restrict__ addsrc,
                                                       float* __restrict__ outp,
                                                       int do_relu) {
    __shared__ float tile[324];
    __shared__ float wsm[81];
    __shared__ float bsm[3];
    const int t = threadIdx.y * 16 + threadIdx.x;
    if (t < 81) wsm[t] = qw[t];
    if (t < 3) bsm[t] = bb[t];
    const int b = blockIdx.z;
    const int h0 = blockIdx.y * 16, w0 = blockIdx.x * 16;
    const int h = h0 + threadIdx.y, w = w0 + threadIdx.x;
    float acc[3] = {0.f, 0.f, 0.f};
    for (int ci = 0; ci < 3; ci++) {
        __syncthreads();
        const float* ibp = in + ((size_t)b * 3 + ci) * HW2;
        for (int i = t; i < 324; i += 256) {
            int ty = i / 18, tx = i - ty * 18;
            int hh = h0 + ty - 1, ww = w0 + tx - 1;
            tile[i] = (hh >= 0 && hh < 512 && ww >= 0 && ww < 512) ? ibp[hh * 512 + ww] : 0.f;
        }
        __syncthreads();
        float tp[9];
#pragma unroll
        for (int dy = 0; dy < 3; dy++)
#pragma unroll
            for (int dx = 0; dx < 3; dx++)
                tp[dy * 3 + dx] = tile[(threadIdx.y + dy) * 18 + threadIdx.x + dx];
#pragma unroll
        for (int o = 0; o < 3; o++) {
            const float* wo = &wsm[o * 27 + ci * 9];
            float a = acc[o];
#pragma unroll
            for (int k = 0; k < 9; k++) a = fmaf(tp[k], wo[k], a);
            acc[o] = a;
        }
    }
#pragma unroll
    for (int o = 0; o < 3; o++) {
        float v = acc[o] + bsm[o];
        if (do_relu) v = fmaxf(v, 0.f);
        if (addsrc) v += addsrc[((size_t)b * 3 + o) * HW2 + h * 512 + w];
        outp[((size_t)b * 3 + o) * HW2 + h * 512 + w] = v;
    }
}

// ---------------------------------------------------------------- launcher
extern "C" void kernel_launch(void* const* d_in, const int* in_sizes, int n_in,
                              void* d_out, int out_size, void* d_ws, size_t ws_size,
                              hipStream_t stream) {
    const float* x         = (const float*)d_in[0];
    const float* shallow_w = (const float*)d_in[1];
    const float* shallow_b = (const float*)d_in[2];
    const float* tex_dw_w  = (const float*)d_in[3];
    const float* tex_dw_b  = (const float*)d_in[4];
    const float* tex_pw_w  = (const float*)d_in[5];
    const float* tex_pw_b  = (const float*)d_in[6];
    const float* router_w  = (const float*)d_in[7];
    const float* router_b  = (const float*)d_in[8];
    const float* exp_dw_w  = (const float*)d_in[9];
    const float* exp_dw_b  = (const float*)d_in[10];
    const float* exp_pw_w  = (const float*)d_in[11];
    const float* exp_pw_b  = (const float*)d_in[12];
    const float* exp_fc1   = (const float*)d_in[13];
    const float* exp_fc2   = (const float*)d_in[14];
    const float* recon_w   = (const float*)d_in[15];
    const float* recon_b   = (const float*)d_in[16];
    const float* ref1_w    = (const float*)d_in[17];
    const float* ref1_b    = (const float*)d_in[18];
    const float* ref2_w    = (const float*)d_in[19];
    const float* ref2_b    = (const float*)d_in[20];

    // workspace layout (~185 MB total)
    float*  feat = (float*)d_ws;                        // BCHW fp32 (64 MB)
    __half* A    = (__half*)(feat + BCHW);              // BCHW half (32 MB)
    __half* Bv   = A + BCHW;                            // BCHW half (32 MB)
    __half* M    = Bv + BCHW;                           // BCHW half (32 MB)
    float*  sr   = (float*)(M + BCHW);                  // 3145728 fp32 (12 MB)
    float*  t1   = sr + 3145728;                        // 3145728 fp32 (12 MB)
    int*    top  = (int*)(t1 + 3145728);                // 262144 int (1 MB)
    float*  qb    = (float*)(top + 262144);
    float*  q_sh  = qb;                 // 1728
    float*  q_tdw = q_sh + 1728;        // 576
    float*  q_tpw = q_tdw + 576;        // 512
    float*  q_edw = q_tpw + 512;        // 8*576
    float*  q_epw = q_edw + 4608;       // 8*4096
    float*  q_r1  = q_epw + 32768;      // 81
    float*  q_r2  = q_r1 + 81;          // 81
    float*  chans = q_r2 + 81;          // 8*256
    float*  yatt  = chans + 2048;       // 8*256

    hipMemsetAsync(chans, 0, 2048 * sizeof(float), stream);

    TernArgs ta;
    ta.d[0] = { shallow_w, q_sh, 1728 };
    ta.d[1] = { tex_dw_w, q_tdw, 576 };
    ta.d[2] = { tex_pw_w, q_tpw, 512 };
    for (int i = 0; i < 8; i++) ta.d[3 + i]  = { exp_dw_w + i * 576,  q_edw + i * 576,  576 };
    for (int i = 0; i < 8; i++) ta.d[11 + i] = { exp_pw_w + i * 4096, q_epw + i * 4096, 4096 };
    ta.d[19] = { ref1_w, q_r1, 81 };
    ta.d[20] = { ref2_w, q_r2, 81 };
    ternarize_kernel<<<21, 256, 0, stream>>>(ta);

    shallow_kernel<<<dim3(16, 16, 4), dim3(16, 16), 0, stream>>>(x, q_sh, shallow_b, feat);
    router_kernel<<<dim3(16, 16, 4), dim3(16, 16), 0, stream>>>(
        feat, q_tdw, tex_dw_b, q_tpw, tex_pw_b, router_w, router_b, top);

    for (int e = 0; e < 4; e++) {
        const int i0 = e * 2, i1 = e * 2 + 1;
        expert_block_kernel<float><<<dim3(32, 32, 4), 256, 0, stream>>>(
            feat, q_edw + i0 * 576, exp_dw_b + i0 * 64, q_epw + i0 * 4096, exp_pw_b + i0 * 64,
            A, chans + i0 * 256);
        attention_kernel<<<1, 256, 0, stream>>>(chans + i0 * 256, exp_fc1 + i0 * 1024,
                                                exp_fc2 + i0 * 1024, yatt + i0 * 256);
        apply_kernel<<<8192, 256, 0, stream>>>(A, yatt + i0 * 256, feat);
        expert_block_kernel<__half><<<dim3(32, 32, 4), 256, 0, stream>>>(
            A, q_edw + i1 * 576, exp_dw_b + i1 * 64, q_epw + i1 * 4096, exp_pw_b + i1 * 64,
            Bv, chans + i1 * 256);
        attention_kernel<<<1, 256, 0, stream>>>(chans + i1 * 256, exp_fc1 + i1 * 1024,
                                                exp_fc2 + i1 * 1024, yatt + i1 * 256);
        select_kernel<<<8192, 256, 0, stream>>>(Bv, yatt + i1 * 256, A, top, M, e);
    }

    recon_kernel<<<dim3(16, 16, 4), dim3(16, 16), 0, stream>>>(M, recon_w, recon_b, x, sr);
    ref_conv_kernel<<<dim3(32, 32, 4), dim3(16, 16), 0, stream>>>(sr, q_r1, ref1_b, nullptr, t1, 1);
    ref_conv_kernel<<<dim3(32, 32, 4), dim3(16, 16), 0, stream>>>(t1, q_r2, ref2_b, sr, (float*)d_out, 0);
}

// Round 3
// 2083.340 us; speedup vs baseline: 1.6558x; 1.6558x over previous
//
#include <hip/hip_runtime.h>
#include <hip/hip_fp16.h>
#include <math.h>

#define HW 65536            // 256*256
#define CHW 4194304         // 64*HW
#define BCHW 16777216       // 4*CHW
#define HW2 262144          // 512*512

// ---------------------------------------------------------------- ternarize
struct TernDesc { const float* src; float* dst; int n; };
struct TernArgs { TernDesc d[21]; };

__global__ __launch_bounds__(256) void ternarize_kernel(TernArgs args) {
    __shared__ float red[256];
    __shared__ float bc[2];
    TernDesc td = args.d[blockIdx.x];
    const int n = td.n;
    const int t = threadIdx.x;
    float s = 0.f;
    for (int i = t; i < n; i += 256) s += fabsf(td.src[i]);
    red[t] = s; __syncthreads();
    for (int k = 128; k > 0; k >>= 1) { if (t < k) red[t] += red[t + k]; __syncthreads(); }
    if (t == 0) bc[0] = 0.75f * red[0] / (float)n;
    __syncthreads();
    const float delta = bc[0];
    float s1 = 0.f, c1 = 0.f;
    for (int i = t; i < n; i += 256) {
        float a = fabsf(td.src[i]);
        if (a > delta) { s1 += a; c1 += 1.f; }
    }
    __syncthreads();
    red[t] = s1; __syncthreads();
    for (int k = 128; k > 0; k >>= 1) { if (t < k) red[t] += red[t + k]; __syncthreads(); }
    float sum1 = red[0];
    __syncthreads();
    red[t] = c1; __syncthreads();
    for (int k = 128; k > 0; k >>= 1) { if (t < k) red[t] += red[t + k]; __syncthreads(); }
    if (t == 0) bc[1] = sum1 / fmaxf(red[0], 1.f);
    __syncthreads();
    const float alpha = bc[1];
    for (int i = t; i < n; i += 256) {
        float w = td.src[i];
        td.dst[i] = (fabsf(w) > delta) ? ((w > 0.f) ? alpha : -alpha) : 0.f;
    }
}

// ---------------------------------------------------------------- shallow 3x3 conv (3->64) + relu, writes fp32 + half
__global__ __launch_bounds__(256) void shallow_kernel(const float* __restrict__ x,
                                                      const float* __restrict__ qw,
                                                      const float* __restrict__ bias,
                                                      float* __restrict__ feat,
                                                      __half* __restrict__ feat_h) {
    __shared__ float wsm[1728];
    __shared__ float bsm[64];
    const int t = threadIdx.y * 16 + threadIdx.x;
    for (int i = t; i < 1728; i += 256) wsm[i] = qw[i];
    if (t < 64) bsm[t] = bias[t];
    __syncthreads();
    const int b = blockIdx.z;
    const int h = blockIdx.y * 16 + threadIdx.y;
    const int w = blockIdx.x * 16 + threadIdx.x;
    const float* xb = x + (size_t)b * 3 * HW;
    float patch[27];
#pragma unroll
    for (int ci = 0; ci < 3; ci++)
#pragma unroll
        for (int dy = 0; dy < 3; dy++)
#pragma unroll
            for (int dx = 0; dx < 3; dx++) {
                int hh = h + dy - 1, ww = w + dx - 1;
                patch[ci * 9 + dy * 3 + dx] =
                    (hh >= 0 && hh < 256 && ww >= 0 && ww < 256) ? xb[ci * HW + hh * 256 + ww] : 0.f;
            }
    float* fb = feat + (size_t)b * CHW + h * 256 + w;
    __half* fhb = feat_h + (size_t)b * CHW + h * 256 + w;
    for (int co = 0; co < 64; co++) {
        const float* wp = &wsm[co * 27];
        float acc = bsm[co];
#pragma unroll
        for (int k = 0; k < 27; k++) acc = fmaf(patch[k], wp[k], acc);
        acc = fmaxf(acc, 0.f);
        fb[(size_t)co * HW] = acc;
        fhb[(size_t)co * HW] = __float2half(acc);
    }
}

// ---------------------------------------------------------------- router: texture state + router conv + argmax
// 16 wide x 8 tall px tile; 2-pass channel staging; fp32 throughout.
__global__ __launch_bounds__(256) void router_kernel(const float* __restrict__ feat,
                                                     const float* __restrict__ qdw,
                                                     const float* __restrict__ dwb,
                                                     const float* __restrict__ qpw,
                                                     const float* __restrict__ pwbias,
                                                     const float* __restrict__ rw,
                                                     const float* __restrict__ rbias,
                                                     int* __restrict__ top) {
    __shared__ float tile[32 * 10 * 20];   // 25600 B, [cl][ry][20]
    __shared__ float tmp[32 * 128];        // 16384 B, [cl][px]
    __shared__ float texbuf[128 * 9];      // 4608 B (stride 9 vs bank conflicts)
    __shared__ float wdw[576];
    __shared__ float wpw[512];
    __shared__ float bdw[64];
    __shared__ float bpw8[8];
    __shared__ float wr[32];
    __shared__ float br[4];
    const int t = threadIdx.x;
    const int b = blockIdx.z;
    const int h0 = blockIdx.y * 8, w0 = blockIdx.x * 16;

    for (int i = t; i < 576; i += 256) wdw[i] = qdw[i];
    for (int i = t; i < 512; i += 256) wpw[i] = qpw[i];
    if (t < 64) bdw[t] = dwb[t];
    if (t < 8) bpw8[t] = pwbias[t];
    if (t < 32) wr[t] = rw[t];
    if (t < 4) br[t] = rbias[t];

    const float* fb = feat + (size_t)b * CHW;
    const int pxg = t & 31, og = t >> 5;   // 32 px-groups x 8 outs
    float acc[4] = {0.f, 0.f, 0.f, 0.f};

    for (int pass = 0; pass < 2; pass++) {
        const int c0 = pass * 32;
        __syncthreads();
        // stage 32 channels, rows h0-1..h0+8, cols w0-2..w0+17
        for (int i = t; i < 6400; i += 256) {
            const int c = i / 200, rem = i - c * 200;
            const int ry = rem / 20, rx = rem - ry * 20;
            const int hh = h0 + ry - 1, ww = w0 + rx - 2;
            tile[i] = (hh >= 0 && hh < 256 && ww >= 0 && ww < 256)
                        ? fb[(size_t)(c0 + c) * HW + hh * 256 + ww] : 0.f;
        }
        __syncthreads();
        // depthwise row-tasks: 32ch x 8rows x 2halves
        for (int k = t; k < 512; k += 256) {
            const int cl = k >> 4, r = (k >> 1) & 7, hf = k & 1;
            const float* wp = &wdw[(c0 + cl) * 9];
            float o[8];
            const float bv = bdw[c0 + cl];
#pragma unroll
            for (int j = 0; j < 8; j++) o[j] = bv;
#pragma unroll
            for (int dy = 0; dy < 3; dy++) {
                const float* rowp = &tile[cl * 200 + (r + dy) * 20 + 8 * hf];
                float f[12];
#pragma unroll
                for (int q = 0; q < 3; q++) {
                    float4 v = *(const float4*)&rowp[q * 4];
                    f[q * 4] = v.x; f[q * 4 + 1] = v.y; f[q * 4 + 2] = v.z; f[q * 4 + 3] = v.w;
                }
                const float wa = wp[dy * 3], wb = wp[dy * 3 + 1], wc = wp[dy * 3 + 2];
#pragma unroll
                for (int j = 0; j < 8; j++)
                    o[j] = fmaf(f[j + 1], wa, fmaf(f[j + 2], wb, fmaf(f[j + 3], wc, o[j])));
            }
            float* tp = &tmp[cl * 128 + r * 16 + hf * 8];
#pragma unroll
            for (int j = 0; j < 8; j++) tp[j] = fmaxf(o[j], 0.f);
        }
        __syncthreads();
        // pointwise partial: out og (8 dims), 4 px per thread
        for (int ci = 0; ci < 32; ci++) {
            const float4 tv = *(const float4*)&tmp[ci * 128 + pxg * 4];
            const float wv = wpw[og * 64 + c0 + ci];
            acc[0] = fmaf(wv, tv.x, acc[0]); acc[1] = fmaf(wv, tv.y, acc[1]);
            acc[2] = fmaf(wv, tv.z, acc[2]); acc[3] = fmaf(wv, tv.w, acc[3]);
        }
    }
#pragma unroll
    for (int j = 0; j < 4; j++) texbuf[(pxg * 4 + j) * 9 + og] = acc[j];
    __syncthreads();
    if (t < 128) {
        float l[4];
        float sgm[8];
#pragma unroll
        for (int j = 0; j < 8; j++)
            sgm[j] = 1.f / (1.f + expf(-(texbuf[t * 9 + j] + bpw8[j])));
        float best = -1e30f; int bi = 0;
#pragma unroll
        for (int e = 0; e < 4; e++) {
            float v = br[e];
#pragma unroll
            for (int j = 0; j < 8; j++) v = fmaf(wr[e * 8 + j], sgm[j], v);
            l[e] = v;
            if (v > best) { best = v; bi = e; }
        }
        (void)l;
        top[(size_t)b * HW + (h0 + (t >> 4)) * 256 + (w0 + (t & 15))] = bi;
    }
}

// ---------------------------------------------------------------- expert block: dw3x3+relu -> pw64x64 (+chansum)
// 16x16 px tile, 2-pass channel staging (half), b128 pointwise, fp32 accum.
__global__ __launch_bounds__(256, 3) void expert_block_kernel(const __half* __restrict__ in,
                                                              const float* __restrict__ qdw,
                                                              const float* __restrict__ dwb,
                                                              const float* __restrict__ qpw,
                                                              const float* __restrict__ pwb,
                                                              __half* __restrict__ out,
                                                              float* __restrict__ chansum) {
    __shared__ __half tile[32 * 18 * 20];    // 23040 B [cl][ry][20]
    __shared__ __half tmp[32 * 256];         // 16384 B [cl][px]
    __shared__ __half wTs[64 * 72];          // 9216 B transposed [ci][co], stride 72 (16B-aligned rows)
    __shared__ float wdw[576];
    __shared__ float bdw[64];
    __shared__ float bpw[64];
    const int t = threadIdx.x;
    const int b = blockIdx.z;
    const int h0 = blockIdx.y * 16, w0 = blockIdx.x * 16;

    for (int i = t; i < 576; i += 256) wdw[i] = qdw[i];
    // transposed pw weights: qpw is [co][ci]; coalesced global read, strided LDS write
    for (int j = t; j < 4096; j += 256) {
        const int co = j >> 6, ci = j & 63;
        wTs[ci * 72 + co] = __float2half(qpw[co * 64 + ci]);
    }
    if (t < 64) { bdw[t] = dwb[t]; bpw[t] = pwb[t]; }

    const __half* ib = in + (size_t)b * CHW;
    const int pxg = t & 31, cog = t >> 5;    // 32 px-groups (8 px) x 8 co-groups (8 co)
    float acc[8][8];
#pragma unroll
    for (int k = 0; k < 8; k++)
#pragma unroll
        for (int j = 0; j < 8; j++) acc[k][j] = 0.f;

    for (int pass = 0; pass < 2; pass++) {
        const int c0 = pass * 32;
        __syncthreads();   // protect tile (prev dw done) and tmp (prev pw done)
        // stage 32 channels: rows h0-1..h0+16 (18), cols w0-2..w0+17 (20)
        for (int i = t; i < 11520; i += 256) {
            const int c = i / 360, rem = i - c * 360;
            const int ry = rem / 20, rx = rem - ry * 20;
            const int hh = h0 + ry - 1, ww = w0 + rx - 2;
            __half v = __float2half(0.f);
            if (hh >= 0 && hh < 256 && ww >= 0 && ww < 256)
                v = ib[(size_t)(c0 + c) * HW + hh * 256 + ww];
            tile[i] = v;
        }
        __syncthreads();
        // depthwise row-tasks: 32ch x 16rows x 2halves = 1024, 8 px each
        for (int k = t; k < 1024; k += 256) {
            const int cl = k >> 5, r = (k >> 1) & 15, hf = k & 1;
            const float* wp = &wdw[(c0 + cl) * 9];
            float o[8];
            const float bv = bdw[c0 + cl];
#pragma unroll
            for (int j = 0; j < 8; j++) o[j] = bv;
#pragma unroll
            for (int dy = 0; dy < 3; dy++) {
                const float2* rowp = (const float2*)&tile[cl * 360 + (r + dy) * 20 + 8 * hf];
                union { float2 f2[3]; __half h[12]; } u;
#pragma unroll
                for (int q = 0; q < 3; q++) u.f2[q] = rowp[q];
                float f[12];
#pragma unroll
                for (int q = 0; q < 12; q++) f[q] = __half2float(u.h[q]);
                const float wa = wp[dy * 3], wb = wp[dy * 3 + 1], wc = wp[dy * 3 + 2];
#pragma unroll
                for (int j = 0; j < 8; j++)
                    o[j] = fmaf(f[j + 1], wa, fmaf(f[j + 2], wb, fmaf(f[j + 3], wc, o[j])));
            }
            __half2 pk[4];
#pragma unroll
            for (int j = 0; j < 4; j++)
                pk[j] = __floats2half2_rn(fmaxf(o[2 * j], 0.f), fmaxf(o[2 * j + 1], 0.f));
            *(float4*)&tmp[cl * 256 + r * 16 + hf * 8] = *(float4*)&pk[0];
        }
        __syncthreads();
        // pointwise partial accumulation over this pass's 32 ci
        for (int ci = 0; ci < 32; ci++) {
            float4 tv4 = *(const float4*)&tmp[ci * 256 + pxg * 8];
            float4 wv4 = *(const float4*)&wTs[(c0 + ci) * 72 + cog * 8];
            const __half2* th = (const __half2*)&tv4;
            const __half2* wh = (const __half2*)&wv4;
            float tv[8], wv[8];
#pragma unroll
            for (int q = 0; q < 4; q++) {
                float2 f = __half22float2(th[q]); tv[2 * q] = f.x; tv[2 * q + 1] = f.y;
                float2 g = __half22float2(wh[q]); wv[2 * q] = g.x; wv[2 * q + 1] = g.y;
            }
#pragma unroll
            for (int k = 0; k < 8; k++)
#pragma unroll
                for (int j = 0; j < 8; j++)
                    acc[k][j] = fmaf(wv[k], tv[j], acc[k][j]);
        }
    }

    // epilogue: bias, store 8px x 8co, channel sums
    const int py = pxg >> 1, pxx = (pxg & 1) * 8;
    __half* obase = out + (size_t)b * CHW + (h0 + py) * 256 + (w0 + pxx);
#pragma unroll
    for (int k = 0; k < 8; k++) {
        const int co = cog * 8 + k;
        const float bv = bpw[co];
        __half2 pk[4];
        float csum = 0.f;
#pragma unroll
        for (int j = 0; j < 4; j++) {
            const float v0 = acc[k][2 * j] + bv, v1 = acc[k][2 * j + 1] + bv;
            csum += v0 + v1;
            pk[j] = __floats2half2_rn(v0, v1);
        }
        *(float4*)&obase[(size_t)co * HW] = *(float4*)&pk[0];
        csum += __shfl_down(csum, 16);
        csum += __shfl_down(csum, 8);
        csum += __shfl_down(csum, 4);
        csum += __shfl_down(csum, 2);
        csum += __shfl_down(csum, 1);
        if (pxg == 0) atomicAdd(&chansum[b * 64 + co], csum);
    }
}

// ---------------------------------------------------------------- channel attention (tiny)
__global__ __launch_bounds__(256) void attention_kernel(const float* __restrict__ chansum,
                                                        const float* __restrict__ fc1,
                                                        const float* __restrict__ fc2,
                                                        float* __restrict__ y) {
    __shared__ float mean_s[256];
    __shared__ float hid[64];
    const int t = threadIdx.x;
    const int b = t >> 6, c = t & 63;
    mean_s[t] = chansum[t] * (1.f / 65536.f);
    __syncthreads();
    if (t < 64) {
        const int b2 = t >> 4, j = t & 15;
        float a = 0.f;
        for (int ci = 0; ci < 64; ci++) a = fmaf(fc1[j * 64 + ci], mean_s[b2 * 64 + ci], a);
        hid[t] = fmaxf(a, 0.f);
    }
    __syncthreads();
    float a = 0.f;
#pragma unroll
    for (int j = 0; j < 16; j++) a = fmaf(fc2[c * 16 + j], hid[b * 16 + j], a);
    y[t] = 1.f / (1.f + expf(-a));
}

// ---------------------------------------------------------------- A = A*y + feat_h  (in-place, all half)
__global__ __launch_bounds__(256) void apply_kernel(__half* __restrict__ A,
                                                    const float* __restrict__ yv,
                                                    const __half* __restrict__ F) {
    const int i8 = blockIdx.x * 256 + threadIdx.x;   // 8-half chunk index, exact grid
    const int ei = i8 << 3;
    const float y = yv[ei >> 16];                    // b*64+c
    float4 av = ((const float4*)A)[i8];
    float4 fv = ((const float4*)F)[i8];
    const __half2* ah = (const __half2*)&av;
    const __half2* fh = (const __half2*)&fv;
    __half2 outv[4];
#pragma unroll
    for (int j = 0; j < 4; j++) {
        const float2 a2 = __half22float2(ah[j]);
        const float2 f2 = __half22float2(fh[j]);
        outv[j] = __floats2half2_rn(fmaf(a2.x, y, f2.x), fmaf(a2.y, y, f2.y));
    }
    ((float4*)A)[i8] = *(float4*)outv;
}

// ---------------------------------------------------------------- routed select: M = B*y + A where top==e
__global__ __launch_bounds__(256) void select_kernel(const __half* __restrict__ Bv,
                                                     const float* __restrict__ yv,
                                                     const __half* __restrict__ A,
                                                     const int* __restrict__ top,
                                                     __half* __restrict__ M, int e) {
    const int i8 = blockIdx.x * 256 + threadIdx.x;   // 8-half chunk, exact grid
    const int ei = i8 << 3;
    const int bc = ei >> 16;
    const int b = bc >> 6;
    const int hw = ei & (HW - 1);
    const int* tp = top + (size_t)b * HW + hw;
    const int4 t0 = ((const int4*)tp)[0];
    const int4 t1 = ((const int4*)tp)[1];
    const int tt[8] = {t0.x, t0.y, t0.z, t0.w, t1.x, t1.y, t1.z, t1.w};
    bool any = false;
#pragma unroll
    for (int j = 0; j < 8; j++) any |= (tt[j] == e);
    if (!any) return;
    const float y = yv[bc];
    float4 bv4 = ((const float4*)Bv)[i8];
    float4 av4 = ((const float4*)A)[i8];
    const __half2* bh = (const __half2*)&bv4;
    const __half2* ah = (const __half2*)&av4;
#pragma unroll
    for (int j = 0; j < 4; j++) {
        const float2 b2 = __half22float2(bh[j]);
        const float2 a2 = __half22float2(ah[j]);
        if (tt[2 * j]     == e) M[ei + 2 * j]     = __float2half(fmaf(b2.x, y, a2.x));
        if (tt[2 * j + 1] == e) M[ei + 2 * j + 1] = __float2half(fmaf(b2.y, y, a2.y));
    }
}

// ---------------------------------------------------------------- bilinear x2 upsample (jax.image.resize semantics)
__device__ __forceinline__ float bilin_up(const float* __restrict__ xb, int h, int w, int r1, int r2) {
    int hlo, hhi; float wrr;
    if (r1 == 0) { hlo = h - 1; hhi = h;     wrr = 0.25f; }
    else         { hlo = h;     hhi = h + 1; wrr = 0.75f; }
    if (hlo < 0)   { hlo = 0;   wrr = 0.f; }
    if (hhi > 255) { hhi = 255; wrr = 1.f; }
    int wlo, whi; float wcc;
    if (r2 == 0) { wlo = w - 1; whi = w;     wcc = 0.25f; }
    else         { wlo = w;     whi = w + 1; wcc = 0.75f; }
    if (wlo < 0)   { wlo = 0;   wcc = 0.f; }
    if (whi > 255) { whi = 255; wcc = 1.f; }
    const float a = xb[hlo * 256 + wlo] * wcc + xb[hlo * 256 + whi] * (1.f - wcc);
    const float b = xb[hhi * 256 + wlo] * wcc + xb[hhi * 256 + whi] * (1.f - wcc);
    return a * wrr + b * (1.f - wrr);
}

// ---------------------------------------------------------------- recon 3x3 (64->12) + pixel shuffle + x_up add
__global__ __launch_bounds__(256) void recon_kernel(const __half* __restrict__ moe,
                                                    const float* __restrict__ rw,
                                                    const float* __restrict__ rbias,
                                                    const float* __restrict__ x,
                                                    float* __restrict__ sr) {
    __shared__ float tile[324];
    __shared__ float wsm[6912];
    __shared__ float bsm[12];
    const int t = threadIdx.y * 16 + threadIdx.x;
    for (int i = t; i < 6912; i += 256) wsm[i] = rw[i];
    if (t < 12) bsm[t] = rbias[t];
    const int b = blockIdx.z;
    const int h0 = blockIdx.y * 16, w0 = blockIdx.x * 16;
    const int h = h0 + threadIdx.y, w = w0 + threadIdx.x;
    const __half* mb = moe + (size_t)b * CHW;
    float acc[12];
#pragma unroll
    for (int o = 0; o < 12; o++) acc[o] = 0.f;
    for (int ci = 0; ci < 64; ci++) {
        __syncthreads();
        for (int i = t; i < 324; i += 256) {
            int ty = i / 18, tx = i - ty * 18;
            int hh = h0 + ty - 1, ww = w0 + tx - 1;
            tile[i] = (hh >= 0 && hh < 256 && ww >= 0 && ww < 256)
                        ? __half2float(mb[(size_t)ci * HW + hh * 256 + ww]) : 0.f;
        }
        __syncthreads();
        float tp[9];
#pragma unroll
        for (int dy = 0; dy < 3; dy++)
#pragma unroll
            for (int dx = 0; dx < 3; dx++)
                tp[dy * 3 + dx] = tile[(threadIdx.y + dy) * 18 + threadIdx.x + dx];
        const float* wc = &wsm[ci * 9];
#pragma unroll
        for (int o = 0; o < 12; o++) {
            const float* wo = wc + o * 576;
            float a = acc[o];
#pragma unroll
            for (int k = 0; k < 9; k++) a = fmaf(tp[k], wo[k], a);
            acc[o] = a;
        }
    }
#pragma unroll
    for (int o = 0; o < 12; o++) {
        const int c = o >> 2, r1 = (o >> 1) & 1, r2 = o & 1;
        const float* xb = x + ((size_t)b * 3 + c) * HW;
        const float xu = bilin_up(xb, h, w, r1, r2);
        const int i2 = 2 * h + r1, j2 = 2 * w + r2;
        sr[((size_t)b * 3 + c) * HW2 + i2 * 512 + j2] = acc[o] + bsm[o] + xu;
    }
}

// ---------------------------------------------------------------- 3x3 conv on [4][3][512][512] (refinement)
__global__ __launch_bounds__(256) void ref_conv_kernel(const float* __restrict__ in,
                                                       const float* __restrict__ qw,
                                                       const float* __restrict__ bb,
                                                       const float* __restrict__ addsrc,
                                                       float* __restrict__ outp,
                                                       int do_relu) {
    __shared__ float tile[324];
    __shared__ float wsm[81];
    __shared__ float bsm[3];
    const int t = threadIdx.y * 16 + threadIdx.x;
    if (t < 81) wsm[t] = qw[t];
    if (t < 3) bsm[t] = bb[t];
    const int b = blockIdx.z;
    const int h0 = blockIdx.y * 16, w0 = blockIdx.x * 16;
    const int h = h0 + threadIdx.y, w = w0 + threadIdx.x;
    float acc[3] = {0.f, 0.f, 0.f};
    for (int ci = 0; ci < 3; ci++) {
        __syncthreads();
        const float* ibp = in + ((size_t)b * 3 + ci) * HW2;
        for (int i = t; i < 324; i += 256) {
            int ty = i / 18, tx = i - ty * 18;
            int hh = h0 + ty - 1, ww = w0 + tx - 1;
            tile[i] = (hh >= 0 && hh < 512 && ww >= 0 && ww < 512) ? ibp[hh * 512 + ww] : 0.f;
        }
        __syncthreads();
        float tp[9];
#pragma unroll
        for (int dy = 0; dy < 3; dy++)
#pragma unroll
            for (int dx = 0; dx < 3; dx++)
                tp[dy * 3 + dx] = tile[(threadIdx.y + dy) * 18 + threadIdx.x + dx];
#pragma unroll
        for (int o = 0; o < 3; o++) {
            const float* wo = &wsm[o * 27 + ci * 9];
            float a = acc[o];
#pragma unroll
            for (int k = 0; k < 9; k++) a = fmaf(tp[k], wo[k], a);
            acc[o] = a;
        }
    }
#pragma unroll
    for (int o = 0; o < 3; o++) {
        float v = acc[o] + bsm[o];
        if (do_relu) v = fmaxf(v, 0.f);
        if (addsrc) v += addsrc[((size_t)b * 3 + o) * HW2 + h * 512 + w];
        outp[((size_t)b * 3 + o) * HW2 + h * 512 + w] = v;
    }
}

// ---------------------------------------------------------------- launcher
extern "C" void kernel_launch(void* const* d_in, const int* in_sizes, int n_in,
                              void* d_out, int out_size, void* d_ws, size_t ws_size,
                              hipStream_t stream) {
    const float* x         = (const float*)d_in[0];
    const float* shallow_w = (const float*)d_in[1];
    const float* shallow_b = (const float*)d_in[2];
    const float* tex_dw_w  = (const float*)d_in[3];
    const float* tex_dw_b  = (const float*)d_in[4];
    const float* tex_pw_w  = (const float*)d_in[5];
    const float* tex_pw_b  = (const float*)d_in[6];
    const float* router_w  = (const float*)d_in[7];
    const float* router_b  = (const float*)d_in[8];
    const float* exp_dw_w  = (const float*)d_in[9];
    const float* exp_dw_b  = (const float*)d_in[10];
    const float* exp_pw_w  = (const float*)d_in[11];
    const float* exp_pw_b  = (const float*)d_in[12];
    const float* exp_fc1   = (const float*)d_in[13];
    const float* exp_fc2   = (const float*)d_in[14];
    const float* recon_w   = (const float*)d_in[15];
    const float* recon_b   = (const float*)d_in[16];
    const float* ref1_w    = (const float*)d_in[17];
    const float* ref1_b    = (const float*)d_in[18];
    const float* ref2_w    = (const float*)d_in[19];
    const float* ref2_b    = (const float*)d_in[20];

    // workspace layout (~193 MB)
    float*  feat   = (float*)d_ws;                     // BCHW fp32 (64 MB)
    __half* feat_h = (__half*)(feat + BCHW);           // BCHW half (32 MB)
    __half* A      = feat_h + BCHW;                    // BCHW half (32 MB)
    __half* Bv     = A + BCHW;                         // BCHW half (32 MB)
    __half* M      = Bv + BCHW;                        // BCHW half (32 MB)
    int*    top    = (int*)(M + BCHW);                 // 1 MB
    float*  qb     = (float*)(top + 262144);
    float*  q_sh   = qb;                 // 1728
    float*  q_tdw  = q_sh + 1728;        // 576
    float*  q_tpw  = q_tdw + 576;        // 512
    float*  q_edw  = q_tpw + 512;        // 8*576
    float*  q_epw  = q_edw + 4608;       // 8*4096
    float*  q_r1   = q_epw + 32768;      // 81
    float*  q_r2   = q_r1 + 81;          // 81
    float*  chans  = q_r2 + 81;          // 8*256
    float*  yatt   = chans + 2048;       // 8*256
    // sr/t1 alias A/Bv (free after MoE select; recon only needs M)
    float*  sr     = (float*)A;          // 12 MB <= 32 MB
    float*  t1     = (float*)Bv;

    hipMemsetAsync(chans, 0, 2048 * sizeof(float), stream);

    TernArgs ta;
    ta.d[0] = { shallow_w, q_sh, 1728 };
    ta.d[1] = { tex_dw_w, q_tdw, 576 };
    ta.d[2] = { tex_pw_w, q_tpw, 512 };
    for (int i = 0; i < 8; i++) ta.d[3 + i]  = { exp_dw_w + i * 576,  q_edw + i * 576,  576 };
    for (int i = 0; i < 8; i++) ta.d[11 + i] = { exp_pw_w + i * 4096, q_epw + i * 4096, 4096 };
    ta.d[19] = { ref1_w, q_r1, 81 };
    ta.d[20] = { ref2_w, q_r2, 81 };
    ternarize_kernel<<<21, 256, 0, stream>>>(ta);

    shallow_kernel<<<dim3(16, 16, 4), dim3(16, 16), 0, stream>>>(x, q_sh, shallow_b, feat, feat_h);
    router_kernel<<<dim3(16, 32, 4), 256, 0, stream>>>(
        feat, q_tdw, tex_dw_b, q_tpw, tex_pw_b, router_w, router_b, top);

    for (int e = 0; e < 4; e++) {
        const int i0 = e * 2, i1 = e * 2 + 1;
        expert_block_kernel<<<dim3(16, 16, 4), 256, 0, stream>>>(
            feat_h, q_edw + i0 * 576, exp_dw_b + i0 * 64, q_epw + i0 * 4096, exp_pw_b + i0 * 64,
            A, chans + i0 * 256);
        attention_kernel<<<1, 256, 0, stream>>>(chans + i0 * 256, exp_fc1 + i0 * 1024,
                                                exp_fc2 + i0 * 1024, yatt + i0 * 256);
        apply_kernel<<<8192, 256, 0, stream>>>(A, yatt + i0 * 256, feat_h);
        expert_block_kernel<<<dim3(16, 16, 4), 256, 0, stream>>>(
            A, q_edw + i1 * 576, exp_dw_b + i1 * 64, q_epw + i1 * 4096, exp_pw_b + i1 * 64,
            Bv, chans + i1 * 256);
        attention_kernel<<<1, 256, 0, stream>>>(chans + i1 * 256, exp_fc1 + i1 * 1024,
                                                exp_fc2 + i1 * 1024, yatt + i1 * 256);
        select_kernel<<<8192, 256, 0, stream>>>(Bv, yatt + i1 * 256, A, top, M, e);
    }

    recon_kernel<<<dim3(16, 16, 4), dim3(16, 16), 0, stream>>>(M, recon_w, recon_b, x, sr);
    ref_conv_kernel<<<dim3(32, 32, 4), dim3(16, 16), 0, stream>>>(sr, q_r1, ref1_b, nullptr, t1, 1);
    ref_conv_kernel<<<dim3(32, 32, 4), dim3(16, 16), 0, stream>>>(t1, q_r2, ref2_b, sr, (float*)d_out, 0);
}

// Round 4
// 1272.469 us; speedup vs baseline: 2.7110x; 1.6372x over previous
//
#include <hip/hip_runtime.h>
#include <hip/hip_fp16.h>
#include <math.h>

#define HW 65536            // 256*256
#define CHW 4194304         // 64*HW  (NHWC elements per batch)
#define BCHW 16777216
#define HW2 262144          // 512*512

typedef _Float16 half8 __attribute__((ext_vector_type(8)));
typedef float f32x4 __attribute__((ext_vector_type(4)));

// ---------------------------------------------------------------- ternarize
struct TernDesc { const float* src; float* dst; int n; };
struct TernArgs { TernDesc d[21]; };

__global__ __launch_bounds__(256) void ternarize_kernel(TernArgs args) {
    __shared__ float red[256];
    __shared__ float bc[2];
    TernDesc td = args.d[blockIdx.x];
    const int n = td.n;
    const int t = threadIdx.x;
    float s = 0.f;
    for (int i = t; i < n; i += 256) s += fabsf(td.src[i]);
    red[t] = s; __syncthreads();
    for (int k = 128; k > 0; k >>= 1) { if (t < k) red[t] += red[t + k]; __syncthreads(); }
    if (t == 0) bc[0] = 0.75f * red[0] / (float)n;
    __syncthreads();
    const float delta = bc[0];
    float s1 = 0.f, c1 = 0.f;
    for (int i = t; i < n; i += 256) {
        float a = fabsf(td.src[i]);
        if (a > delta) { s1 += a; c1 += 1.f; }
    }
    __syncthreads();
    red[t] = s1; __syncthreads();
    for (int k = 128; k > 0; k >>= 1) { if (t < k) red[t] += red[t + k]; __syncthreads(); }
    float sum1 = red[0];
    __syncthreads();
    red[t] = c1; __syncthreads();
    for (int k = 128; k > 0; k >>= 1) { if (t < k) red[t] += red[t + k]; __syncthreads(); }
    if (t == 0) bc[1] = sum1 / fmaxf(red[0], 1.f);
    __syncthreads();
    const float alpha = bc[1];
    for (int i = t; i < n; i += 256) {
        float w = td.src[i];
        td.dst[i] = (fabsf(w) > delta) ? ((w > 0.f) ? alpha : -alpha) : 0.f;
    }
}

// ---------------------------------------------------------------- shallow 3x3 (3->64)+relu; feat fp32 NCHW + feat_h half NHWC
__global__ __launch_bounds__(256) void shallow_kernel(const float* __restrict__ x,
                                                      const float* __restrict__ qw,
                                                      const float* __restrict__ bias,
                                                      float* __restrict__ feat,
                                                      __half* __restrict__ feat_h) {
    __shared__ float wsm[1728];
    __shared__ float bsm[64];
    const int t = threadIdx.y * 16 + threadIdx.x;
    for (int i = t; i < 1728; i += 256) wsm[i] = qw[i];
    if (t < 64) bsm[t] = bias[t];
    __syncthreads();
    const int b = blockIdx.z;
    const int h = blockIdx.y * 16 + threadIdx.y;
    const int w = blockIdx.x * 16 + threadIdx.x;
    const float* xb = x + (size_t)b * 3 * HW;
    float patch[27];
#pragma unroll
    for (int ci = 0; ci < 3; ci++)
#pragma unroll
        for (int dy = 0; dy < 3; dy++)
#pragma unroll
            for (int dx = 0; dx < 3; dx++) {
                int hh = h + dy - 1, ww = w + dx - 1;
                patch[ci * 9 + dy * 3 + dx] =
                    (hh >= 0 && hh < 256 && ww >= 0 && ww < 256) ? xb[ci * HW + hh * 256 + ww] : 0.f;
            }
    float* fb = feat + (size_t)b * CHW + h * 256 + w;      // NCHW fp32
    __half* fhb = feat_h + ((size_t)b * HW + h * 256 + w) * 64;  // NHWC half
    for (int cg = 0; cg < 8; cg++) {
        half8 pk;
#pragma unroll
        for (int k = 0; k < 8; k++) {
            const int co = cg * 8 + k;
            const float* wp = &wsm[co * 27];
            float acc = bsm[co];
#pragma unroll
            for (int q = 0; q < 27; q++) acc = fmaf(patch[q], wp[q], acc);
            acc = fmaxf(acc, 0.f);
            fb[(size_t)co * HW] = acc;
            pk[k] = (_Float16)acc;
        }
        *(half8*)&fhb[cg * 8] = pk;
    }
}

// ---------------------------------------------------------------- router (fp32 NCHW feat) - unchanged structure
__global__ __launch_bounds__(256) void router_kernel(const float* __restrict__ feat,
                                                     const float* __restrict__ qdw,
                                                     const float* __restrict__ dwb,
                                                     const float* __restrict__ qpw,
                                                     const float* __restrict__ pwbias,
                                                     const float* __restrict__ rw,
                                                     const float* __restrict__ rbias,
                                                     int* __restrict__ top) {
    __shared__ float tile[32 * 10 * 20];
    __shared__ float tmp[32 * 128];
    __shared__ float texbuf[128 * 9];
    __shared__ float wdw[576];
    __shared__ float wpw[512];
    __shared__ float bdw[64];
    __shared__ float bpw8[8];
    __shared__ float wr[32];
    __shared__ float br[4];
    const int t = threadIdx.x;
    const int b = blockIdx.z;
    const int h0 = blockIdx.y * 8, w0 = blockIdx.x * 16;

    for (int i = t; i < 576; i += 256) wdw[i] = qdw[i];
    for (int i = t; i < 512; i += 256) wpw[i] = qpw[i];
    if (t < 64) bdw[t] = dwb[t];
    if (t < 8) bpw8[t] = pwbias[t];
    if (t < 32) wr[t] = rw[t];
    if (t < 4) br[t] = rbias[t];

    const float* fb = feat + (size_t)b * CHW;
    const int pxg = t & 31, og = t >> 5;
    float acc[4] = {0.f, 0.f, 0.f, 0.f};

    for (int pass = 0; pass < 2; pass++) {
        const int c0 = pass * 32;
        __syncthreads();
        for (int i = t; i < 6400; i += 256) {
            const int c = i / 200, rem = i - c * 200;
            const int ry = rem / 20, rx = rem - ry * 20;
            const int hh = h0 + ry - 1, ww = w0 + rx - 2;
            tile[i] = (hh >= 0 && hh < 256 && ww >= 0 && ww < 256)
                        ? fb[(size_t)(c0 + c) * HW + hh * 256 + ww] : 0.f;
        }
        __syncthreads();
        for (int k = t; k < 512; k += 256) {
            const int cl = k >> 4, r = (k >> 1) & 7, hf = k & 1;
            const float* wp = &wdw[(c0 + cl) * 9];
            float o[8];
            const float bv = bdw[c0 + cl];
#pragma unroll
            for (int j = 0; j < 8; j++) o[j] = bv;
#pragma unroll
            for (int dy = 0; dy < 3; dy++) {
                const float* rowp = &tile[cl * 200 + (r + dy) * 20 + 8 * hf];
                float f[12];
#pragma unroll
                for (int q = 0; q < 3; q++) {
                    float4 v = *(const float4*)&rowp[q * 4];
                    f[q * 4] = v.x; f[q * 4 + 1] = v.y; f[q * 4 + 2] = v.z; f[q * 4 + 3] = v.w;
                }
                const float wa = wp[dy * 3], wb = wp[dy * 3 + 1], wc = wp[dy * 3 + 2];
#pragma unroll
                for (int j = 0; j < 8; j++)
                    o[j] = fmaf(f[j + 1], wa, fmaf(f[j + 2], wb, fmaf(f[j + 3], wc, o[j])));
            }
            float* tp = &tmp[cl * 128 + r * 16 + hf * 8];
#pragma unroll
            for (int j = 0; j < 8; j++) tp[j] = fmaxf(o[j], 0.f);
        }
        __syncthreads();
        for (int ci = 0; ci < 32; ci++) {
            const float4 tv = *(const float4*)&tmp[ci * 128 + pxg * 4];
            const float wv = wpw[og * 64 + c0 + ci];
            acc[0] = fmaf(wv, tv.x, acc[0]); acc[1] = fmaf(wv, tv.y, acc[1]);
            acc[2] = fmaf(wv, tv.z, acc[2]); acc[3] = fmaf(wv, tv.w, acc[3]);
        }
    }
#pragma unroll
    for (int j = 0; j < 4; j++) texbuf[(pxg * 4 + j) * 9 + og] = acc[j];
    __syncthreads();
    if (t < 128) {
        float sgm[8];
#pragma unroll
        for (int j = 0; j < 8; j++)
            sgm[j] = 1.f / (1.f + expf(-(texbuf[t * 9 + j] + bpw8[j])));
        float best = -1e30f; int bi = 0;
#pragma unroll
        for (int e = 0; e < 4; e++) {
            float v = br[e];
#pragma unroll
            for (int j = 0; j < 8; j++) v = fmaf(wr[e * 8 + j], sgm[j], v);
            if (v > best) { best = v; bi = e; }
        }
        top[(size_t)b * HW + (h0 + (t >> 4)) * 256 + (w0 + (t & 15))] = bi;
    }
}

// ---------------------------------------------------------------- expert block: NHWC, dw(VALU fp32) -> pw(MFMA f16)
__global__ __launch_bounds__(256, 3) void expert_block_kernel(const __half* __restrict__ in,
                                                              const float* __restrict__ qdw,
                                                              const float* __restrict__ dwb,
                                                              const float* __restrict__ qpw,
                                                              const float* __restrict__ pwb,
                                                              __half* __restrict__ out,
                                                              float* __restrict__ chansum) {
    __shared__ __half tile[4 * 324 * 8];   // [cg][ry*18+rx][8ci] 20736 B
    __shared__ __half wT[64 * 72];         // [co][ci pad72] 9216 B
    __shared__ __half wdwh[9 * 64];        // [tap][ci] 1152 B
    __shared__ float bdw[64];
    __shared__ float bpw[64];
    const int t = threadIdx.x;
    const int b = blockIdx.z;
    const int h0 = blockIdx.y * 16, w0 = blockIdx.x * 16;

    for (int i = t; i < 4096; i += 256) wT[(i >> 6) * 72 + (i & 63)] = __float2half(qpw[i]);
    for (int i = t; i < 576; i += 256) {
        const int ci = i / 9, tap = i - ci * 9;
        wdwh[tap * 64 + ci] = __float2half(qdw[i]);
    }
    if (t < 64) { bdw[t] = dwb[t]; bpw[t] = pwb[t]; }

    const int lane = t & 63, wv = t >> 6;
    const int l15 = lane & 15, quad = lane >> 4;
    f32x4 acc[4][4];
#pragma unroll
    for (int i = 0; i < 4; i++)
#pragma unroll
        for (int j = 0; j < 4; j++) acc[i][j] = (f32x4){0.f, 0.f, 0.f, 0.f};

    const __half* ib = in + (size_t)b * CHW;

    for (int pass = 0; pass < 2; pass++) {
        __syncthreads();
        // stage 32 ci of the 18x18 halo ([cg][px][8])
        for (int i = t; i < 1296; i += 256) {
            const int cg = i & 3;
            const int rem = i >> 2;            // 0..323
            const int ry = rem / 18, rx = rem - ry * 18;
            const int hh = h0 + ry - 1, ww = w0 + rx - 1;
            half8 v = {};
            if (hh >= 0 && hh < 256 && ww >= 0 && ww < 256)
                v = *(const half8*)&ib[(size_t)(hh * 256 + ww) * 64 + pass * 32 + cg * 8];
            *(half8*)&tile[(cg * 324 + rem) * 8] = v;
        }
        __syncthreads();
        // B fragments: B[k=ci][n=co], lane holds n=l15, k=quad*8+j
        half8 bf[4];
#pragma unroll
        for (int ct = 0; ct < 4; ct++)
            bf[ct] = *(const half8*)&wT[(ct * 16 + l15) * 72 + pass * 32 + quad * 8];
        // dw weights + bias for lane's 8 ci
        half8 wv9[9];
#pragma unroll
        for (int tap = 0; tap < 9; tap++)
            wv9[tap] = *(const half8*)&wdwh[tap * 64 + pass * 32 + quad * 8];
        float bias8[8];
#pragma unroll
        for (int j = 0; j < 8; j++) bias8[j] = bdw[pass * 32 + quad * 8 + j];
        // 4 px-row tiles per wave
#pragma unroll
        for (int T = 0; T < 4; T++) {
            const int py = wv * 4 + T;     // tile-local row
            half8 xv[9];
#pragma unroll
            for (int dy = 0; dy < 3; dy++)
#pragma unroll
                for (int dx = 0; dx < 3; dx++)
                    xv[dy * 3 + dx] = *(const half8*)&tile[(quad * 324 + (py + dy) * 18 + (l15 + dx)) * 8];
            float o[8];
#pragma unroll
            for (int j = 0; j < 8; j++) o[j] = bias8[j];
#pragma unroll
            for (int tap = 0; tap < 9; tap++)
#pragma unroll
                for (int j = 0; j < 8; j++)
                    o[j] = fmaf((float)xv[tap][j], (float)wv9[tap][j], o[j]);
            half8 a;
#pragma unroll
            for (int j = 0; j < 8; j++) a[j] = (_Float16)fmaxf(o[j], 0.f);
#pragma unroll
            for (int ct = 0; ct < 4; ct++)
                acc[T][ct] = __builtin_amdgcn_mfma_f32_16x16x32_f16(a, bf[ct], acc[T][ct], 0, 0, 0);
        }
    }
    // epilogue: D row=(quad*4+r)=px col, col=l15=co within co-tile
    __half* ob = out + (size_t)b * CHW;
    float cs[4] = {0.f, 0.f, 0.f, 0.f};
#pragma unroll
    for (int T = 0; T < 4; T++) {
        const int py = h0 + wv * 4 + T;
#pragma unroll
        for (int ct = 0; ct < 4; ct++) {
            const int co = ct * 16 + l15;
            const float bv = bpw[co];
#pragma unroll
            for (int r = 0; r < 4; r++) {
                const int pxc = quad * 4 + r;
                const float v = acc[T][ct][r] + bv;
                cs[ct] += v;
                ob[(size_t)(py * 256 + w0 + pxc) * 64 + co] = __float2half(v);
            }
        }
    }
#pragma unroll
    for (int ct = 0; ct < 4; ct++) {
        float s = cs[ct];
        s += __shfl_xor(s, 16);
        s += __shfl_xor(s, 32);
        if (quad == 0) atomicAdd(&chansum[b * 64 + ct * 16 + l15], s);
    }
}

// ---------------------------------------------------------------- apply: A = A*y + F (NHWC), attention fused
__global__ __launch_bounds__(256) void apply_kernel(__half* __restrict__ A,
                                                    const float* __restrict__ chansum,
                                                    const float* __restrict__ fc1,
                                                    const float* __restrict__ fc2,
                                                    const __half* __restrict__ F) {
    __shared__ float hid[16];
    __shared__ float ysm[64];
    const int t = threadIdx.x;
    const int i8 = blockIdx.x * 256 + t;
    const int ei = i8 << 3;
    const int b = ei >> 22;
    if (t < 16) {
        float a = 0.f;
        for (int ci = 0; ci < 64; ci++) a = fmaf(fc1[t * 64 + ci], chansum[b * 64 + ci], a);
        hid[t] = fmaxf(a, 0.f) * (1.f / 65536.f);
    }
    __syncthreads();
    if (t < 64) {
        float a = 0.f;
#pragma unroll
        for (int j = 0; j < 16; j++) a = fmaf(fc2[t * 16 + j], hid[j], a);
        ysm[t] = 1.f / (1.f + expf(-a));
    }
    __syncthreads();
    const int c0 = ei & 63;
    float4 av = ((const float4*)A)[i8];
    float4 fv = ((const float4*)F)[i8];
    const __half2* ah = (const __half2*)&av;
    const __half2* fh = (const __half2*)&fv;
    __half2 outv[4];
#pragma unroll
    for (int j = 0; j < 4; j++) {
        const float2 a2 = __half22float2(ah[j]);
        const float2 f2 = __half22float2(fh[j]);
        outv[j] = __floats2half2_rn(fmaf(a2.x, ysm[c0 + 2 * j], f2.x),
                                    fmaf(a2.y, ysm[c0 + 2 * j + 1], f2.y));
    }
    ((float4*)A)[i8] = *(float4*)outv;
}

// ---------------------------------------------------------------- select: M = B*y + A where top==e (NHWC), attention fused
__global__ __launch_bounds__(256) void select_kernel(const __half* __restrict__ Bv,
                                                     const float* __restrict__ chansum,
                                                     const float* __restrict__ fc1,
                                                     const float* __restrict__ fc2,
                                                     const __half* __restrict__ A,
                                                     const int* __restrict__ top,
                                                     __half* __restrict__ M, int e) {
    __shared__ float hid[16];
    __shared__ float ysm[64];
    const int t = threadIdx.x;
    const int i8 = blockIdx.x * 256 + t;
    const int ei = i8 << 3;
    const int b = ei >> 22;
    if (t < 16) {
        float a = 0.f;
        for (int ci = 0; ci < 64; ci++) a = fmaf(fc1[t * 64 + ci], chansum[b * 64 + ci], a);
        hid[t] = fmaxf(a, 0.f) * (1.f / 65536.f);
    }
    __syncthreads();
    if (t < 64) {
        float a = 0.f;
#pragma unroll
        for (int j = 0; j < 16; j++) a = fmaf(fc2[t * 16 + j], hid[j], a);
        ysm[t] = 1.f / (1.f + expf(-a));
    }
    __syncthreads();
    const int px = ei >> 6;        // global pixel index == top index
    if (top[px] != e) return;
    const int c0 = ei & 63;
    float4 bv4 = ((const float4*)Bv)[i8];
    float4 av4 = ((const float4*)A)[i8];
    const __half2* bh = (const __half2*)&bv4;
    const __half2* ah = (const __half2*)&av4;
    __half2 outv[4];
#pragma unroll
    for (int j = 0; j < 4; j++) {
        const float2 b2 = __half22float2(bh[j]);
        const float2 a2 = __half22float2(ah[j]);
        outv[j] = __floats2half2_rn(fmaf(b2.x, ysm[c0 + 2 * j], a2.x),
                                    fmaf(b2.y, ysm[c0 + 2 * j + 1], a2.y));
    }
    ((float4*)M)[i8] = *(float4*)outv;
}

// ---------------------------------------------------------------- bilinear x2 upsample (jax.image.resize semantics)
__device__ __forceinline__ float bilin_up(const float* __restrict__ xb, int h, int w, int r1, int r2) {
    int hlo, hhi; float wrr;
    if (r1 == 0) { hlo = h - 1; hhi = h;     wrr = 0.25f; }
    else         { hlo = h;     hhi = h + 1; wrr = 0.75f; }
    if (hlo < 0)   { hlo = 0;   wrr = 0.f; }
    if (hhi > 255) { hhi = 255; wrr = 1.f; }
    int wlo, whi; float wcc;
    if (r2 == 0) { wlo = w - 1; whi = w;     wcc = 0.25f; }
    else         { wlo = w;     whi = w + 1; wcc = 0.75f; }
    if (wlo < 0)   { wlo = 0;   wcc = 0.f; }
    if (whi > 255) { whi = 255; wcc = 1.f; }
    const float a = xb[hlo * 256 + wlo] * wcc + xb[hlo * 256 + whi] * (1.f - wcc);
    const float b = xb[hhi * 256 + wlo] * wcc + xb[hhi * 256 + whi] * (1.f - wcc);
    return a * wrr + b * (1.f - wrr);
}

// ---------------------------------------------------------------- recon: 9 shifted MFMA GEMMs + pixel shuffle + x_up
__global__ __launch_bounds__(256, 3) void recon_kernel(const __half* __restrict__ moe,   // NHWC
                                                       const float* __restrict__ rw,     // [12][64][9]
                                                       const float* __restrict__ rbias,
                                                       const float* __restrict__ x,
                                                       float* __restrict__ sr) {
    __shared__ __half tile[4 * 324 * 8];     // 20736 B
    __shared__ __half Wt[9 * 16 * 72];       // [tap][n pad16][ci pad72] 20736 B
    __shared__ float bsm12[12];
    const int t = threadIdx.x;
    const int b = blockIdx.z;
    const int h0 = blockIdx.y * 16, w0 = blockIdx.x * 16;

    // stage Wt: B[k=ci][n=o] = rw[o][ci][tap]
    for (int i = t; i < 9216; i += 256) {
        const int tap = i / 1024, rem = i - tap * 1024;
        const int n = rem >> 6, ci = rem & 63;
        Wt[(tap * 16 + n) * 72 + ci] = __float2half(n < 12 ? rw[n * 576 + ci * 9 + tap] : 0.f);
    }
    if (t < 12) bsm12[t] = rbias[t];

    const int lane = t & 63, wvi = t >> 6;
    const int l15 = lane & 15, quad = lane >> 4;
    f32x4 acc[4];
#pragma unroll
    for (int i = 0; i < 4; i++) acc[i] = (f32x4){0.f, 0.f, 0.f, 0.f};

    const __half* mb = moe + (size_t)b * CHW;

    for (int pass = 0; pass < 2; pass++) {
        __syncthreads();
        for (int i = t; i < 1296; i += 256) {
            const int cg = i & 3;
            const int rem = i >> 2;
            const int ry = rem / 18, rx = rem - ry * 18;
            const int hh = h0 + ry - 1, ww = w0 + rx - 1;
            half8 v = {};
            if (hh >= 0 && hh < 256 && ww >= 0 && ww < 256)
                v = *(const half8*)&mb[(size_t)(hh * 256 + ww) * 64 + pass * 32 + cg * 8];
            *(half8*)&tile[(cg * 324 + rem) * 8] = v;
        }
        __syncthreads();
        half8 bf[9];
#pragma unroll
        for (int tap = 0; tap < 9; tap++)
            bf[tap] = *(const half8*)&Wt[(tap * 16 + l15) * 72 + pass * 32 + quad * 8];
#pragma unroll
        for (int T = 0; T < 4; T++) {
            const int py = wvi * 4 + T;
#pragma unroll
            for (int dy = 0; dy < 3; dy++)
#pragma unroll
                for (int dx = 0; dx < 3; dx++) {
                    half8 a = *(const half8*)&tile[(quad * 324 + (py + dy) * 18 + (l15 + dx)) * 8];
                    acc[T] = __builtin_amdgcn_mfma_f32_16x16x32_f16(a, bf[dy * 3 + dx], acc[T], 0, 0, 0);
                }
        }
    }
    // epilogue: col=l15=o (use <12), rows=quad*4+r=px col
    if (l15 < 12) {
        const int c = l15 >> 2, r1 = (l15 >> 1) & 1, r2 = l15 & 1;
        const float* xb = x + ((size_t)b * 3 + c) * HW;
        const float bv = bsm12[l15];
        float* sb = sr + ((size_t)b * 3 + c) * HW2;
#pragma unroll
        for (int T = 0; T < 4; T++) {
            const int py = h0 + wvi * 4 + T;
#pragma unroll
            for (int r = 0; r < 4; r++) {
                const int wglob = w0 + quad * 4 + r;
                const float xu = bilin_up(xb, py, wglob, r1, r2);
                sb[(2 * py + r1) * 512 + 2 * wglob + r2] = acc[T][r] + bv + xu;
            }
        }
    }
}

// ---------------------------------------------------------------- 3x3 conv on [4][3][512][512] (refinement)
__global__ __launch_bounds__(256) void ref_conv_kernel(const float* __restrict__ in,
                                                       const float* __restrict__ qw,
                                                       const float* __restrict__ bb,
                                                       const float* __restrict__ addsrc,
                                                       float* __restrict__ outp,
                                                       int do_relu) {
    __shared__ float tile[324];
    __shared__ float wsm[81];
    __shared__ float bsm[3];
    const int t = threadIdx.y * 16 + threadIdx.x;
    if (t < 81) wsm[t] = qw[t];
    if (t < 3) bsm[t] = bb[t];
    const int b = blockIdx.z;
    const int h0 = blockIdx.y * 16, w0 = blockIdx.x * 16;
    const int h = h0 + threadIdx.y, w = w0 + threadIdx.x;
    float acc[3] = {0.f, 0.f, 0.f};
    for (int ci = 0; ci < 3; ci++) {
        __syncthreads();
        const float* ibp = in + ((size_t)b * 3 + ci) * HW2;
        for (int i = t; i < 324; i += 256) {
            int ty = i / 18, tx = i - ty * 18;
            int hh = h0 + ty - 1, ww = w0 + tx - 1;
            tile[i] = (hh >= 0 && hh < 512 && ww >= 0 && ww < 512) ? ibp[hh * 512 + ww] : 0.f;
        }
        __syncthreads();
        float tp[9];
#pragma unroll
        for (int dy = 0; dy < 3; dy++)
#pragma unroll
            for (int dx = 0; dx < 3; dx++)
                tp[dy * 3 + dx] = tile[(threadIdx.y + dy) * 18 + threadIdx.x + dx];
#pragma unroll
        for (int o = 0; o < 3; o++) {
            const float* wo = &wsm[o * 27 + ci * 9];
            float a = acc[o];
#pragma unroll
            for (int k = 0; k < 9; k++) a = fmaf(tp[k], wo[k], a);
            acc[o] = a;
        }
    }
#pragma unroll
    for (int o = 0; o < 3; o++) {
        float v = acc[o] + bsm[o];
        if (do_relu) v = fmaxf(v, 0.f);
        if (addsrc) v += addsrc[((size_t)b * 3 + o) * HW2 + h * 512 + w];
        outp[((size_t)b * 3 + o) * HW2 + h * 512 + w] = v;
    }
}

// ---------------------------------------------------------------- launcher
extern "C" void kernel_launch(void* const* d_in, const int* in_sizes, int n_in,
                              void* d_out, int out_size, void* d_ws, size_t ws_size,
                              hipStream_t stream) {
    const float* x         = (const float*)d_in[0];
    const float* shallow_w = (const float*)d_in[1];
    const float* shallow_b = (const float*)d_in[2];
    const float* tex_dw_w  = (const float*)d_in[3];
    const float* tex_dw_b  = (const float*)d_in[4];
    const float* tex_pw_w  = (const float*)d_in[5];
    const float* tex_pw_b  = (const float*)d_in[6];
    const float* router_w  = (const float*)d_in[7];
    const float* router_b  = (const float*)d_in[8];
    const float* exp_dw_w  = (const float*)d_in[9];
    const float* exp_dw_b  = (const float*)d_in[10];
    const float* exp_pw_w  = (const float*)d_in[11];
    const float* exp_pw_b  = (const float*)d_in[12];
    const float* exp_fc1   = (const float*)d_in[13];
    const float* exp_fc2   = (const float*)d_in[14];
    const float* recon_w   = (const float*)d_in[15];
    const float* recon_b   = (const float*)d_in[16];
    const float* ref1_w    = (const float*)d_in[17];
    const float* ref1_b    = (const float*)d_in[18];
    const float* ref2_w    = (const float*)d_in[19];
    const float* ref2_b    = (const float*)d_in[20];

    // workspace (~193 MB)
    float*  feat   = (float*)d_ws;                     // BCHW fp32 NCHW (64 MB)
    __half* feat_h = (__half*)(feat + BCHW);           // NHWC half (32 MB)
    __half* A      = feat_h + BCHW;                    // NHWC half (32 MB)
    __half* Bv     = A + BCHW;                         // NHWC half (32 MB)
    __half* M      = Bv + BCHW;                        // NHWC half (32 MB)
    int*    top    = (int*)(M + BCHW);                 // 1 MB
    float*  qb     = (float*)(top + 262144);
    float*  q_sh   = qb;                 // 1728
    float*  q_tdw  = q_sh + 1728;        // 576
    float*  q_tpw  = q_tdw + 576;        // 512
    float*  q_edw  = q_tpw + 512;        // 8*576
    float*  q_epw  = q_edw + 4608;       // 8*4096
    float*  q_r1   = q_epw + 32768;      // 81
    float*  q_r2   = q_r1 + 81;          // 81
    float*  chans  = q_r2 + 81;          // 8*256
    float*  sr     = (float*)A;          // alias: recon output (12 MB), A dead by then
    float*  t1     = (float*)Bv;         // alias

    hipMemsetAsync(chans, 0, 2048 * sizeof(float), stream);

    TernArgs ta;
    ta.d[0] = { shallow_w, q_sh, 1728 };
    ta.d[1] = { tex_dw_w, q_tdw, 576 };
    ta.d[2] = { tex_pw_w, q_tpw, 512 };
    for (int i = 0; i < 8; i++) ta.d[3 + i]  = { exp_dw_w + i * 576,  q_edw + i * 576,  576 };
    for (int i = 0; i < 8; i++) ta.d[11 + i] = { exp_pw_w + i * 4096, q_epw + i * 4096, 4096 };
    ta.d[19] = { ref1_w, q_r1, 81 };
    ta.d[20] = { ref2_w, q_r2, 81 };
    ternarize_kernel<<<21, 256, 0, stream>>>(ta);

    shallow_kernel<<<dim3(16, 16, 4), dim3(16, 16), 0, stream>>>(x, q_sh, shallow_b, feat, feat_h);
    router_kernel<<<dim3(16, 32, 4), 256, 0, stream>>>(
        feat, q_tdw, tex_dw_b, q_tpw, tex_pw_b, router_w, router_b, top);

    for (int e = 0; e < 4; e++) {
        const int i0 = e * 2, i1 = e * 2 + 1;
        expert_block_kernel<<<dim3(16, 16, 4), 256, 0, stream>>>(
            feat_h, q_edw + i0 * 576, exp_dw_b + i0 * 64, q_epw + i0 * 4096, exp_pw_b + i0 * 64,
            A, chans + i0 * 256);
        apply_kernel<<<8192, 256, 0, stream>>>(A, chans + i0 * 256, exp_fc1 + i0 * 1024,
                                               exp_fc2 + i0 * 1024, feat_h);
        expert_block_kernel<<<dim3(16, 16, 4), 256, 0, stream>>>(
            A, q_edw + i1 * 576, exp_dw_b + i1 * 64, q_epw + i1 * 4096, exp_pw_b + i1 * 64,
            Bv, chans + i1 * 256);
        select_kernel<<<8192, 256, 0, stream>>>(Bv, chans + i1 * 256, exp_fc1 + i1 * 1024,
                                                exp_fc2 + i1 * 1024, A, top, M, e);
    }

    recon_kernel<<<dim3(16, 16, 4), 256, 0, stream>>>(M, recon_w, recon_b, x, sr);
    ref_conv_kernel<<<dim3(32, 32, 4), dim3(16, 16), 0, stream>>>(sr, q_r1, ref1_b, nullptr, t1, 1);
    ref_conv_kernel<<<dim3(32, 32, 4), dim3(16, 16), 0, stream>>>(t1, q_r2, ref2_b, sr, (float*)d_out, 0);
}

// Round 5
// 1120.040 us; speedup vs baseline: 3.0799x; 1.1361x over previous
//
#include <hip/hip_runtime.h>
#include <hip/hip_fp16.h>
#include <math.h>

#define HW 65536            // 256*256
#define CHW 4194304         // 64*HW  (NHWC elements per batch)
#define BCHW 16777216
#define HW2 262144          // 512*512

typedef _Float16 half8 __attribute__((ext_vector_type(8)));
typedef float f32x4 __attribute__((ext_vector_type(4)));

// ---------------------------------------------------------------- ternarize
struct TernDesc { const float* src; float* dst; int n; };
struct TernArgs { TernDesc d[21]; };

__global__ __launch_bounds__(256) void ternarize_kernel(TernArgs args) {
    __shared__ float red[256];
    __shared__ float bc[2];
    TernDesc td = args.d[blockIdx.x];
    const int n = td.n;
    const int t = threadIdx.x;
    float s = 0.f;
    for (int i = t; i < n; i += 256) s += fabsf(td.src[i]);
    red[t] = s; __syncthreads();
    for (int k = 128; k > 0; k >>= 1) { if (t < k) red[t] += red[t + k]; __syncthreads(); }
    if (t == 0) bc[0] = 0.75f * red[0] / (float)n;
    __syncthreads();
    const float delta = bc[0];
    float s1 = 0.f, c1 = 0.f;
    for (int i = t; i < n; i += 256) {
        float a = fabsf(td.src[i]);
        if (a > delta) { s1 += a; c1 += 1.f; }
    }
    __syncthreads();
    red[t] = s1; __syncthreads();
    for (int k = 128; k > 0; k >>= 1) { if (t < k) red[t] += red[t + k]; __syncthreads(); }
    float sum1 = red[0];
    __syncthreads();
    red[t] = c1; __syncthreads();
    for (int k = 128; k > 0; k >>= 1) { if (t < k) red[t] += red[t + k]; __syncthreads(); }
    if (t == 0) bc[1] = sum1 / fmaxf(red[0], 1.f);
    __syncthreads();
    const float alpha = bc[1];
    for (int i = t; i < n; i += 256) {
        float w = td.src[i];
        td.dst[i] = (fabsf(w) > delta) ? ((w > 0.f) ? alpha : -alpha) : 0.f;
    }
}

// ---------------------------------------------------------------- fused shallow conv + texture encoder + router
// 16x16 px tile; recomputes feat on an 18x18 halo from a 20x20 x tile.
// Writes feat_h (NHWC half) and top (argmax expert). Router path all fp32,
// identical fmaf ordering to the previous (passing) version.
__global__ __launch_bounds__(256) void shallow_router_kernel(
    const float* __restrict__ x,
    const float* __restrict__ qsh,  const float* __restrict__ shb,
    const float* __restrict__ qtdw, const float* __restrict__ tdwb,
    const float* __restrict__ qtpw, const float* __restrict__ tpwb,
    const float* __restrict__ rw,   const float* __restrict__ rbias,
    __half* __restrict__ feat_h, int* __restrict__ top) {
    __shared__ float xs[1200];          // [3][20][20]
    __shared__ float feats[324 * 33];   // [halo px][ch pad33]
    const int t = threadIdx.x;
    const int b = blockIdx.z;
    const int h0 = blockIdx.y * 16, w0 = blockIdx.x * 16;
    const float* xb = x + (size_t)b * 3 * HW;

    for (int i = t; i < 1200; i += 256) {
        const int ci = i / 400, rem = i - ci * 400;
        const int ry = rem / 20, rx = rem - ry * 20;
        const int hh = h0 + ry - 2, ww = w0 + rx - 2;
        xs[i] = (hh >= 0 && hh < 256 && ww >= 0 && ww < 256) ? xb[ci * HW + hh * 256 + ww] : 0.f;
    }
    const int iy = t >> 4, ix = t & 15;
    float tex[8] = {0, 0, 0, 0, 0, 0, 0, 0};
    __half* fhb = feat_h + (size_t)b * CHW;
    __syncthreads();

    for (int pass = 0; pass < 2; pass++) {
        const int c0 = pass * 32;
        if (pass) __syncthreads();          // feats rewrite vs prior readers
        // shallow: px-per-thread; ternary weights via uniform scalar loads
        for (int rep = 0; rep < 2; rep++) {
            const int p = t + rep * 256;
            if (p < 324) {
                const int ry = p / 18, rx = p - ry * 18;
                float patch[27];
#pragma unroll
                for (int ci = 0; ci < 3; ci++)
#pragma unroll
                    for (int dy = 0; dy < 3; dy++)
#pragma unroll
                        for (int dx = 0; dx < 3; dx++)
                            patch[ci * 9 + dy * 3 + dx] = xs[ci * 400 + (ry + dy) * 20 + rx + dx];
                for (int co = 0; co < 32; co++) {
                    const float* wp = &qsh[(c0 + co) * 27];
                    float a = shb[c0 + co];
#pragma unroll
                    for (int k = 0; k < 27; k++) a = fmaf(patch[k], wp[k], a);
                    feats[p * 33 + co] = fmaxf(a, 0.f);
                }
            }
        }
        __syncthreads();
        // feat_h writeout (interior 16x16, this pass's 32 ch)
        for (int id = t; id < 1024; id += 256) {
            const int p = id >> 2, cg = id & 3;
            const int py = p >> 4, px = p & 15;
            const float* fp = &feats[((py + 1) * 18 + px + 1) * 33 + cg * 8];
            half8 pk;
#pragma unroll
            for (int j = 0; j < 8; j++) pk[j] = (_Float16)fp[j];
            *(half8*)&fhb[((size_t)((h0 + py) * 256 + w0 + px)) * 64 + c0 + cg * 8] = pk;
        }
        // texture dw 3x3 + partial pw (this thread's interior px)
        for (int ch = 0; ch < 32; ch++) {
            const float* wp = &qtdw[(c0 + ch) * 9];
            float o = tdwb[c0 + ch];
#pragma unroll
            for (int dy = 0; dy < 3; dy++) {
                const float* rowp = &feats[((iy + dy) * 18 + ix) * 33 + ch];
                o = fmaf(rowp[0], wp[dy * 3],
                    fmaf(rowp[33], wp[dy * 3 + 1],
                        fmaf(rowp[66], wp[dy * 3 + 2], o)));
            }
            const float tc = fmaxf(o, 0.f);
#pragma unroll
            for (int j = 0; j < 8; j++) tex[j] = fmaf(qtpw[j * 64 + c0 + ch], tc, tex[j]);
        }
    }
    float sgm[8];
#pragma unroll
    for (int j = 0; j < 8; j++) sgm[j] = 1.f / (1.f + expf(-(tex[j] + tpwb[j])));
    float best = -1e30f; int bi = 0;
#pragma unroll
    for (int e = 0; e < 4; e++) {
        float v = rbias[e];
#pragma unroll
        for (int j = 0; j < 8; j++) v = fmaf(rw[e * 8 + j], sgm[j], v);
        if (v > best) { best = v; bi = e; }     // first max (jnp.argmax)
    }
    top[(size_t)b * HW + (h0 + iy) * 256 + w0 + ix] = bi;
}

// ---------------------------------------------------------------- expert block: NHWC, dw(VALU fp32) -> pw(MFMA f16)
// APPLY: staged input = in*y + F (channel attention of the PREVIOUS block,
// computed in-block from csprev); applied interior written back to Aap.
template <bool APPLY>
__global__ __launch_bounds__(256, 3) void expert_block_kernel(const __half* __restrict__ in,
                                                              const float* __restrict__ qdw,
                                                              const float* __restrict__ dwb,
                                                              const float* __restrict__ qpw,
                                                              const float* __restrict__ pwb,
                                                              __half* __restrict__ out,
                                                              float* __restrict__ chansum,
                                                              const float* __restrict__ csprev,
                                                              const float* __restrict__ fc1,
                                                              const float* __restrict__ fc2,
                                                              const __half* __restrict__ F,
                                                              __half* __restrict__ Aap) {
    __shared__ __half tile[4 * 324 * 8];   // [cg][ry*18+rx][8ci] 20736 B
    __shared__ __half wT[64 * 72];         // [co][ci pad72] 9216 B
    __shared__ __half wdwh[9 * 64];        // [tap][ci] 1152 B
    __shared__ float bdw[64];
    __shared__ float bpw[64];
    __shared__ __half obuf[4 * 1088];      // per-wave store staging [col 16][co pad68]
    __shared__ float hid[16];
    __shared__ float ysm[64];
    const int t = threadIdx.x;
    const int b = blockIdx.z;
    const int h0 = blockIdx.y * 16, w0 = blockIdx.x * 16;

    for (int i = t; i < 4096; i += 256) wT[(i >> 6) * 72 + (i & 63)] = __float2half(qpw[i]);
    for (int i = t; i < 576; i += 256) {
        const int ci = i / 9, tap = i - ci * 9;
        wdwh[tap * 64 + ci] = __float2half(qdw[i]);
    }
    if (t < 64) { bdw[t] = dwb[t]; bpw[t] = pwb[t]; }

    if (APPLY) {
        if (t < 16) {
            float a = 0.f;
            for (int ci = 0; ci < 64; ci++) a = fmaf(fc1[t * 64 + ci], csprev[b * 64 + ci], a);
            hid[t] = fmaxf(a, 0.f) * (1.f / 65536.f);
        }
        __syncthreads();
        if (t < 64) {
            float a = 0.f;
#pragma unroll
            for (int j = 0; j < 16; j++) a = fmaf(fc2[t * 16 + j], hid[j], a);
            ysm[t] = 1.f / (1.f + expf(-a));
        }
    }

    const int lane = t & 63, wv = t >> 6;
    const int l15 = lane & 15, quad = lane >> 4;
    f32x4 acc[4][4];
#pragma unroll
    for (int i = 0; i < 4; i++)
#pragma unroll
        for (int j = 0; j < 4; j++) acc[i][j] = (f32x4){0.f, 0.f, 0.f, 0.f};

    const __half* ib = in + (size_t)b * CHW;
    const __half* Fb = APPLY ? (F + (size_t)b * CHW) : nullptr;
    __half* Ab = APPLY ? (Aap + (size_t)b * CHW) : nullptr;

    for (int pass = 0; pass < 2; pass++) {
        __syncthreads();
        // stage 32 ci of the 18x18 halo ([cg][px][8]); optional apply+writeback
        for (int i = t; i < 1296; i += 256) {
            const int cg = i & 3;
            const int rem = i >> 2;
            const int ry = rem / 18, rx = rem - ry * 18;
            const int hh = h0 + ry - 1, ww = w0 + rx - 1;
            half8 v = {};
            if (hh >= 0 && hh < 256 && ww >= 0 && ww < 256) {
                const size_t off = (size_t)(hh * 256 + ww) * 64 + pass * 32 + cg * 8;
                v = *(const half8*)&ib[off];
                if (APPLY) {
                    half8 f = *(const half8*)&Fb[off];
#pragma unroll
                    for (int j = 0; j < 8; j++)
                        v[j] = (_Float16)fmaf((float)v[j], ysm[pass * 32 + cg * 8 + j], (float)f[j]);
                    if (ry >= 1 && ry <= 16 && rx >= 1 && rx <= 16)
                        *(half8*)&Ab[off] = v;
                }
            }
            *(half8*)&tile[(cg * 324 + rem) * 8] = v;
        }
        __syncthreads();
        // B fragments: B[k=ci][n=co]
        half8 bf[4];
#pragma unroll
        for (int ct = 0; ct < 4; ct++)
            bf[ct] = *(const half8*)&wT[(ct * 16 + l15) * 72 + pass * 32 + quad * 8];
        half8 wv9[9];
#pragma unroll
        for (int tap = 0; tap < 9; tap++)
            wv9[tap] = *(const half8*)&wdwh[tap * 64 + pass * 32 + quad * 8];
        float bias8[8];
#pragma unroll
        for (int j = 0; j < 8; j++) bias8[j] = bdw[pass * 32 + quad * 8 + j];
#pragma unroll
        for (int T = 0; T < 4; T++) {
            const int py = wv * 4 + T;
            half8 xv[9];
#pragma unroll
            for (int dy = 0; dy < 3; dy++)
#pragma unroll
                for (int dx = 0; dx < 3; dx++)
                    xv[dy * 3 + dx] = *(const half8*)&tile[(quad * 324 + (py + dy) * 18 + (l15 + dx)) * 8];
            float o[8];
#pragma unroll
            for (int j = 0; j < 8; j++) o[j] = bias8[j];
#pragma unroll
            for (int tap = 0; tap < 9; tap++)
#pragma unroll
                for (int j = 0; j < 8; j++)
                    o[j] = fmaf((float)xv[tap][j], (float)wv9[tap][j], o[j]);
            half8 a;
#pragma unroll
            for (int j = 0; j < 8; j++) a[j] = (_Float16)fmaxf(o[j], 0.f);
#pragma unroll
            for (int ct = 0; ct < 4; ct++)
                acc[T][ct] = __builtin_amdgcn_mfma_f32_16x16x32_f16(a, bf[ct], acc[T][ct], 0, 0, 0);
        }
    }
    // epilogue: per-wave LDS transpose -> coalesced 16B stores (one 16px x 64ch row per T)
    __half* ob = out + (size_t)b * CHW;
    __half* myo = &obuf[wv * 1088];
    float cs[4] = {0.f, 0.f, 0.f, 0.f};
#pragma unroll
    for (int T = 0; T < 4; T++) {
#pragma unroll
        for (int ct = 0; ct < 4; ct++) {
            const float bv = bpw[ct * 16 + l15];
#pragma unroll
            for (int r = 0; r < 4; r++) {
                const float v = acc[T][ct][r] + bv;
                cs[ct] += v;
                myo[(quad * 4 + r) * 68 + ct * 16 + l15] = __float2half(v);
            }
        }
        const int py = h0 + wv * 4 + T;
        const size_t base = (size_t)(py * 256 + w0) * 64;
        half8 v0 = *(const half8*)&myo[(lane >> 3) * 68 + (lane & 7) * 8];
        *(half8*)&ob[base + lane * 8] = v0;
        half8 v1 = *(const half8*)&myo[(8 + (lane >> 3)) * 68 + (lane & 7) * 8];
        *(half8*)&ob[base + (lane + 64) * 8] = v1;
    }
#pragma unroll
    for (int ct = 0; ct < 4; ct++) {
        float s = cs[ct];
        s += __shfl_xor(s, 16);
        s += __shfl_xor(s, 32);
        if (quad == 0) atomicAdd(&chansum[b * 64 + ct * 16 + l15], s);
    }
}

// ---------------------------------------------------------------- select: M = B*y + Aap where top==e (NHWC), attention fused
__global__ __launch_bounds__(256) void select_kernel(const __half* __restrict__ Bv,
                                                     const float* __restrict__ chansum,
                                                     const float* __restrict__ fc1,
                                                     const float* __restrict__ fc2,
                                                     const __half* __restrict__ A,
                                                     const int* __restrict__ top,
                                                     __half* __restrict__ M, int e) {
    __shared__ float hid[16];
    __shared__ float ysm[64];
    const int t = threadIdx.x;
    const int i8 = blockIdx.x * 256 + t;
    const int ei = i8 << 3;
    const int b = ei >> 22;
    if (t < 16) {
        float a = 0.f;
        for (int ci = 0; ci < 64; ci++) a = fmaf(fc1[t * 64 + ci], chansum[b * 64 + ci], a);
        hid[t] = fmaxf(a, 0.f) * (1.f / 65536.f);
    }
    __syncthreads();
    if (t < 64) {
        float a = 0.f;
#pragma unroll
        for (int j = 0; j < 16; j++) a = fmaf(fc2[t * 16 + j], hid[j], a);
        ysm[t] = 1.f / (1.f + expf(-a));
    }
    __syncthreads();
    const int px = ei >> 6;
    if (top[px] != e) return;
    const int c0 = ei & 63;
    float4 bv4 = ((const float4*)Bv)[i8];
    float4 av4 = ((const float4*)A)[i8];
    const __half2* bh = (const __half2*)&bv4;
    const __half2* ah = (const __half2*)&av4;
    __half2 outv[4];
#pragma unroll
    for (int j = 0; j < 4; j++) {
        const float2 b2 = __half22float2(bh[j]);
        const float2 a2 = __half22float2(ah[j]);
        outv[j] = __floats2half2_rn(fmaf(b2.x, ysm[c0 + 2 * j], a2.x),
                                    fmaf(b2.y, ysm[c0 + 2 * j + 1], a2.y));
    }
    ((float4*)M)[i8] = *(float4*)outv;
}

// ---------------------------------------------------------------- bilinear x2 upsample (jax.image.resize semantics)
__device__ __forceinline__ float bilin_up(const float* __restrict__ xb, int h, int w, int r1, int r2) {
    int hlo, hhi; float wrr;
    if (r1 == 0) { hlo = h - 1; hhi = h;     wrr = 0.25f; }
    else         { hlo = h;     hhi = h + 1; wrr = 0.75f; }
    if (hlo < 0)   { hlo = 0;   wrr = 0.f; }
    if (hhi > 255) { hhi = 255; wrr = 1.f; }
    int wlo, whi; float wcc;
    if (r2 == 0) { wlo = w - 1; whi = w;     wcc = 0.25f; }
    else         { wlo = w;     whi = w + 1; wcc = 0.75f; }
    if (wlo < 0)   { wlo = 0;   wcc = 0.f; }
    if (whi > 255) { whi = 255; wcc = 1.f; }
    const float a = xb[hlo * 256 + wlo] * wcc + xb[hlo * 256 + whi] * (1.f - wcc);
    const float b = xb[hhi * 256 + wlo] * wcc + xb[hhi * 256 + whi] * (1.f - wcc);
    return a * wrr + b * (1.f - wrr);
}

// ---------------------------------------------------------------- recon: 9 shifted MFMA GEMMs + pixel shuffle + x_up
__global__ __launch_bounds__(256, 3) void recon_kernel(const __half* __restrict__ moe,   // NHWC
                                                       const float* __restrict__ rw,     // [12][64][9]
                                                       const float* __restrict__ rbias,
                                                       const float* __restrict__ x,
                                                       float* __restrict__ sr) {
    __shared__ __half tile[4 * 324 * 8];
    __shared__ __half Wt[9 * 16 * 72];
    __shared__ float bsm12[12];
    const int t = threadIdx.x;
    const int b = blockIdx.z;
    const int h0 = blockIdx.y * 16, w0 = blockIdx.x * 16;

    for (int i = t; i < 9216; i += 256) {
        const int tap = i / 1024, rem = i - tap * 1024;
        const int n = rem >> 6, ci = rem & 63;
        Wt[(tap * 16 + n) * 72 + ci] = __float2half(n < 12 ? rw[n * 576 + ci * 9 + tap] : 0.f);
    }
    if (t < 12) bsm12[t] = rbias[t];

    const int lane = t & 63, wvi = t >> 6;
    const int l15 = lane & 15, quad = lane >> 4;
    f32x4 acc[4];
#pragma unroll
    for (int i = 0; i < 4; i++) acc[i] = (f32x4){0.f, 0.f, 0.f, 0.f};

    const __half* mb = moe + (size_t)b * CHW;

    for (int pass = 0; pass < 2; pass++) {
        __syncthreads();
        for (int i = t; i < 1296; i += 256) {
            const int cg = i & 3;
            const int rem = i >> 2;
            const int ry = rem / 18, rx = rem - ry * 18;
            const int hh = h0 + ry - 1, ww = w0 + rx - 1;
            half8 v = {};
            if (hh >= 0 && hh < 256 && ww >= 0 && ww < 256)
                v = *(const half8*)&mb[(size_t)(hh * 256 + ww) * 64 + pass * 32 + cg * 8];
            *(half8*)&tile[(cg * 324 + rem) * 8] = v;
        }
        __syncthreads();
        half8 bf[9];
#pragma unroll
        for (int tap = 0; tap < 9; tap++)
            bf[tap] = *(const half8*)&Wt[(tap * 16 + l15) * 72 + pass * 32 + quad * 8];
#pragma unroll
        for (int T = 0; T < 4; T++) {
            const int py = wvi * 4 + T;
#pragma unroll
            for (int dy = 0; dy < 3; dy++)
#pragma unroll
                for (int dx = 0; dx < 3; dx++) {
                    half8 a = *(const half8*)&tile[(quad * 324 + (py + dy) * 18 + (l15 + dx)) * 8];
                    acc[T] = __builtin_amdgcn_mfma_f32_16x16x32_f16(a, bf[dy * 3 + dx], acc[T], 0, 0, 0);
                }
        }
    }
    if (l15 < 12) {
        const int c = l15 >> 2, r1 = (l15 >> 1) & 1, r2 = l15 & 1;
        const float* xb = x + ((size_t)b * 3 + c) * HW;
        const float bv = bsm12[l15];
        float* sb = sr + ((size_t)b * 3 + c) * HW2;
#pragma unroll
        for (int T = 0; T < 4; T++) {
            const int py = h0 + wvi * 4 + T;
#pragma unroll
            for (int r = 0; r < 4; r++) {
                const int wglob = w0 + quad * 4 + r;
                const float xu = bilin_up(xb, py, wglob, r1, r2);
                sb[(2 * py + r1) * 512 + 2 * wglob + r2] = acc[T][r] + bv + xu;
            }
        }
    }
}

// ---------------------------------------------------------------- 3x3 conv on [4][3][512][512] (refinement)
__global__ __launch_bounds__(256) void ref_conv_kernel(const float* __restrict__ in,
                                                       const float* __restrict__ qw,
                                                       const float* __restrict__ bb,
                                                       const float* __restrict__ addsrc,
                                                       float* __restrict__ outp,
                                                       int do_relu) {
    __shared__ float tile[324];
    __shared__ float wsm[81];
    __shared__ float bsm[3];
    const int t = threadIdx.y * 16 + threadIdx.x;
    if (t < 81) wsm[t] = qw[t];
    if (t < 3) bsm[t] = bb[t];
    const int b = blockIdx.z;
    const int h0 = blockIdx.y * 16, w0 = blockIdx.x * 16;
    const int h = h0 + threadIdx.y, w = w0 + threadIdx.x;
    float acc[3] = {0.f, 0.f, 0.f};
    for (int ci = 0; ci < 3; ci++) {
        __syncthreads();
        const float* ibp = in + ((size_t)b * 3 + ci) * HW2;
        for (int i = t; i < 324; i += 256) {
            int ty = i / 18, tx = i - ty * 18;
            int hh = h0 + ty - 1, ww = w0 + tx - 1;
            tile[i] = (hh >= 0 && hh < 512 && ww >= 0 && ww < 512) ? ibp[hh * 512 + ww] : 0.f;
        }
        __syncthreads();
        float tp[9];
#pragma unroll
        for (int dy = 0; dy < 3; dy++)
#pragma unroll
            for (int dx = 0; dx < 3; dx++)
                tp[dy * 3 + dx] = tile[(threadIdx.y + dy) * 18 + threadIdx.x + dx];
#pragma unroll
        for (int o = 0; o < 3; o++) {
            const float* wo = &wsm[o * 27 + ci * 9];
            float a = acc[o];
#pragma unroll
            for (int k = 0; k < 9; k++) a = fmaf(tp[k], wo[k], a);
            acc[o] = a;
        }
    }
#pragma unroll
    for (int o = 0; o < 3; o++) {
        float v = acc[o] + bsm[o];
        if (do_relu) v = fmaxf(v, 0.f);
        if (addsrc) v += addsrc[((size_t)b * 3 + o) * HW2 + h * 512 + w];
        outp[((size_t)b * 3 + o) * HW2 + h * 512 + w] = v;
    }
}

// ---------------------------------------------------------------- launcher
extern "C" void kernel_launch(void* const* d_in, const int* in_sizes, int n_in,
                              void* d_out, int out_size, void* d_ws, size_t ws_size,
                              hipStream_t stream) {
    const float* x         = (const float*)d_in[0];
    const float* shallow_w = (const float*)d_in[1];
    const float* shallow_b = (const float*)d_in[2];
    const float* tex_dw_w  = (const float*)d_in[3];
    const float* tex_dw_b  = (const float*)d_in[4];
    const float* tex_pw_w  = (const float*)d_in[5];
    const float* tex_pw_b  = (const float*)d_in[6];
    const float* router_w  = (const float*)d_in[7];
    const float* router_b  = (const float*)d_in[8];
    const float* exp_dw_w  = (const float*)d_in[9];
    const float* exp_dw_b  = (const float*)d_in[10];
    const float* exp_pw_w  = (const float*)d_in[11];
    const float* exp_pw_b  = (const float*)d_in[12];
    const float* exp_fc1   = (const float*)d_in[13];
    const float* exp_fc2   = (const float*)d_in[14];
    const float* recon_w   = (const float*)d_in[15];
    const float* recon_b   = (const float*)d_in[16];
    const float* ref1_w    = (const float*)d_in[17];
    const float* ref1_b    = (const float*)d_in[18];
    const float* ref2_w    = (const float*)d_in[19];
    const float* ref2_b    = (const float*)d_in[20];

    // workspace (~162 MB): 5 half NHWC buffers + top + weights
    __half* feat_h = (__half*)d_ws;          // 32 MB
    __half* A      = feat_h + BCHW;          // raw block-1 output
    __half* Aap    = A + BCHW;               // applied (A*y + feat)
    __half* Bv     = Aap + BCHW;             // block-2 output
    __half* M      = Bv + BCHW;              // routed MoE output
    int*    top    = (int*)(M + BCHW);       // 1 MB
    float*  qb     = (float*)(top + 262144);
    float*  q_sh   = qb;                 // 1728
    float*  q_tdw  = q_sh + 1728;        // 576
    float*  q_tpw  = q_tdw + 576;        // 512
    float*  q_edw  = q_tpw + 512;        // 8*576
    float*  q_epw  = q_edw + 4608;       // 8*4096
    float*  q_r1   = q_epw + 32768;      // 81
    float*  q_r2   = q_r1 + 81;          // 81
    float*  chans  = q_r2 + 81;          // 8*256
    float*  sr     = (float*)A;          // alias: A dead after expert3 block2
    float*  t1     = (float*)Aap;        // alias: Aap dead after select3

    hipMemsetAsync(chans, 0, 2048 * sizeof(float), stream);

    TernArgs ta;
    ta.d[0] = { shallow_w, q_sh, 1728 };
    ta.d[1] = { tex_dw_w, q_tdw, 576 };
    ta.d[2] = { tex_pw_w, q_tpw, 512 };
    for (int i = 0; i < 8; i++) ta.d[3 + i]  = { exp_dw_w + i * 576,  q_edw + i * 576,  576 };
    for (int i = 0; i < 8; i++) ta.d[11 + i] = { exp_pw_w + i * 4096, q_epw + i * 4096, 4096 };
    ta.d[19] = { ref1_w, q_r1, 81 };
    ta.d[20] = { ref2_w, q_r2, 81 };
    ternarize_kernel<<<21, 256, 0, stream>>>(ta);

    shallow_router_kernel<<<dim3(16, 16, 4), 256, 0, stream>>>(
        x, q_sh, shallow_b, q_tdw, tex_dw_b, q_tpw, tex_pw_b, router_w, router_b,
        feat_h, top);

    for (int e = 0; e < 4; e++) {
        const int i0 = e * 2, i1 = e * 2 + 1;
        expert_block_kernel<false><<<dim3(16, 16, 4), 256, 0, stream>>>(
            feat_h, q_edw + i0 * 576, exp_dw_b + i0 * 64, q_epw + i0 * 4096, exp_pw_b + i0 * 64,
            A, chans + i0 * 256, nullptr, nullptr, nullptr, nullptr, nullptr);
        expert_block_kernel<true><<<dim3(16, 16, 4), 256, 0, stream>>>(
            A, q_edw + i1 * 576, exp_dw_b + i1 * 64, q_epw + i1 * 4096, exp_pw_b + i1 * 64,
            Bv, chans + i1 * 256,
            chans + i0 * 256, exp_fc1 + i0 * 1024, exp_fc2 + i0 * 1024, feat_h, Aap);
        select_kernel<<<8192, 256, 0, stream>>>(Bv, chans + i1 * 256, exp_fc1 + i1 * 1024,
                                                exp_fc2 + i1 * 1024, Aap, top, M, e);
    }

    recon_kernel<<<dim3(16, 16, 4), 256, 0, stream>>>(M, recon_w, recon_b, x, sr);
    ref_conv_kernel<<<dim3(32, 32, 4), dim3(16, 16), 0, stream>>>(sr, q_r1, ref1_b, nullptr, t1, 1);
    ref_conv_kernel<<<dim3(32, 32, 4), dim3(16, 16), 0, stream>>>(t1, q_r2, ref2_b, sr, (float*)d_out, 0);
}

// Round 6
// 929.093 us; speedup vs baseline: 3.7129x; 1.2055x over previous
//
#include <hip/hip_runtime.h>
#include <hip/hip_fp16.h>
#include <math.h>

#define HW 65536            // 256*256
#define CHW 4194304         // 64*HW  (NHWC elements per batch)
#define BCHW 16777216
#define HW2 262144          // 512*512

typedef _Float16 half8 __attribute__((ext_vector_type(8)));
typedef float f32x4 __attribute__((ext_vector_type(4)));

// ---------------------------------------------------------------- ternarize
struct TernDesc { const float* src; float* dst; int n; };
struct TernArgs { TernDesc d[21]; };

__global__ __launch_bounds__(256) void ternarize_kernel(TernArgs args) {
    __shared__ float red[256];
    __shared__ float bc[2];
    TernDesc td = args.d[blockIdx.x];
    const int n = td.n;
    const int t = threadIdx.x;
    float s = 0.f;
    for (int i = t; i < n; i += 256) s += fabsf(td.src[i]);
    red[t] = s; __syncthreads();
    for (int k = 128; k > 0; k >>= 1) { if (t < k) red[t] += red[t + k]; __syncthreads(); }
    if (t == 0) bc[0] = 0.75f * red[0] / (float)n;
    __syncthreads();
    const float delta = bc[0];
    float s1 = 0.f, c1 = 0.f;
    for (int i = t; i < n; i += 256) {
        float a = fabsf(td.src[i]);
        if (a > delta) { s1 += a; c1 += 1.f; }
    }
    __syncthreads();
    red[t] = s1; __syncthreads();
    for (int k = 128; k > 0; k >>= 1) { if (t < k) red[t] += red[t + k]; __syncthreads(); }
    float sum1 = red[0];
    __syncthreads();
    red[t] = c1; __syncthreads();
    for (int k = 128; k > 0; k >>= 1) { if (t < k) red[t] += red[t + k]; __syncthreads(); }
    if (t == 0) bc[1] = sum1 / fmaxf(red[0], 1.f);
    __syncthreads();
    const float alpha = bc[1];
    for (int i = t; i < n; i += 256) {
        float w = td.src[i];
        td.dst[i] = (fabsf(w) > delta) ? ((w > 0.f) ? alpha : -alpha) : 0.f;
    }
}

// ---------------------------------------------------------------- fused shallow conv + texture encoder + router
__global__ __launch_bounds__(256) void shallow_router_kernel(
    const float* __restrict__ x,
    const float* __restrict__ qsh,  const float* __restrict__ shb,
    const float* __restrict__ qtdw, const float* __restrict__ tdwb,
    const float* __restrict__ qtpw, const float* __restrict__ tpwb,
    const float* __restrict__ rw,   const float* __restrict__ rbias,
    __half* __restrict__ feat_h, int* __restrict__ top) {
    __shared__ float xs[1200];          // [3][20][20]
    __shared__ float feats[324 * 33];   // [halo px][ch pad33]
    const int t = threadIdx.x;
    const int b = blockIdx.z;
    const int h0 = blockIdx.y * 16, w0 = blockIdx.x * 16;
    const float* xb = x + (size_t)b * 3 * HW;

    for (int i = t; i < 1200; i += 256) {
        const int ci = i / 400, rem = i - ci * 400;
        const int ry = rem / 20, rx = rem - ry * 20;
        const int hh = h0 + ry - 2, ww = w0 + rx - 2;
        xs[i] = (hh >= 0 && hh < 256 && ww >= 0 && ww < 256) ? xb[ci * HW + hh * 256 + ww] : 0.f;
    }
    const int iy = t >> 4, ix = t & 15;
    float tex[8] = {0, 0, 0, 0, 0, 0, 0, 0};
    __half* fhb = feat_h + (size_t)b * CHW;
    __syncthreads();

    for (int pass = 0; pass < 2; pass++) {
        const int c0 = pass * 32;
        if (pass) __syncthreads();
        for (int rep = 0; rep < 2; rep++) {
            const int p = t + rep * 256;
            if (p < 324) {
                const int ry = p / 18, rx = p - ry * 18;
                float patch[27];
#pragma unroll
                for (int ci = 0; ci < 3; ci++)
#pragma unroll
                    for (int dy = 0; dy < 3; dy++)
#pragma unroll
                        for (int dx = 0; dx < 3; dx++)
                            patch[ci * 9 + dy * 3 + dx] = xs[ci * 400 + (ry + dy) * 20 + rx + dx];
                for (int co = 0; co < 32; co++) {
                    const float* wp = &qsh[(c0 + co) * 27];
                    float a = shb[c0 + co];
#pragma unroll
                    for (int k = 0; k < 27; k++) a = fmaf(patch[k], wp[k], a);
                    feats[p * 33 + co] = fmaxf(a, 0.f);
                }
            }
        }
        __syncthreads();
        for (int id = t; id < 1024; id += 256) {
            const int p = id >> 2, cg = id & 3;
            const int py = p >> 4, px = p & 15;
            const float* fp = &feats[((py + 1) * 18 + px + 1) * 33 + cg * 8];
            half8 pk;
#pragma unroll
            for (int j = 0; j < 8; j++) pk[j] = (_Float16)fp[j];
            *(half8*)&fhb[((size_t)((h0 + py) * 256 + w0 + px)) * 64 + c0 + cg * 8] = pk;
        }
        for (int ch = 0; ch < 32; ch++) {
            const float* wp = &qtdw[(c0 + ch) * 9];
            float o = tdwb[c0 + ch];
#pragma unroll
            for (int dy = 0; dy < 3; dy++) {
                const float* rowp = &feats[((iy + dy) * 18 + ix) * 33 + ch];
                o = fmaf(rowp[0], wp[dy * 3],
                    fmaf(rowp[33], wp[dy * 3 + 1],
                        fmaf(rowp[66], wp[dy * 3 + 2], o)));
            }
            const float tc = fmaxf(o, 0.f);
#pragma unroll
            for (int j = 0; j < 8; j++) tex[j] = fmaf(qtpw[j * 64 + c0 + ch], tc, tex[j]);
        }
    }
    float sgm[8];
#pragma unroll
    for (int j = 0; j < 8; j++) sgm[j] = 1.f / (1.f + expf(-(tex[j] + tpwb[j])));
    float best = -1e30f; int bi = 0;
#pragma unroll
    for (int e = 0; e < 4; e++) {
        float v = rbias[e];
#pragma unroll
        for (int j = 0; j < 8; j++) v = fmaf(rw[e * 8 + j], sgm[j], v);
        if (v > best) { best = v; bi = e; }     // first max (jnp.argmax)
    }
    top[(size_t)b * HW + (h0 + iy) * 256 + w0 + ix] = bi;
}

// ---------------------------------------------------------------- expert block, 2 experts per dispatch (grid z = b + 4*sub)
// APPLY=false (block1): in=feat_h, out=Apair[sub] dense.
// APPLY=true  (block2): in=Apair[sub] (apply y0 during staging), out=Bv_sh
//   routed-only; applied staged value written routed-only to Aap_sh.
template <bool APPLY>
__global__ __launch_bounds__(256, 3) void expert_block_kernel(
    const __half* __restrict__ in,
    const float* __restrict__ qdw_b, const float* __restrict__ dwb_b,
    const float* __restrict__ qpw_b, const float* __restrict__ pwb_b,
    __half* __restrict__ out_b, float* __restrict__ chans_b,
    const float* __restrict__ fc1_b, const float* __restrict__ fc2_b,
    const __half* __restrict__ F, __half* __restrict__ Aap,
    const int* __restrict__ topg, int superstep) {
    __shared__ __half tile[4 * 324 * 8];   // [cg][ry*18+rx][8ci]
    __shared__ __half wT[64 * 72];         // [co][ci pad72]
    __shared__ __half wdwh[9 * 64];        // [tap][ci]
    __shared__ float bdw[64];
    __shared__ float bpw[64];
    __shared__ __half obuf[4 * 1088];      // per-wave [px 16][co pad68]
    __shared__ float hid[16];
    __shared__ float ysm[64];
    __shared__ unsigned char topsm[256];
    const int t = threadIdx.x;
    const int z = blockIdx.z;
    const int b = z & 3, sub = z >> 2;
    const int expert = superstep * 2 + sub;
    const int layer = expert * 2 + (APPLY ? 1 : 0);
    const float* qdw = qdw_b + layer * 576;
    const float* dwb = dwb_b + layer * 64;
    const float* qpw = qpw_b + layer * 4096;
    const float* pwb = pwb_b + layer * 64;
    float* chansum = chans_b + layer * 256;
    const int h0 = blockIdx.y * 16, w0 = blockIdx.x * 16;

    for (int i = t; i < 4096; i += 256) wT[(i >> 6) * 72 + (i & 63)] = __float2half(qpw[i]);
    for (int i = t; i < 576; i += 256) {
        const int ci = i / 9, tap = i - ci * 9;
        wdwh[tap * 64 + ci] = __float2half(qdw[i]);
    }
    if (t < 64) { bdw[t] = dwb[t]; bpw[t] = pwb[t]; }

    if (APPLY) {
        topsm[t] = (unsigned char)topg[(size_t)b * HW + (h0 + (t >> 4)) * 256 + w0 + (t & 15)];
        const float* cs0 = chans_b + (expert * 2) * 256;
        const float* fc1 = fc1_b + (expert * 2) * 1024;
        const float* fc2 = fc2_b + (expert * 2) * 1024;
        if (t < 16) {
            float a = 0.f;
            for (int ci = 0; ci < 64; ci++) a = fmaf(fc1[t * 64 + ci], cs0[b * 64 + ci], a);
            hid[t] = fmaxf(a, 0.f) * (1.f / 65536.f);
        }
        __syncthreads();
        if (t < 64) {
            float a = 0.f;
#pragma unroll
            for (int j = 0; j < 16; j++) a = fmaf(fc2[t * 16 + j], hid[j], a);
            ysm[t] = 1.f / (1.f + expf(-a));
        }
    }

    const int lane = t & 63, wv = t >> 6;
    const int l15 = lane & 15, quad = lane >> 4;
    f32x4 acc[4][4];
#pragma unroll
    for (int i = 0; i < 4; i++)
#pragma unroll
        for (int j = 0; j < 4; j++) acc[i][j] = (f32x4){0.f, 0.f, 0.f, 0.f};

    const __half* ib = (APPLY ? in + (size_t)sub * BCHW : in) + (size_t)b * CHW;
    const __half* Fb = APPLY ? (F + (size_t)b * CHW) : nullptr;
    __half* Ab = APPLY ? (Aap + (size_t)b * CHW) : nullptr;
    __half* ob = APPLY ? (out_b + (size_t)b * CHW)
                       : (out_b + (size_t)sub * BCHW + (size_t)b * CHW);

    for (int pass = 0; pass < 2; pass++) {
        __syncthreads();
        for (int i = t; i < 1296; i += 256) {
            const int cg = i & 3;
            const int rem = i >> 2;
            const int ry = rem / 18, rx = rem - ry * 18;
            const int hh = h0 + ry - 1, ww = w0 + rx - 1;
            half8 v = {};
            if (hh >= 0 && hh < 256 && ww >= 0 && ww < 256) {
                const size_t off = (size_t)(hh * 256 + ww) * 64 + pass * 32 + cg * 8;
                v = *(const half8*)&ib[off];
                if (APPLY) {
                    half8 f = *(const half8*)&Fb[off];
#pragma unroll
                    for (int j = 0; j < 8; j++)
                        v[j] = (_Float16)fmaf((float)v[j], ysm[pass * 32 + cg * 8 + j], (float)f[j]);
                    if (ry >= 1 && ry <= 16 && rx >= 1 && rx <= 16 &&
                        topsm[(ry - 1) * 16 + (rx - 1)] == expert)
                        *(half8*)&Ab[off] = v;
                }
            }
            *(half8*)&tile[(cg * 324 + rem) * 8] = v;
        }
        __syncthreads();
        half8 bf[4];
#pragma unroll
        for (int ct = 0; ct < 4; ct++)
            bf[ct] = *(const half8*)&wT[(ct * 16 + l15) * 72 + pass * 32 + quad * 8];
        half8 wv9[9];
#pragma unroll
        for (int tap = 0; tap < 9; tap++)
            wv9[tap] = *(const half8*)&wdwh[tap * 64 + pass * 32 + quad * 8];
        float bias8[8];
#pragma unroll
        for (int j = 0; j < 8; j++) bias8[j] = bdw[pass * 32 + quad * 8 + j];
#pragma unroll
        for (int T = 0; T < 4; T++) {
            const int py = wv * 4 + T;
            half8 xv[9];
#pragma unroll
            for (int dy = 0; dy < 3; dy++)
#pragma unroll
                for (int dx = 0; dx < 3; dx++)
                    xv[dy * 3 + dx] = *(const half8*)&tile[(quad * 324 + (py + dy) * 18 + (l15 + dx)) * 8];
            float o[8];
#pragma unroll
            for (int j = 0; j < 8; j++) o[j] = bias8[j];
#pragma unroll
            for (int tap = 0; tap < 9; tap++)
#pragma unroll
                for (int j = 0; j < 8; j++)
                    o[j] = fmaf((float)xv[tap][j], (float)wv9[tap][j], o[j]);
            half8 a;
#pragma unroll
            for (int j = 0; j < 8; j++) a[j] = (_Float16)fmaxf(o[j], 0.f);
#pragma unroll
            for (int ct = 0; ct < 4; ct++)
                acc[T][ct] = __builtin_amdgcn_mfma_f32_16x16x32_f16(a, bf[ct], acc[T][ct], 0, 0, 0);
        }
    }
    // epilogue: per-wave LDS transpose -> 16B stores (masked to routed px if APPLY)
    __half* myo = &obuf[wv * 1088];
    float cs[4] = {0.f, 0.f, 0.f, 0.f};
    const int pxa = lane >> 3;
#pragma unroll
    for (int T = 0; T < 4; T++) {
        const int py_loc = wv * 4 + T;
#pragma unroll
        for (int ct = 0; ct < 4; ct++) {
            const float bv = bpw[ct * 16 + l15];
#pragma unroll
            for (int r = 0; r < 4; r++) {
                const float v = acc[T][ct][r] + bv;
                cs[ct] += v;
                myo[(quad * 4 + r) * 68 + ct * 16 + l15] = __float2half(v);
            }
        }
        const int py = h0 + py_loc;
        const size_t base = (size_t)(py * 256 + w0) * 64;
        half8 v0 = *(const half8*)&myo[pxa * 68 + (lane & 7) * 8];
        half8 v1 = *(const half8*)&myo[(8 + pxa) * 68 + (lane & 7) * 8];
        if (!APPLY || topsm[py_loc * 16 + pxa] == expert)
            *(half8*)&ob[base + lane * 8] = v0;
        if (!APPLY || topsm[py_loc * 16 + 8 + pxa] == expert)
            *(half8*)&ob[base + (lane + 64) * 8] = v1;
    }
#pragma unroll
    for (int ct = 0; ct < 4; ct++) {
        float s = cs[ct];
        s += __shfl_xor(s, 16);
        s += __shfl_xor(s, 32);
        if (quad == 0) atomicAdd(&chansum[b * 64 + ct * 16 + l15], s);
    }
}

// ---------------------------------------------------------------- final select: M = Bv_sh*y1(top) + Aap_sh (dense)
__global__ __launch_bounds__(256) void select_kernel(const __half* __restrict__ Bv,
                                                     const __half* __restrict__ Aap,
                                                     const float* __restrict__ chans,
                                                     const float* __restrict__ fc1b,
                                                     const float* __restrict__ fc2b,
                                                     const int* __restrict__ top,
                                                     __half* __restrict__ M) {
    __shared__ float hid[4][16];
    __shared__ float ysm[4][64];
    const int t = threadIdx.x;
    const int i8 = blockIdx.x * 256 + t;
    const size_t ei = (size_t)i8 << 3;
    const int b = (int)(ei >> 22);
    if (t < 64) {
        const int e = t >> 4, j = t & 15, i1 = e * 2 + 1;
        const float* fc1 = fc1b + i1 * 1024;
        const float* cs = chans + i1 * 256 + b * 64;
        float a = 0.f;
        for (int ci = 0; ci < 64; ci++) a = fmaf(fc1[j * 64 + ci], cs[ci], a);
        hid[e][j] = fmaxf(a, 0.f) * (1.f / 65536.f);
    }
    __syncthreads();
    {
        const int e = t >> 6, c = t & 63, i1 = e * 2 + 1;
        const float* fc2 = fc2b + i1 * 1024;
        float a = 0.f;
#pragma unroll
        for (int j = 0; j < 16; j++) a = fmaf(fc2[c * 16 + j], hid[e][j], a);
        ysm[e][c] = 1.f / (1.f + expf(-a));
    }
    __syncthreads();
    const int px = (int)(ei >> 6);
    const int e = top[px];
    const int c0 = (int)(ei & 63);
    float4 bv4 = ((const float4*)Bv)[i8];
    float4 av4 = ((const float4*)Aap)[i8];
    const __half2* bh = (const __half2*)&bv4;
    const __half2* ah = (const __half2*)&av4;
    __half2 outv[4];
#pragma unroll
    for (int j = 0; j < 4; j++) {
        const float2 b2 = __half22float2(bh[j]);
        const float2 a2 = __half22float2(ah[j]);
        outv[j] = __floats2half2_rn(fmaf(b2.x, ysm[e][c0 + 2 * j], a2.x),
                                    fmaf(b2.y, ysm[e][c0 + 2 * j + 1], a2.y));
    }
    ((float4*)M)[i8] = *(float4*)outv;
}

// ---------------------------------------------------------------- bilinear x2 upsample (jax.image.resize semantics)
__device__ __forceinline__ float bilin_up(const float* __restrict__ xb, int h, int w, int r1, int r2) {
    int hlo, hhi; float wrr;
    if (r1 == 0) { hlo = h - 1; hhi = h;     wrr = 0.25f; }
    else         { hlo = h;     hhi = h + 1; wrr = 0.75f; }
    if (hlo < 0)   { hlo = 0;   wrr = 0.f; }
    if (hhi > 255) { hhi = 255; wrr = 1.f; }
    int wlo, whi; float wcc;
    if (r2 == 0) { wlo = w - 1; whi = w;     wcc = 0.25f; }
    else         { wlo = w;     whi = w + 1; wcc = 0.75f; }
    if (wlo < 0)   { wlo = 0;   wcc = 0.f; }
    if (whi > 255) { whi = 255; wcc = 1.f; }
    const float a = xb[hlo * 256 + wlo] * wcc + xb[hlo * 256 + whi] * (1.f - wcc);
    const float b = xb[hhi * 256 + wlo] * wcc + xb[hhi * 256 + whi] * (1.f - wcc);
    return a * wrr + b * (1.f - wrr);
}

// ---------------------------------------------------------------- recon: 9 shifted MFMA GEMMs + pixel shuffle + x_up
__global__ __launch_bounds__(256, 3) void recon_kernel(const __half* __restrict__ moe,   // NHWC
                                                       const float* __restrict__ rw,     // [12][64][9]
                                                       const float* __restrict__ rbias,
                                                       const float* __restrict__ x,
                                                       float* __restrict__ sr) {
    __shared__ __half tile[4 * 324 * 8];
    __shared__ __half Wt[9 * 16 * 72];
    __shared__ float bsm12[12];
    const int t = threadIdx.x;
    const int b = blockIdx.z;
    const int h0 = blockIdx.y * 16, w0 = blockIdx.x * 16;

    for (int i = t; i < 9216; i += 256) {
        const int tap = i / 1024, rem = i - tap * 1024;
        const int n = rem >> 6, ci = rem & 63;
        Wt[(tap * 16 + n) * 72 + ci] = __float2half(n < 12 ? rw[n * 576 + ci * 9 + tap] : 0.f);
    }
    if (t < 12) bsm12[t] = rbias[t];

    const int lane = t & 63, wvi = t >> 6;
    const int l15 = lane & 15, quad = lane >> 4;
    f32x4 acc[4];
#pragma unroll
    for (int i = 0; i < 4; i++) acc[i] = (f32x4){0.f, 0.f, 0.f, 0.f};

    const __half* mb = moe + (size_t)b * CHW;

    for (int pass = 0; pass < 2; pass++) {
        __syncthreads();
        for (int i = t; i < 1296; i += 256) {
            const int cg = i & 3;
            const int rem = i >> 2;
            const int ry = rem / 18, rx = rem - ry * 18;
            const int hh = h0 + ry - 1, ww = w0 + rx - 1;
            half8 v = {};
            if (hh >= 0 && hh < 256 && ww >= 0 && ww < 256)
                v = *(const half8*)&mb[(size_t)(hh * 256 + ww) * 64 + pass * 32 + cg * 8];
            *(half8*)&tile[(cg * 324 + rem) * 8] = v;
        }
        __syncthreads();
        half8 bf[9];
#pragma unroll
        for (int tap = 0; tap < 9; tap++)
            bf[tap] = *(const half8*)&Wt[(tap * 16 + l15) * 72 + pass * 32 + quad * 8];
#pragma unroll
        for (int T = 0; T < 4; T++) {
            const int py = wvi * 4 + T;
#pragma unroll
            for (int dy = 0; dy < 3; dy++)
#pragma unroll
                for (int dx = 0; dx < 3; dx++) {
                    half8 a = *(const half8*)&tile[(quad * 324 + (py + dy) * 18 + (l15 + dx)) * 8];
                    acc[T] = __builtin_amdgcn_mfma_f32_16x16x32_f16(a, bf[dy * 3 + dx], acc[T], 0, 0, 0);
                }
        }
    }
    if (l15 < 12) {
        const int c = l15 >> 2, r1 = (l15 >> 1) & 1, r2 = l15 & 1;
        const float* xb = x + ((size_t)b * 3 + c) * HW;
        const float bv = bsm12[l15];
        float* sb = sr + ((size_t)b * 3 + c) * HW2;
#pragma unroll
        for (int T = 0; T < 4; T++) {
            const int py = h0 + wvi * 4 + T;
#pragma unroll
            for (int r = 0; r < 4; r++) {
                const int wglob = w0 + quad * 4 + r;
                const float xu = bilin_up(xb, py, wglob, r1, r2);
                sb[(2 * py + r1) * 512 + 2 * wglob + r2] = acc[T][r] + bv + xu;
            }
        }
    }
}

// ---------------------------------------------------------------- 3x3 conv on [4][3][512][512] (refinement)
__global__ __launch_bounds__(256) void ref_conv_kernel(const float* __restrict__ in,
                                                       const float* __restrict__ qw,
                                                       const float* __restrict__ bb,
                                                       const float* __restrict__ addsrc,
                                                       float* __restrict__ outp,
                                                       int do_relu) {
    __shared__ float tile[324];
    __shared__ float wsm[81];
    __shared__ float bsm[3];
    const int t = threadIdx.y * 16 + threadIdx.x;
    if (t < 81) wsm[t] = qw[t];
    if (t < 3) bsm[t] = bb[t];
    const int b = blockIdx.z;
    const int h0 = blockIdx.y * 16, w0 = blockIdx.x * 16;
    const int h = h0 + threadIdx.y, w = w0 + threadIdx.x;
    float acc[3] = {0.f, 0.f, 0.f};
    for (int ci = 0; ci < 3; ci++) {
        __syncthreads();
        const float* ibp = in + ((size_t)b * 3 + ci) * HW2;
        for (int i = t; i < 324; i += 256) {
            int ty = i / 18, tx = i - ty * 18;
            int hh = h0 + ty - 1, ww = w0 + tx - 1;
            tile[i] = (hh >= 0 && hh < 512 && ww >= 0 && ww < 512) ? ibp[hh * 512 + ww] : 0.f;
        }
        __syncthreads();
        float tp[9];
#pragma unroll
        for (int dy = 0; dy < 3; dy++)
#pragma unroll
            for (int dx = 0; dx < 3; dx++)
                tp[dy * 3 + dx] = tile[(threadIdx.y + dy) * 18 + threadIdx.x + dx];
#pragma unroll
        for (int o = 0; o < 3; o++) {
            const float* wo = &wsm[o * 27 + ci * 9];
            float a = acc[o];
#pragma unroll
            for (int k = 0; k < 9; k++) a = fmaf(tp[k], wo[k], a);
            acc[o] = a;
        }
    }
#pragma unroll
    for (int o = 0; o < 3; o++) {
        float v = acc[o] + bsm[o];
        if (do_relu) v = fmaxf(v, 0.f);
        if (addsrc) v += addsrc[((size_t)b * 3 + o) * HW2 + h * 512 + w];
        outp[((size_t)b * 3 + o) * HW2 + h * 512 + w] = v;
    }
}

// ---------------------------------------------------------------- launcher
extern "C" void kernel_launch(void* const* d_in, const int* in_sizes, int n_in,
                              void* d_out, int out_size, void* d_ws, size_t ws_size,
                              hipStream_t stream) {
    const float* x         = (const float*)d_in[0];
    const float* shallow_w = (const float*)d_in[1];
    const float* shallow_b = (const float*)d_in[2];
    const float* tex_dw_w  = (const float*)d_in[3];
    const float* tex_dw_b  = (const float*)d_in[4];
    const float* tex_pw_w  = (const float*)d_in[5];
    const float* tex_pw_b  = (const float*)d_in[6];
    const float* router_w  = (const float*)d_in[7];
    const float* router_b  = (const float*)d_in[8];
    const float* exp_dw_w  = (const float*)d_in[9];
    const float* exp_dw_b  = (const float*)d_in[10];
    const float* exp_pw_w  = (const float*)d_in[11];
    const float* exp_pw_b  = (const float*)d_in[12];
    const float* exp_fc1   = (const float*)d_in[13];
    const float* exp_fc2   = (const float*)d_in[14];
    const float* recon_w   = (const float*)d_in[15];
    const float* recon_b   = (const float*)d_in[16];
    const float* ref1_w    = (const float*)d_in[17];
    const float* ref1_b    = (const float*)d_in[18];
    const float* ref2_w    = (const float*)d_in[19];
    const float* ref2_b    = (const float*)d_in[20];

    // workspace (~161 MB)
    __half* feat_h = (__half*)d_ws;              // 32 MB
    __half* Apair  = feat_h + BCHW;              // 64 MB (2 slots, reused across supersteps)
    __half* Bv_sh  = Apair + 2 * (size_t)BCHW;   // 32 MB, routed-shared
    __half* Aap_sh = Bv_sh + BCHW;               // 32 MB, routed-shared
    int*    top    = (int*)(Aap_sh + BCHW);      // 1 MB
    float*  qb     = (float*)(top + 262144);
    float*  q_sh   = qb;                 // 1728
    float*  q_tdw  = q_sh + 1728;        // 576
    float*  q_tpw  = q_tdw + 576;        // 512
    float*  q_edw  = q_tpw + 512;        // 8*576
    float*  q_epw  = q_edw + 4608;       // 8*4096
    float*  q_r1   = q_epw + 32768;      // 81
    float*  q_r2   = q_r1 + 81;          // 81
    float*  chans  = q_r2 + 81;          // 8*256
    __half* M      = Apair;              // alias: Apair dead after superstep 1 block2
    float*  sr     = (float*)Bv_sh;      // alias: dead after select
    float*  t1     = (float*)Aap_sh;     // alias: dead after select

    hipMemsetAsync(chans, 0, 2048 * sizeof(float), stream);

    TernArgs ta;
    ta.d[0] = { shallow_w, q_sh, 1728 };
    ta.d[1] = { tex_dw_w, q_tdw, 576 };
    ta.d[2] = { tex_pw_w, q_tpw, 512 };
    for (int i = 0; i < 8; i++) ta.d[3 + i]  = { exp_dw_w + i * 576,  q_edw + i * 576,  576 };
    for (int i = 0; i < 8; i++) ta.d[11 + i] = { exp_pw_w + i * 4096, q_epw + i * 4096, 4096 };
    ta.d[19] = { ref1_w, q_r1, 81 };
    ta.d[20] = { ref2_w, q_r2, 81 };
    ternarize_kernel<<<21, 256, 0, stream>>>(ta);

    shallow_router_kernel<<<dim3(16, 16, 4), 256, 0, stream>>>(
        x, q_sh, shallow_b, q_tdw, tex_dw_b, q_tpw, tex_pw_b, router_w, router_b,
        feat_h, top);

    for (int s = 0; s < 2; s++) {
        expert_block_kernel<false><<<dim3(16, 16, 8), 256, 0, stream>>>(
            feat_h, q_edw, exp_dw_b, q_epw, exp_pw_b,
            Apair, chans, nullptr, nullptr, nullptr, nullptr, nullptr, s);
        expert_block_kernel<true><<<dim3(16, 16, 8), 256, 0, stream>>>(
            Apair, q_edw, exp_dw_b, q_epw, exp_pw_b,
            Bv_sh, chans, exp_fc1, exp_fc2, feat_h, Aap_sh, top, s);
    }
    select_kernel<<<8192, 256, 0, stream>>>(Bv_sh, Aap_sh, chans, exp_fc1, exp_fc2, top, M);

    recon_kernel<<<dim3(16, 16, 4), 256, 0, stream>>>(M, recon_w, recon_b, x, sr);
    ref_conv_kernel<<<dim3(32, 32, 4), dim3(16, 16), 0, stream>>>(sr, q_r1, ref1_b, nullptr, t1, 1);
    ref_conv_kernel<<<dim3(32, 32, 4), dim3(16, 16), 0, stream>>>(t1, q_r2, ref2_b, sr, (float*)d_out, 0);
}

// Round 7
// 846.155 us; speedup vs baseline: 4.0768x; 1.0980x over previous
//
#include <hip/hip_runtime.h>
#include <hip/hip_fp16.h>
#include <math.h>

#define HW 65536            // 256*256
#define CHW 4194304         // 64*HW  (NHWC elements per batch)
#define BCHW 16777216
#define HW2 262144          // 512*512
#define TS 325              // tile pad stride (px) to break LDS write conflicts

typedef _Float16 half8 __attribute__((ext_vector_type(8)));
typedef float f32x4 __attribute__((ext_vector_type(4)));

// ---------------------------------------------------------------- ternarize
struct TernDesc { const float* src; float* dst; int n; };
struct TernArgs { TernDesc d[21]; };

__global__ __launch_bounds__(256) void ternarize_kernel(TernArgs args) {
    __shared__ float red[256];
    __shared__ float bc[2];
    TernDesc td = args.d[blockIdx.x];
    const int n = td.n;
    const int t = threadIdx.x;
    float s = 0.f;
    for (int i = t; i < n; i += 256) s += fabsf(td.src[i]);
    red[t] = s; __syncthreads();
    for (int k = 128; k > 0; k >>= 1) { if (t < k) red[t] += red[t + k]; __syncthreads(); }
    if (t == 0) bc[0] = 0.75f * red[0] / (float)n;
    __syncthreads();
    const float delta = bc[0];
    float s1 = 0.f, c1 = 0.f;
    for (int i = t; i < n; i += 256) {
        float a = fabsf(td.src[i]);
        if (a > delta) { s1 += a; c1 += 1.f; }
    }
    __syncthreads();
    red[t] = s1; __syncthreads();
    for (int k = 128; k > 0; k >>= 1) { if (t < k) red[t] += red[t + k]; __syncthreads(); }
    float sum1 = red[0];
    __syncthreads();
    red[t] = c1; __syncthreads();
    for (int k = 128; k > 0; k >>= 1) { if (t < k) red[t] += red[t + k]; __syncthreads(); }
    if (t == 0) bc[1] = sum1 / fmaxf(red[0], 1.f);
    __syncthreads();
    const float alpha = bc[1];
    for (int i = t; i < n; i += 256) {
        float w = td.src[i];
        td.dst[i] = (fabsf(w) > delta) ? ((w > 0.f) ? alpha : -alpha) : 0.f;
    }
}

// ---------------------------------------------------------------- fused shallow conv + texture encoder + router
__global__ __launch_bounds__(256) void shallow_router_kernel(
    const float* __restrict__ x,
    const float* __restrict__ qsh,  const float* __restrict__ shb,
    const float* __restrict__ qtdw, const float* __restrict__ tdwb,
    const float* __restrict__ qtpw, const float* __restrict__ tpwb,
    const float* __restrict__ rw,   const float* __restrict__ rbias,
    __half* __restrict__ feat_h, int* __restrict__ top) {
    __shared__ float xs[1200];          // [3][20][20]
    __shared__ float feats[324 * 33];   // [halo px][ch pad33]
    const int t = threadIdx.x;
    const int b = blockIdx.z;
    const int h0 = blockIdx.y * 16, w0 = blockIdx.x * 16;
    const float* xb = x + (size_t)b * 3 * HW;

    for (int i = t; i < 1200; i += 256) {
        const int ci = i / 400, rem = i - ci * 400;
        const int ry = rem / 20, rx = rem - ry * 20;
        const int hh = h0 + ry - 2, ww = w0 + rx - 2;
        xs[i] = (hh >= 0 && hh < 256 && ww >= 0 && ww < 256) ? xb[ci * HW + hh * 256 + ww] : 0.f;
    }
    const int iy = t >> 4, ix = t & 15;
    float tex[8] = {0, 0, 0, 0, 0, 0, 0, 0};
    __half* fhb = feat_h + (size_t)b * CHW;
    __syncthreads();

    for (int pass = 0; pass < 2; pass++) {
        const int c0 = pass * 32;
        if (pass) __syncthreads();
        for (int rep = 0; rep < 2; rep++) {
            const int p = t + rep * 256;
            if (p < 324) {
                const int ry = p / 18, rx = p - ry * 18;
                float patch[27];
#pragma unroll
                for (int ci = 0; ci < 3; ci++)
#pragma unroll
                    for (int dy = 0; dy < 3; dy++)
#pragma unroll
                        for (int dx = 0; dx < 3; dx++)
                            patch[ci * 9 + dy * 3 + dx] = xs[ci * 400 + (ry + dy) * 20 + rx + dx];
                for (int co = 0; co < 32; co++) {
                    const float* wp = &qsh[(c0 + co) * 27];
                    float a = shb[c0 + co];
#pragma unroll
                    for (int k = 0; k < 27; k++) a = fmaf(patch[k], wp[k], a);
                    feats[p * 33 + co] = fmaxf(a, 0.f);
                }
            }
        }
        __syncthreads();
        for (int id = t; id < 1024; id += 256) {
            const int p = id >> 2, cg = id & 3;
            const int py = p >> 4, px = p & 15;
            const float* fp = &feats[((py + 1) * 18 + px + 1) * 33 + cg * 8];
            half8 pk;
#pragma unroll
            for (int j = 0; j < 8; j++) pk[j] = (_Float16)fp[j];
            *(half8*)&fhb[((size_t)((h0 + py) * 256 + w0 + px)) * 64 + c0 + cg * 8] = pk;
        }
        for (int ch = 0; ch < 32; ch++) {
            const float* wp = &qtdw[(c0 + ch) * 9];
            float o = tdwb[c0 + ch];
#pragma unroll
            for (int dy = 0; dy < 3; dy++) {
                const float* rowp = &feats[((iy + dy) * 18 + ix) * 33 + ch];
                o = fmaf(rowp[0], wp[dy * 3],
                    fmaf(rowp[33], wp[dy * 3 + 1],
                        fmaf(rowp[66], wp[dy * 3 + 2], o)));
            }
            const float tc = fmaxf(o, 0.f);
#pragma unroll
            for (int j = 0; j < 8; j++) tex[j] = fmaf(qtpw[j * 64 + c0 + ch], tc, tex[j]);
        }
    }
    float sgm[8];
#pragma unroll
    for (int j = 0; j < 8; j++) sgm[j] = 1.f / (1.f + expf(-(tex[j] + tpwb[j])));
    float best = -1e30f; int bi = 0;
#pragma unroll
    for (int e = 0; e < 4; e++) {
        float v = rbias[e];
#pragma unroll
        for (int j = 0; j < 8; j++) v = fmaf(rw[e * 8 + j], sgm[j], v);
        if (v > best) { best = v; bi = e; }     // first max (jnp.argmax)
    }
    top[(size_t)b * HW + (h0 + iy) * 256 + w0 + ix] = bi;
}

// ---------------------------------------------------------------- y_kernel: channel attention vectors from chansum
struct YArgs { int layers[4]; int nL; };
__global__ __launch_bounds__(256) void y_kernel(const float* __restrict__ chans,
                                                const float* __restrict__ fc1b,
                                                const float* __restrict__ fc2b,
                                                float* __restrict__ yv, YArgs a) {
    __shared__ float hid[16][16];
    const int t = threadIdx.x;
    const int npair = a.nL * 4;
    if (t < npair * 16) {
        const int p = t >> 4, j = t & 15;
        const int li = a.layers[p >> 2], b = p & 3;
        const float* fc1 = fc1b + li * 1024;
        const float* cs = chans + li * 256 + b * 64;
        float s = 0.f;
        for (int ci = 0; ci < 64; ci++) s = fmaf(fc1[j * 64 + ci], cs[ci], s);
        hid[p][j] = fmaxf(s, 0.f) * (1.f / 65536.f);
    }
    __syncthreads();
    for (int idx = t; idx < npair * 64; idx += 256) {
        const int p = idx >> 6, c = idx & 63;
        const int li = a.layers[p >> 2], b = p & 3;
        const float* fc2 = fc2b + li * 1024;
        float s = 0.f;
#pragma unroll
        for (int j = 0; j < 16; j++) s = fmaf(fc2[c * 16 + j], hid[p][j], s);
        yv[li * 256 + b * 64 + c] = 1.f / (1.f + expf(-s));
    }
}

// ---------------------------------------------------------------- expert block: single-phase staging, 2 experts/dispatch
// APPLY=false: in=feat_h, out=Apair[sub] dense.
// APPLY=true:  in=Apair[sub], staged value = in*y0 + F (y0 precomputed in yv);
//   applied interior written routed-only to Aap; out=Bv routed-only.
template <bool APPLY>
__global__ __launch_bounds__(256, 3) void expert_block_kernel(
    const __half* __restrict__ in,
    const float* __restrict__ qdw_b, const float* __restrict__ dwb_b,
    const float* __restrict__ qpw_b, const float* __restrict__ pwb_b,
    __half* __restrict__ out_b, float* __restrict__ chans_b,
    const float* __restrict__ yv,
    const __half* __restrict__ F, __half* __restrict__ Aap,
    const int* __restrict__ topg, int superstep) {
    __shared__ __half tile[8 * TS * 8];    // 41600 B [cg][px pad TS][8ci]; obuf aliases after compute
    __shared__ __half wT[64 * 72];         // [co][ci pad72]
    __shared__ __half wdwh[9 * 64];        // [tap][ci]
    __shared__ float bdw[64];
    __shared__ float bpw[64];
    __shared__ unsigned char topsm[256];
    const int t = threadIdx.x;
    const int z = blockIdx.z;
    const int b = z & 3, sub = z >> 2;
    const int expert = superstep * 2 + sub;
    const int layer = expert * 2 + (APPLY ? 1 : 0);
    const float* qdw = qdw_b + layer * 576;
    const float* dwb = dwb_b + layer * 64;
    const float* qpw = qpw_b + layer * 4096;
    const float* pwb = pwb_b + layer * 64;
    float* chansum = chans_b + layer * 256;
    const int h0 = blockIdx.y * 16, w0 = blockIdx.x * 16;

    // weights -> LDS (read post-barrier only)
    for (int i = t; i < 4096; i += 256) wT[(i >> 6) * 72 + (i & 63)] = __float2half(qpw[i]);
    for (int i = t; i < 576; i += 256) {
        const int ci = i / 9, tap = i - ci * 9;
        wdwh[tap * 64 + ci] = __float2half(qdw[i]);
    }
    if (t < 64) { bdw[t] = dwb[t]; bpw[t] = pwb[t]; }
    if (APPLY)
        topsm[t] = (unsigned char)topg[(size_t)b * HW + (h0 + (t >> 4)) * 256 + w0 + (t & 15)];

    // per-thread y registers (staging cg = t&7 is loop-invariant)
    const int scg = t & 7;
    float y8[8];
    if (APPLY) {
        const float* yp = yv + (layer - 1) * 256 + b * 64 + scg * 8;
#pragma unroll
        for (int j = 0; j < 8; j++) y8[j] = yp[j];
    }

    const __half* ib = (APPLY ? in + (size_t)sub * BCHW : in) + (size_t)b * CHW;
    const __half* Fb = APPLY ? (F + (size_t)b * CHW) : nullptr;
    __half* Ab = APPLY ? (Aap + (size_t)b * CHW) : nullptr;
    __half* ob = APPLY ? (out_b + (size_t)b * CHW)
                       : (out_b + (size_t)sub * BCHW + (size_t)b * CHW);
    const int* tb = APPLY ? (topg + (size_t)b * HW) : nullptr;

    // single-phase staging of all 64 ci over 18x18 halo
    for (int i = t; i < 2592; i += 256) {
        const int cg = i & 7;              // == scg
        const int rem = i >> 3;            // 0..323
        const int ry = rem / 18, rx = rem - ry * 18;
        const int hh = h0 + ry - 1, ww = w0 + rx - 1;
        half8 v = {};
        if (hh >= 0 && hh < 256 && ww >= 0 && ww < 256) {
            const size_t off = (size_t)(hh * 256 + ww) * 64 + cg * 8;
            v = *(const half8*)&ib[off];
            if (APPLY) {
                half8 f = *(const half8*)&Fb[off];
#pragma unroll
                for (int j = 0; j < 8; j++)
                    v[j] = (_Float16)fmaf((float)v[j], y8[j], (float)f[j]);
                if (ry >= 1 && ry <= 16 && rx >= 1 && rx <= 16 &&
                    tb[hh * 256 + ww] == expert)
                    *(half8*)&Ab[off] = v;
            }
        }
        *(half8*)&tile[(cg * TS + rem) * 8] = v;
    }
    __syncthreads();

    const int lane = t & 63, wv = t >> 6;
    const int l15 = lane & 15, quad = lane >> 4;
    f32x4 acc[4][4];
#pragma unroll
    for (int i = 0; i < 4; i++)
#pragma unroll
        for (int j = 0; j < 4; j++) acc[i][j] = (f32x4){0.f, 0.f, 0.f, 0.f};

#pragma unroll
    for (int kh = 0; kh < 2; kh++) {
        const int cgk = kh * 4 + quad;
        half8 bf[4];
#pragma unroll
        for (int ct = 0; ct < 4; ct++)
            bf[ct] = *(const half8*)&wT[(ct * 16 + l15) * 72 + kh * 32 + quad * 8];
        half8 wv9[9];
#pragma unroll
        for (int tap = 0; tap < 9; tap++)
            wv9[tap] = *(const half8*)&wdwh[tap * 64 + kh * 32 + quad * 8];
        float bias8[8];
#pragma unroll
        for (int j = 0; j < 8; j++) bias8[j] = bdw[kh * 32 + quad * 8 + j];
#pragma unroll
        for (int T = 0; T < 4; T++) {
            const int py = wv * 4 + T;
            half8 xv[9];
#pragma unroll
            for (int dy = 0; dy < 3; dy++)
#pragma unroll
                for (int dx = 0; dx < 3; dx++)
                    xv[dy * 3 + dx] = *(const half8*)&tile[(cgk * TS + (py + dy) * 18 + (l15 + dx)) * 8];
            float o[8];
#pragma unroll
            for (int j = 0; j < 8; j++) o[j] = bias8[j];
#pragma unroll
            for (int tap = 0; tap < 9; tap++)
#pragma unroll
                for (int j = 0; j < 8; j++)
                    o[j] = fmaf((float)xv[tap][j], (float)wv9[tap][j], o[j]);
            half8 a;
#pragma unroll
            for (int j = 0; j < 8; j++) a[j] = (_Float16)fmaxf(o[j], 0.f);
#pragma unroll
            for (int ct = 0; ct < 4; ct++)
                acc[T][ct] = __builtin_amdgcn_mfma_f32_16x16x32_f16(a, bf[ct], acc[T][ct], 0, 0, 0);
        }
    }
    __syncthreads();   // all tile reads done; safe to alias obuf onto tile

    __half* obuf = tile;                 // 8704 B needed, fits
    __half* myo = &obuf[wv * 1088];
    float cs[4] = {0.f, 0.f, 0.f, 0.f};
    const int pxa = lane >> 3;
#pragma unroll
    for (int T = 0; T < 4; T++) {
        const int py_loc = wv * 4 + T;
#pragma unroll
        for (int ct = 0; ct < 4; ct++) {
            const float bv = bpw[ct * 16 + l15];
#pragma unroll
            for (int r = 0; r < 4; r++) {
                const float v = acc[T][ct][r] + bv;
                cs[ct] += v;
                myo[(quad * 4 + r) * 68 + ct * 16 + l15] = __float2half(v);
            }
        }
        const int py = h0 + py_loc;
        const size_t base = (size_t)(py * 256 + w0) * 64;
        half8 v0 = *(const half8*)&myo[pxa * 68 + (lane & 7) * 8];
        half8 v1 = *(const half8*)&myo[(8 + pxa) * 68 + (lane & 7) * 8];
        if (!APPLY || topsm[py_loc * 16 + pxa] == expert)
            *(half8*)&ob[base + lane * 8] = v0;
        if (!APPLY || topsm[py_loc * 16 + 8 + pxa] == expert)
            *(half8*)&ob[base + (lane + 64) * 8] = v1;
    }
#pragma unroll
    for (int ct = 0; ct < 4; ct++) {
        float s = cs[ct];
        s += __shfl_xor(s, 16);
        s += __shfl_xor(s, 32);
        if (quad == 0) atomicAdd(&chansum[b * 64 + ct * 16 + l15], s);
    }
}

// ---------------------------------------------------------------- final select: M = Bv*y1(top) + Aap (dense)
__global__ __launch_bounds__(256) void select_kernel(const __half* __restrict__ Bv,
                                                     const __half* __restrict__ Aap,
                                                     const float* __restrict__ yv,
                                                     const int* __restrict__ top,
                                                     __half* __restrict__ M) {
    __shared__ float ysm[4][64];
    const int t = threadIdx.x;
    const int i8 = blockIdx.x * 256 + t;
    const size_t ei = (size_t)i8 << 3;
    const int b = (int)(ei >> 22);
    {
        const int e = t >> 6, c = t & 63;
        ysm[e][c] = yv[(e * 2 + 1) * 256 + b * 64 + c];
    }
    __syncthreads();
    const int px = (int)(ei >> 6);
    const int e = top[px];
    const int c0 = (int)(ei & 63);
    float4 bv4 = ((const float4*)Bv)[i8];
    float4 av4 = ((const float4*)Aap)[i8];
    const __half2* bh = (const __half2*)&bv4;
    const __half2* ah = (const __half2*)&av4;
    __half2 outv[4];
#pragma unroll
    for (int j = 0; j < 4; j++) {
        const float2 b2 = __half22float2(bh[j]);
        const float2 a2 = __half22float2(ah[j]);
        outv[j] = __floats2half2_rn(fmaf(b2.x, ysm[e][c0 + 2 * j], a2.x),
                                    fmaf(b2.y, ysm[e][c0 + 2 * j + 1], a2.y));
    }
    ((float4*)M)[i8] = *(float4*)outv;
}

// ---------------------------------------------------------------- bilinear x2 upsample (jax.image.resize semantics)
__device__ __forceinline__ float bilin_up(const float* __restrict__ xb, int h, int w, int r1, int r2) {
    int hlo, hhi; float wrr;
    if (r1 == 0) { hlo = h - 1; hhi = h;     wrr = 0.25f; }
    else         { hlo = h;     hhi = h + 1; wrr = 0.75f; }
    if (hlo < 0)   { hlo = 0;   wrr = 0.f; }
    if (hhi > 255) { hhi = 255; wrr = 1.f; }
    int wlo, whi; float wcc;
    if (r2 == 0) { wlo = w - 1; whi = w;     wcc = 0.25f; }
    else         { wlo = w;     whi = w + 1; wcc = 0.75f; }
    if (wlo < 0)   { wlo = 0;   wcc = 0.f; }
    if (whi > 255) { whi = 255; wcc = 1.f; }
    const float a = xb[hlo * 256 + wlo] * wcc + xb[hlo * 256 + whi] * (1.f - wcc);
    const float b = xb[hhi * 256 + wlo] * wcc + xb[hhi * 256 + whi] * (1.f - wcc);
    return a * wrr + b * (1.f - wrr);
}

// ---------------------------------------------------------------- recon: 9 shifted MFMA GEMMs + pixel shuffle + x_up
__global__ __launch_bounds__(256, 3) void recon_kernel(const __half* __restrict__ moe,   // NHWC
                                                       const float* __restrict__ rw,     // [12][64][9]
                                                       const float* __restrict__ rbias,
                                                       const float* __restrict__ x,
                                                       float* __restrict__ sr) {
    __shared__ __half tile[4 * 324 * 8];
    __shared__ __half Wt[9 * 16 * 72];
    __shared__ float bsm12[12];
    const int t = threadIdx.x;
    const int b = blockIdx.z;
    const int h0 = blockIdx.y * 16, w0 = blockIdx.x * 16;

    for (int i = t; i < 9216; i += 256) {
        const int tap = i / 1024, rem = i - tap * 1024;
        const int n = rem >> 6, ci = rem & 63;
        Wt[(tap * 16 + n) * 72 + ci] = __float2half(n < 12 ? rw[n * 576 + ci * 9 + tap] : 0.f);
    }
    if (t < 12) bsm12[t] = rbias[t];

    const int lane = t & 63, wvi = t >> 6;
    const int l15 = lane & 15, quad = lane >> 4;
    f32x4 acc[4];
#pragma unroll
    for (int i = 0; i < 4; i++) acc[i] = (f32x4){0.f, 0.f, 0.f, 0.f};

    const __half* mb = moe + (size_t)b * CHW;

    for (int pass = 0; pass < 2; pass++) {
        __syncthreads();
        for (int i = t; i < 1296; i += 256) {
            const int cg = i & 3;
            const int rem = i >> 2;
            const int ry = rem / 18, rx = rem - ry * 18;
            const int hh = h0 + ry - 1, ww = w0 + rx - 1;
            half8 v = {};
            if (hh >= 0 && hh < 256 && ww >= 0 && ww < 256)
                v = *(const half8*)&mb[(size_t)(hh * 256 + ww) * 64 + pass * 32 + cg * 8];
            *(half8*)&tile[(cg * 324 + rem) * 8] = v;
        }
        __syncthreads();
        half8 bf[9];
#pragma unroll
        for (int tap = 0; tap < 9; tap++)
            bf[tap] = *(const half8*)&Wt[(tap * 16 + l15) * 72 + pass * 32 + quad * 8];
#pragma unroll
        for (int T = 0; T < 4; T++) {
            const int py = wvi * 4 + T;
#pragma unroll
            for (int dy = 0; dy < 3; dy++)
#pragma unroll
                for (int dx = 0; dx < 3; dx++) {
                    half8 a = *(const half8*)&tile[(quad * 324 + (py + dy) * 18 + (l15 + dx)) * 8];
                    acc[T] = __builtin_amdgcn_mfma_f32_16x16x32_f16(a, bf[dy * 3 + dx], acc[T], 0, 0, 0);
                }
        }
    }
    if (l15 < 12) {
        const int c = l15 >> 2, r1 = (l15 >> 1) & 1, r2 = l15 & 1;
        const float* xb = x + ((size_t)b * 3 + c) * HW;
        const float bv = bsm12[l15];
        float* sb = sr + ((size_t)b * 3 + c) * HW2;
#pragma unroll
        for (int T = 0; T < 4; T++) {
            const int py = h0 + wvi * 4 + T;
#pragma unroll
            for (int r = 0; r < 4; r++) {
                const int wglob = w0 + quad * 4 + r;
                const float xu = bilin_up(xb, py, wglob, r1, r2);
                sb[(2 * py + r1) * 512 + 2 * wglob + r2] = acc[T][r] + bv + xu;
            }
        }
    }
}

// ---------------------------------------------------------------- 3x3 conv on [4][3][512][512] (refinement)
__global__ __launch_bounds__(256) void ref_conv_kernel(const float* __restrict__ in,
                                                       const float* __restrict__ qw,
                                                       const float* __restrict__ bb,
                                                       const float* __restrict__ addsrc,
                                                       float* __restrict__ outp,
                                                       int do_relu) {
    __shared__ float tile[324];
    __shared__ float wsm[81];
    __shared__ float bsm[3];
    const int t = threadIdx.y * 16 + threadIdx.x;
    if (t < 81) wsm[t] = qw[t];
    if (t < 3) bsm[t] = bb[t];
    const int b = blockIdx.z;
    const int h0 = blockIdx.y * 16, w0 = blockIdx.x * 16;
    const int h = h0 + threadIdx.y, w = w0 + threadIdx.x;
    float acc[3] = {0.f, 0.f, 0.f};
    for (int ci = 0; ci < 3; ci++) {
        __syncthreads();
        const float* ibp = in + ((size_t)b * 3 + ci) * HW2;
        for (int i = t; i < 324; i += 256) {
            int ty = i / 18, tx = i - ty * 18;
            int hh = h0 + ty - 1, ww = w0 + tx - 1;
            tile[i] = (hh >= 0 && hh < 512 && ww >= 0 && ww < 512) ? ibp[hh * 512 + ww] : 0.f;
        }
        __syncthreads();
        float tp[9];
#pragma unroll
        for (int dy = 0; dy < 3; dy++)
#pragma unroll
            for (int dx = 0; dx < 3; dx++)
                tp[dy * 3 + dx] = tile[(threadIdx.y + dy) * 18 + threadIdx.x + dx];
#pragma unroll
        for (int o = 0; o < 3; o++) {
            const float* wo = &wsm[o * 27 + ci * 9];
            float a = acc[o];
#pragma unroll
            for (int k = 0; k < 9; k++) a = fmaf(tp[k], wo[k], a);
            acc[o] = a;
        }
    }
#pragma unroll
    for (int o = 0; o < 3; o++) {
        float v = acc[o] + bsm[o];
        if (do_relu) v = fmaxf(v, 0.f);
        if (addsrc) v += addsrc[((size_t)b * 3 + o) * HW2 + h * 512 + w];
        outp[((size_t)b * 3 + o) * HW2 + h * 512 + w] = v;
    }
}

// ---------------------------------------------------------------- launcher
extern "C" void kernel_launch(void* const* d_in, const int* in_sizes, int n_in,
                              void* d_out, int out_size, void* d_ws, size_t ws_size,
                              hipStream_t stream) {
    const float* x         = (const float*)d_in[0];
    const float* shallow_w = (const float*)d_in[1];
    const float* shallow_b = (const float*)d_in[2];
    const float* tex_dw_w  = (const float*)d_in[3];
    const float* tex_dw_b  = (const float*)d_in[4];
    const float* tex_pw_w  = (const float*)d_in[5];
    const float* tex_pw_b  = (const float*)d_in[6];
    const float* router_w  = (const float*)d_in[7];
    const float* router_b  = (const float*)d_in[8];
    const float* exp_dw_w  = (const float*)d_in[9];
    const float* exp_dw_b  = (const float*)d_in[10];
    const float* exp_pw_w  = (const float*)d_in[11];
    const float* exp_pw_b  = (const float*)d_in[12];
    const float* exp_fc1   = (const float*)d_in[13];
    const float* exp_fc2   = (const float*)d_in[14];
    const float* recon_w   = (const float*)d_in[15];
    const float* recon_b   = (const float*)d_in[16];
    const float* ref1_w    = (const float*)d_in[17];
    const float* ref1_b    = (const float*)d_in[18];
    const float* ref2_w    = (const float*)d_in[19];
    const float* ref2_b    = (const float*)d_in[20];

    // workspace (~161 MB)
    __half* feat_h = (__half*)d_ws;              // 32 MB
    __half* Apair  = feat_h + BCHW;              // 64 MB (2 slots per superstep)
    __half* Bv_sh  = Apair + 2 * (size_t)BCHW;   // 32 MB, routed-shared
    __half* Aap_sh = Bv_sh + BCHW;               // 32 MB, routed-shared
    int*    top    = (int*)(Aap_sh + BCHW);      // 1 MB
    float*  qb     = (float*)(top + 262144);
    float*  q_sh   = qb;                 // 1728
    float*  q_tdw  = q_sh + 1728;        // 576
    float*  q_tpw  = q_tdw + 576;        // 512
    float*  q_edw  = q_tpw + 512;        // 8*576
    float*  q_epw  = q_edw + 4608;       // 8*4096
    float*  q_r1   = q_epw + 32768;      // 81
    float*  q_r2   = q_r1 + 81;          // 81
    float*  chans  = q_r2 + 81;          // 8*256
    float*  yv     = chans + 2048;       // 8*256
    __half* M      = Apair;              // alias: Apair dead after superstep 1 block2
    float*  sr     = (float*)Bv_sh;      // alias: dead after select
    float*  t1     = (float*)Aap_sh;     // alias: dead after select

    hipMemsetAsync(chans, 0, 2048 * sizeof(float), stream);

    TernArgs ta;
    ta.d[0] = { shallow_w, q_sh, 1728 };
    ta.d[1] = { tex_dw_w, q_tdw, 576 };
    ta.d[2] = { tex_pw_w, q_tpw, 512 };
    for (int i = 0; i < 8; i++) ta.d[3 + i]  = { exp_dw_w + i * 576,  q_edw + i * 576,  576 };
    for (int i = 0; i < 8; i++) ta.d[11 + i] = { exp_pw_w + i * 4096, q_epw + i * 4096, 4096 };
    ta.d[19] = { ref1_w, q_r1, 81 };
    ta.d[20] = { ref2_w, q_r2, 81 };
    ternarize_kernel<<<21, 256, 0, stream>>>(ta);

    shallow_router_kernel<<<dim3(16, 16, 4), 256, 0, stream>>>(
        x, q_sh, shallow_b, q_tdw, tex_dw_b, q_tpw, tex_pw_b, router_w, router_b,
        feat_h, top);

    for (int s = 0; s < 2; s++) {
        expert_block_kernel<false><<<dim3(16, 16, 8), 256, 0, stream>>>(
            feat_h, q_edw, exp_dw_b, q_epw, exp_pw_b,
            Apair, chans, nullptr, nullptr, nullptr, nullptr, s);
        YArgs ya; ya.layers[0] = s * 4; ya.layers[1] = s * 4 + 2;
        ya.layers[2] = 0; ya.layers[3] = 0; ya.nL = 2;
        y_kernel<<<1, 256, 0, stream>>>(chans, exp_fc1, exp_fc2, yv, ya);
        expert_block_kernel<true><<<dim3(16, 16, 8), 256, 0, stream>>>(
            Apair, q_edw, exp_dw_b, q_epw, exp_pw_b,
            Bv_sh, chans, yv, feat_h, Aap_sh, top, s);
    }
    {
        YArgs ya; ya.layers[0] = 1; ya.layers[1] = 3; ya.layers[2] = 5; ya.layers[3] = 7;
        ya.nL = 4;
        y_kernel<<<1, 256, 0, stream>>>(chans, exp_fc1, exp_fc2, yv, ya);
    }
    select_kernel<<<8192, 256, 0, stream>>>(Bv_sh, Aap_sh, yv, top, M);

    recon_kernel<<<dim3(16, 16, 4), 256, 0, stream>>>(M, recon_w, recon_b, x, sr);
    ref_conv_kernel<<<dim3(32, 32, 4), dim3(16, 16), 0, stream>>>(sr, q_r1, ref1_b, nullptr, t1, 1);
    ref_conv_kernel<<<dim3(32, 32, 4), dim3(16, 16), 0, stream>>>(t1, q_r2, ref2_b, sr, (float*)d_out, 0);
}

// Round 8
// 508.195 us; speedup vs baseline: 6.7880x; 1.6650x over previous
//
#include <hip/hip_runtime.h>
#include <hip/hip_fp16.h>
#include <math.h>

#define HW 65536            // 256*256
#define CHW 4194304         // 64*HW  (NHWC elements per batch)
#define BCHW 16777216
#define HW2 262144          // 512*512
#define TS 325              // tile pad stride (px) to break LDS conflicts

typedef _Float16 half8 __attribute__((ext_vector_type(8)));
typedef float f32x4 __attribute__((ext_vector_type(4)));

// ---------------------------------------------------------------- ternarize
struct TernDesc { const float* src; float* dst; int n; };
struct TernArgs { TernDesc d[21]; };

__global__ __launch_bounds__(256) void ternarize_kernel(TernArgs args) {
    __shared__ float red[256];
    __shared__ float bc[2];
    TernDesc td = args.d[blockIdx.x];
    const int n = td.n;
    const int t = threadIdx.x;
    float s = 0.f;
    for (int i = t; i < n; i += 256) s += fabsf(td.src[i]);
    red[t] = s; __syncthreads();
    for (int k = 128; k > 0; k >>= 1) { if (t < k) red[t] += red[t + k]; __syncthreads(); }
    if (t == 0) bc[0] = 0.75f * red[0] / (float)n;
    __syncthreads();
    const float delta = bc[0];
    float s1 = 0.f, c1 = 0.f;
    for (int i = t; i < n; i += 256) {
        float a = fabsf(td.src[i]);
        if (a > delta) { s1 += a; c1 += 1.f; }
    }
    __syncthreads();
    red[t] = s1; __syncthreads();
    for (int k = 128; k > 0; k >>= 1) { if (t < k) red[t] += red[t + k]; __syncthreads(); }
    float sum1 = red[0];
    __syncthreads();
    red[t] = c1; __syncthreads();
    for (int k = 128; k > 0; k >>= 1) { if (t < k) red[t] += red[t + k]; __syncthreads(); }
    if (t == 0) bc[1] = sum1 / fmaxf(red[0], 1.f);
    __syncthreads();
    const float alpha = bc[1];
    for (int i = t; i < n; i += 256) {
        float w = td.src[i];
        td.dst[i] = (fabsf(w) > delta) ? ((w > 0.f) ? alpha : -alpha) : 0.f;
    }
}

// ---------------------------------------------------------------- fused shallow conv + texture encoder + router
__global__ __launch_bounds__(256) void shallow_router_kernel(
    const float* __restrict__ x,
    const float* __restrict__ qsh,  const float* __restrict__ shb,
    const float* __restrict__ qtdw, const float* __restrict__ tdwb,
    const float* __restrict__ qtpw, const float* __restrict__ tpwb,
    const float* __restrict__ rw,   const float* __restrict__ rbias,
    __half* __restrict__ feat_h, int* __restrict__ top) {
    __shared__ float xs[1200];          // [3][20][20]
    __shared__ float feats[324 * 33];   // [halo px][ch pad33]
    const int t = threadIdx.x;
    const int b = blockIdx.z;
    const int h0 = blockIdx.y * 16, w0 = blockIdx.x * 16;
    const float* xb = x + (size_t)b * 3 * HW;

    for (int i = t; i < 1200; i += 256) {
        const int ci = i / 400, rem = i - ci * 400;
        const int ry = rem / 20, rx = rem - ry * 20;
        const int hh = h0 + ry - 2, ww = w0 + rx - 2;
        xs[i] = (hh >= 0 && hh < 256 && ww >= 0 && ww < 256) ? xb[ci * HW + hh * 256 + ww] : 0.f;
    }
    const int iy = t >> 4, ix = t & 15;
    float tex[8] = {0, 0, 0, 0, 0, 0, 0, 0};
    __half* fhb = feat_h + (size_t)b * CHW;
    __syncthreads();

    for (int pass = 0; pass < 2; pass++) {
        const int c0 = pass * 32;
        if (pass) __syncthreads();
        for (int rep = 0; rep < 2; rep++) {
            const int p = t + rep * 256;
            if (p < 324) {
                const int ry = p / 18, rx = p - ry * 18;
                float patch[27];
#pragma unroll
                for (int ci = 0; ci < 3; ci++)
#pragma unroll
                    for (int dy = 0; dy < 3; dy++)
#pragma unroll
                        for (int dx = 0; dx < 3; dx++)
                            patch[ci * 9 + dy * 3 + dx] = xs[ci * 400 + (ry + dy) * 20 + rx + dx];
                for (int co = 0; co < 32; co++) {
                    const float* wp = &qsh[(c0 + co) * 27];
                    float a = shb[c0 + co];
#pragma unroll
                    for (int k = 0; k < 27; k++) a = fmaf(patch[k], wp[k], a);
                    feats[p * 33 + co] = fmaxf(a, 0.f);
                }
            }
        }
        __syncthreads();
        for (int id = t; id < 1024; id += 256) {
            const int p = id >> 2, cg = id & 3;
            const int py = p >> 4, px = p & 15;
            const float* fp = &feats[((py + 1) * 18 + px + 1) * 33 + cg * 8];
            half8 pk;
#pragma unroll
            for (int j = 0; j < 8; j++) pk[j] = (_Float16)fp[j];
            *(half8*)&fhb[((size_t)((h0 + py) * 256 + w0 + px)) * 64 + c0 + cg * 8] = pk;
        }
        for (int ch = 0; ch < 32; ch++) {
            const float* wp = &qtdw[(c0 + ch) * 9];
            float o = tdwb[c0 + ch];
#pragma unroll
            for (int dy = 0; dy < 3; dy++) {
                const float* rowp = &feats[((iy + dy) * 18 + ix) * 33 + ch];
                o = fmaf(rowp[0], wp[dy * 3],
                    fmaf(rowp[33], wp[dy * 3 + 1],
                        fmaf(rowp[66], wp[dy * 3 + 2], o)));
            }
            const float tc = fmaxf(o, 0.f);
#pragma unroll
            for (int j = 0; j < 8; j++) tex[j] = fmaf(qtpw[j * 64 + c0 + ch], tc, tex[j]);
        }
    }
    float sgm[8];
#pragma unroll
    for (int j = 0; j < 8; j++) sgm[j] = 1.f / (1.f + expf(-(tex[j] + tpwb[j])));
    float best = -1e30f; int bi = 0;
#pragma unroll
    for (int e = 0; e < 4; e++) {
        float v = rbias[e];
#pragma unroll
        for (int j = 0; j < 8; j++) v = fmaf(rw[e * 8 + j], sgm[j], v);
        if (v > best) { best = v; bi = e; }     // first max (jnp.argmax)
    }
    top[(size_t)b * HW + (h0 + iy) * 256 + w0 + ix] = bi;
}

// ---------------------------------------------------------------- y_kernel: channel attention vectors from chansum
struct YArgs { int layers[4]; int nL; };
__global__ __launch_bounds__(256) void y_kernel(const float* __restrict__ chans,
                                                const float* __restrict__ fc1b,
                                                const float* __restrict__ fc2b,
                                                float* __restrict__ yv, YArgs a) {
    __shared__ float hid[16][16];
    const int t = threadIdx.x;
    const int npair = a.nL * 4;
    if (t < npair * 16) {
        const int p = t >> 4, j = t & 15;
        const int li = a.layers[p >> 2], b = p & 3;
        const float* fc1 = fc1b + li * 1024;
        const float* cs = chans + li * 256 + b * 64;
        float s = 0.f;
        for (int ci = 0; ci < 64; ci++) s = fmaf(fc1[j * 64 + ci], cs[ci], s);
        hid[p][j] = fmaxf(s, 0.f) * (1.f / 65536.f);
    }
    __syncthreads();
    for (int idx = t; idx < npair * 64; idx += 256) {
        const int p = idx >> 6, c = idx & 63;
        const int li = a.layers[p >> 2], b = p & 3;
        const float* fc2 = fc2b + li * 1024;
        float s = 0.f;
#pragma unroll
        for (int j = 0; j < 16; j++) s = fmaf(fc2[c * 16 + j], hid[p][j], s);
        yv[li * 256 + b * 64 + c] = 1.f / (1.f + expf(-s));
    }
}

// ---------------------------------------------------------------- expert block: 512 threads, 16x16 tile, 2 experts/dispatch
// APPLY=false: in=feat_h, out=Apair[sub] dense.
// APPLY=true:  in=Apair[sub], staged value = in*y0 + F (y0 in yv);
//   applied interior written routed-only to Aap; out=Bv routed-only.
template <bool APPLY>
__global__ __launch_bounds__(512, 4) void expert_block_kernel(
    const __half* __restrict__ in,
    const float* __restrict__ qdw_b, const float* __restrict__ dwb_b,
    const float* __restrict__ qpw_b, const float* __restrict__ pwb_b,
    __half* __restrict__ out_b, float* __restrict__ chans_b,
    const float* __restrict__ yv,
    const __half* __restrict__ F, __half* __restrict__ Aap,
    const int* __restrict__ topg, int superstep) {
    __shared__ __half tile[8 * TS * 8];    // 41600 B; obuf aliases after compute
    __shared__ __half wT[64 * 72];         // [co][ci pad72] 9216 B
    __shared__ __half wdwh[9 * 64];        // [tap][ci] 1152 B
    __shared__ float bdw[64];
    __shared__ float bpw[64];
    __shared__ float csb[8][64];           // per-wave chansum staging
    __shared__ unsigned char topsm[256];
    const int t = threadIdx.x;
    const int z = blockIdx.z;
    const int b = z & 3, sub = z >> 2;
    const int expert = superstep * 2 + sub;
    const int layer = expert * 2 + (APPLY ? 1 : 0);
    const float* qdw = qdw_b + layer * 576;
    const float* dwb = dwb_b + layer * 64;
    const float* qpw = qpw_b + layer * 4096;
    const float* pwb = pwb_b + layer * 64;
    float* chansum = chans_b + layer * 256;
    const int h0 = blockIdx.y * 16, w0 = blockIdx.x * 16;

    for (int i = t; i < 4096; i += 512) wT[(i >> 6) * 72 + (i & 63)] = __float2half(qpw[i]);
    for (int i = t; i < 576; i += 512) {
        const int ci = i / 9, tap = i - ci * 9;
        wdwh[tap * 64 + ci] = __float2half(qdw[i]);
    }
    if (t < 64) { bdw[t] = dwb[t]; bpw[t] = pwb[t]; }
    if (APPLY && t < 256)
        topsm[t] = (unsigned char)topg[(size_t)b * HW + (h0 + (t >> 4)) * 256 + w0 + (t & 15)];

    // per-thread y registers (staging cg = t&7 is loop-invariant; 512 % 8 == 0)
    const int scg = t & 7;
    float y8[8];
    if (APPLY) {
        const float* yp = yv + (layer - 1) * 256 + b * 64 + scg * 8;
#pragma unroll
        for (int j = 0; j < 8; j++) y8[j] = yp[j];
    }

    const __half* ib = (APPLY ? in + (size_t)sub * BCHW : in) + (size_t)b * CHW;
    const __half* Fb = APPLY ? (F + (size_t)b * CHW) : nullptr;
    __half* Ab = APPLY ? (Aap + (size_t)b * CHW) : nullptr;
    __half* ob = APPLY ? (out_b + (size_t)b * CHW)
                       : (out_b + (size_t)sub * BCHW + (size_t)b * CHW);
    const int* tb = APPLY ? (topg + (size_t)b * HW) : nullptr;

    // single-phase staging of all 64 ci over the 18x18 halo (5-6 iters/thread)
    for (int i = t; i < 2592; i += 512) {
        const int cg = i & 7;              // == scg
        const int rem = i >> 3;            // 0..323
        const int ry = rem / 18, rx = rem - ry * 18;
        const int hh = h0 + ry - 1, ww = w0 + rx - 1;
        half8 v = {};
        if (hh >= 0 && hh < 256 && ww >= 0 && ww < 256) {
            const size_t off = (size_t)(hh * 256 + ww) * 64 + cg * 8;
            v = *(const half8*)&ib[off];
            if (APPLY) {
                half8 f = *(const half8*)&Fb[off];
#pragma unroll
                for (int j = 0; j < 8; j++)
                    v[j] = (_Float16)fmaf((float)v[j], y8[j], (float)f[j]);
                if (ry >= 1 && ry <= 16 && rx >= 1 && rx <= 16 &&
                    tb[hh * 256 + ww] == expert)
                    *(half8*)&Ab[off] = v;
            }
        }
        *(half8*)&tile[(cg * TS + rem) * 8] = v;
    }
    __syncthreads();

    const int lane = t & 63, wv = t >> 6;      // 8 waves, 2 rows each
    const int l15 = lane & 15, quad = lane >> 4;
    f32x4 acc[2][4];
#pragma unroll
    for (int i = 0; i < 2; i++)
#pragma unroll
        for (int j = 0; j < 4; j++) acc[i][j] = (f32x4){0.f, 0.f, 0.f, 0.f};

#pragma unroll
    for (int kh = 0; kh < 2; kh++) {
        const int cgk = kh * 4 + quad;
        half8 bf[4];
#pragma unroll
        for (int ct = 0; ct < 4; ct++)
            bf[ct] = *(const half8*)&wT[(ct * 16 + l15) * 72 + kh * 32 + quad * 8];
        half8 wv9[9];
#pragma unroll
        for (int tap = 0; tap < 9; tap++)
            wv9[tap] = *(const half8*)&wdwh[tap * 64 + kh * 32 + quad * 8];
        float bias8[8];
#pragma unroll
        for (int j = 0; j < 8; j++) bias8[j] = bdw[kh * 32 + quad * 8 + j];
#pragma unroll
        for (int T = 0; T < 2; T++) {
            const int py = wv * 2 + T;
            half8 xv[9];
#pragma unroll
            for (int dy = 0; dy < 3; dy++)
#pragma unroll
                for (int dx = 0; dx < 3; dx++)
                    xv[dy * 3 + dx] = *(const half8*)&tile[(cgk * TS + (py + dy) * 18 + (l15 + dx)) * 8];
            float o[8];
#pragma unroll
            for (int j = 0; j < 8; j++) o[j] = bias8[j];
#pragma unroll
            for (int tap = 0; tap < 9; tap++)
#pragma unroll
                for (int j = 0; j < 8; j++)
                    o[j] = fmaf((float)xv[tap][j], (float)wv9[tap][j], o[j]);
            half8 a;
#pragma unroll
            for (int j = 0; j < 8; j++) a[j] = (_Float16)fmaxf(o[j], 0.f);
#pragma unroll
            for (int ct = 0; ct < 4; ct++)
                acc[T][ct] = __builtin_amdgcn_mfma_f32_16x16x32_f16(a, bf[ct], acc[T][ct], 0, 0, 0);
        }
    }
    __syncthreads();   // tile reads done; alias obuf onto tile

    __half* obuf = tile;                 // 8 waves x 1088 halves = 17408 B, fits
    __half* myo = &obuf[wv * 1088];
    float cs[4] = {0.f, 0.f, 0.f, 0.f};
    const int pxa = lane >> 3;
#pragma unroll
    for (int T = 0; T < 2; T++) {
        const int py_loc = wv * 2 + T;
#pragma unroll
        for (int ct = 0; ct < 4; ct++) {
            const float bv = bpw[ct * 16 + l15];
#pragma unroll
            for (int r = 0; r < 4; r++) {
                const float v = acc[T][ct][r] + bv;
                cs[ct] += v;
                myo[(quad * 4 + r) * 68 + ct * 16 + l15] = __float2half(v);
            }
        }
        const int py = h0 + py_loc;
        const size_t base = (size_t)(py * 256 + w0) * 64;
        half8 v0 = *(const half8*)&myo[pxa * 68 + (lane & 7) * 8];
        half8 v1 = *(const half8*)&myo[(8 + pxa) * 68 + (lane & 7) * 8];
        if (!APPLY || topsm[py_loc * 16 + pxa] == expert)
            *(half8*)&ob[base + lane * 8] = v0;
        if (!APPLY || topsm[py_loc * 16 + 8 + pxa] == expert)
            *(half8*)&ob[base + (lane + 64) * 8] = v1;
    }
    // per-block chansum reduction: wave partials -> LDS -> 64 atomics/block
#pragma unroll
    for (int ct = 0; ct < 4; ct++) {
        float s = cs[ct];
        s += __shfl_xor(s, 16);
        s += __shfl_xor(s, 32);
        if (quad == 0) csb[wv][ct * 16 + l15] = s;
    }
    __syncthreads();
    if (t < 64) {
        float s = 0.f;
#pragma unroll
        for (int w = 0; w < 8; w++) s += csb[w][t];
        atomicAdd(&chansum[b * 64 + t], s);
    }
}

// ---------------------------------------------------------------- bilinear x2 upsample (jax.image.resize semantics)
__device__ __forceinline__ float bilin_up(const float* __restrict__ xb, int h, int w, int r1, int r2) {
    int hlo, hhi; float wrr;
    if (r1 == 0) { hlo = h - 1; hhi = h;     wrr = 0.25f; }
    else         { hlo = h;     hhi = h + 1; wrr = 0.75f; }
    if (hlo < 0)   { hlo = 0;   wrr = 0.f; }
    if (hhi > 255) { hhi = 255; wrr = 1.f; }
    int wlo, whi; float wcc;
    if (r2 == 0) { wlo = w - 1; whi = w;     wcc = 0.25f; }
    else         { wlo = w;     whi = w + 1; wcc = 0.75f; }
    if (wlo < 0)   { wlo = 0;   wcc = 0.f; }
    if (whi > 255) { whi = 255; wcc = 1.f; }
    const float a = xb[hlo * 256 + wlo] * wcc + xb[hlo * 256 + whi] * (1.f - wcc);
    const float b = xb[hhi * 256 + wlo] * wcc + xb[hhi * 256 + whi] * (1.f - wcc);
    return a * wrr + b * (1.f - wrr);
}

// ---------------------------------------------------------------- recon with fused select: stages M = Bv*y1(top) + Aap
__global__ __launch_bounds__(256, 3) void recon_kernel(const __half* __restrict__ Bv,
                                                       const __half* __restrict__ Aap,
                                                       const int* __restrict__ topg,
                                                       const float* __restrict__ yv,
                                                       const float* __restrict__ rw,   // [12][64][9]
                                                       const float* __restrict__ rbias,
                                                       const float* __restrict__ x,
                                                       float* __restrict__ sr) {
    __shared__ __half tile[4 * 324 * 8];
    __shared__ __half Wt[9 * 16 * 72];
    __shared__ float bsm12[12];
    __shared__ float ysm[4][64];
    const int t = threadIdx.x;
    const int b = blockIdx.z;
    const int h0 = blockIdx.y * 16, w0 = blockIdx.x * 16;

    for (int i = t; i < 9216; i += 256) {
        const int tap = i / 1024, rem = i - tap * 1024;
        const int n = rem >> 6, ci = rem & 63;
        Wt[(tap * 16 + n) * 72 + ci] = __float2half(n < 12 ? rw[n * 576 + ci * 9 + tap] : 0.f);
    }
    if (t < 12) bsm12[t] = rbias[t];
    {
        const int e = t >> 6, c = t & 63;
        ysm[e][c] = yv[(e * 2 + 1) * 256 + b * 64 + c];
    }

    const int lane = t & 63, wvi = t >> 6;
    const int l15 = lane & 15, quad = lane >> 4;
    f32x4 acc[4];
#pragma unroll
    for (int i = 0; i < 4; i++) acc[i] = (f32x4){0.f, 0.f, 0.f, 0.f};

    const __half* bb = Bv + (size_t)b * CHW;
    const __half* ab = Aap + (size_t)b * CHW;
    const int* tb = topg + (size_t)b * HW;

    for (int pass = 0; pass < 2; pass++) {
        __syncthreads();
        for (int i = t; i < 1296; i += 256) {
            const int cg = i & 3;
            const int rem = i >> 2;
            const int ry = rem / 18, rx = rem - ry * 18;
            const int hh = h0 + ry - 1, ww = w0 + rx - 1;
            half8 v = {};
            if (hh >= 0 && hh < 256 && ww >= 0 && ww < 256) {
                const size_t off = (size_t)(hh * 256 + ww) * 64 + pass * 32 + cg * 8;
                half8 bv8 = *(const half8*)&bb[off];
                half8 av8 = *(const half8*)&ab[off];
                const int e = tb[hh * 256 + ww];
                const float* yp = &ysm[e][pass * 32 + cg * 8];
#pragma unroll
                for (int j = 0; j < 8; j++)
                    v[j] = (_Float16)fmaf((float)bv8[j], yp[j], (float)av8[j]);
            }
            *(half8*)&tile[(cg * 324 + rem) * 8] = v;
        }
        __syncthreads();
        half8 bf[9];
#pragma unroll
        for (int tap = 0; tap < 9; tap++)
            bf[tap] = *(const half8*)&Wt[(tap * 16 + l15) * 72 + pass * 32 + quad * 8];
#pragma unroll
        for (int T = 0; T < 4; T++) {
            const int py = wvi * 4 + T;
#pragma unroll
            for (int dy = 0; dy < 3; dy++)
#pragma unroll
                for (int dx = 0; dx < 3; dx++) {
                    half8 a = *(const half8*)&tile[(quad * 324 + (py + dy) * 18 + (l15 + dx)) * 8];
                    acc[T] = __builtin_amdgcn_mfma_f32_16x16x32_f16(a, bf[dy * 3 + dx], acc[T], 0, 0, 0);
                }
        }
    }
    if (l15 < 12) {
        const int c = l15 >> 2, r1 = (l15 >> 1) & 1, r2 = l15 & 1;
        const float* xb = x + ((size_t)b * 3 + c) * HW;
        const float bv = bsm12[l15];
        float* sb = sr + ((size_t)b * 3 + c) * HW2;
#pragma unroll
        for (int T = 0; T < 4; T++) {
            const int py = h0 + wvi * 4 + T;
#pragma unroll
            for (int r = 0; r < 4; r++) {
                const int wglob = w0 + quad * 4 + r;
                const float xu = bilin_up(xb, py, wglob, r1, r2);
                sb[(2 * py + r1) * 512 + 2 * wglob + r2] = acc[T][r] + bv + xu;
            }
        }
    }
}

// ---------------------------------------------------------------- 3x3 conv on [4][3][512][512] (refinement)
__global__ __launch_bounds__(256) void ref_conv_kernel(const float* __restrict__ in,
                                                       const float* __restrict__ qw,
                                                       const float* __restrict__ bb,
                                                       const float* __restrict__ addsrc,
                                                       float* __restrict__ outp,
                                                       int do_relu) {
    __shared__ float tile[324];
    __shared__ float wsm[81];
    __shared__ float bsm[3];
    const int t = threadIdx.y * 16 + threadIdx.x;
    if (t < 81) wsm[t] = qw[t];
    if (t < 3) bsm[t] = bb[t];
    const int b = blockIdx.z;
    const int h0 = blockIdx.y * 16, w0 = blockIdx.x * 16;
    const int h = h0 + threadIdx.y, w = w0 + threadIdx.x;
    float acc[3] = {0.f, 0.f, 0.f};
    for (int ci = 0; ci < 3; ci++) {
        __syncthreads();
        const float* ibp = in + ((size_t)b * 3 + ci) * HW2;
        for (int i = t; i < 324; i += 256) {
            int ty = i / 18, tx = i - ty * 18;
            int hh = h0 + ty - 1, ww = w0 + tx - 1;
            tile[i] = (hh >= 0 && hh < 512 && ww >= 0 && ww < 512) ? ibp[hh * 512 + ww] : 0.f;
        }
        __syncthreads();
        float tp[9];
#pragma unroll
        for (int dy = 0; dy < 3; dy++)
#pragma unroll
            for (int dx = 0; dx < 3; dx++)
                tp[dy * 3 + dx] = tile[(threadIdx.y + dy) * 18 + threadIdx.x + dx];
#pragma unroll
        for (int o = 0; o < 3; o++) {
            const float* wo = &wsm[o * 27 + ci * 9];
            float a = acc[o];
#pragma unroll
            for (int k = 0; k < 9; k++) a = fmaf(tp[k], wo[k], a);
            acc[o] = a;
        }
    }
#pragma unroll
    for (int o = 0; o < 3; o++) {
        float v = acc[o] + bsm[o];
        if (do_relu) v = fmaxf(v, 0.f);
        if (addsrc) v += addsrc[((size_t)b * 3 + o) * HW2 + h * 512 + w];
        outp[((size_t)b * 3 + o) * HW2 + h * 512 + w] = v;
    }
}

// ---------------------------------------------------------------- launcher
extern "C" void kernel_launch(void* const* d_in, const int* in_sizes, int n_in,
                              void* d_out, int out_size, void* d_ws, size_t ws_size,
                              hipStream_t stream) {
    const float* x         = (const float*)d_in[0];
    const float* shallow_w = (const float*)d_in[1];
    const float* shallow_b = (const float*)d_in[2];
    const float* tex_dw_w  = (const float*)d_in[3];
    const float* tex_dw_b  = (const float*)d_in[4];
    const float* tex_pw_w  = (const float*)d_in[5];
    const float* tex_pw_b  = (const float*)d_in[6];
    const float* router_w  = (const float*)d_in[7];
    const float* router_b  = (const float*)d_in[8];
    const float* exp_dw_w  = (const float*)d_in[9];
    const float* exp_dw_b  = (const float*)d_in[10];
    const float* exp_pw_w  = (const float*)d_in[11];
    const float* exp_pw_b  = (const float*)d_in[12];
    const float* exp_fc1   = (const float*)d_in[13];
    const float* exp_fc2   = (const float*)d_in[14];
    const float* recon_w   = (const float*)d_in[15];
    const float* recon_b   = (const float*)d_in[16];
    const float* ref1_w    = (const float*)d_in[17];
    const float* ref1_b    = (const float*)d_in[18];
    const float* ref2_w    = (const float*)d_in[19];
    const float* ref2_b    = (const float*)d_in[20];

    // workspace (~161 MB)
    __half* feat_h = (__half*)d_ws;              // 32 MB
    __half* Apair  = feat_h + BCHW;              // 64 MB (2 slots per superstep)
    __half* Bv_sh  = Apair + 2 * (size_t)BCHW;   // 32 MB, routed-shared
    __half* Aap_sh = Bv_sh + BCHW;               // 32 MB, routed-shared
    int*    top    = (int*)(Aap_sh + BCHW);      // 1 MB
    float*  qb     = (float*)(top + 262144);
    float*  q_sh   = qb;                 // 1728
    float*  q_tdw  = q_sh + 1728;        // 576
    float*  q_tpw  = q_tdw + 576;        // 512
    float*  q_edw  = q_tpw + 512;        // 8*576
    float*  q_epw  = q_edw + 4608;       // 8*4096
    float*  q_r1   = q_epw + 32768;      // 81
    float*  q_r2   = q_r1 + 81;          // 81
    float*  chans  = q_r2 + 81;          // 8*256
    float*  yv     = chans + 2048;       // 8*256
    // sr/t1 live in Apair (dead after superstep 1 block2); recon reads Bv/Aap
    float*  sr     = (float*)Apair;            // 12 MB
    float*  t1     = ((float*)Apair) + 3145728; // 12 MB

    hipMemsetAsync(chans, 0, 2048 * sizeof(float), stream);

    TernArgs ta;
    ta.d[0] = { shallow_w, q_sh, 1728 };
    ta.d[1] = { tex_dw_w, q_tdw, 576 };
    ta.d[2] = { tex_pw_w, q_tpw, 512 };
    for (int i = 0; i < 8; i++) ta.d[3 + i]  = { exp_dw_w + i * 576,  q_edw + i * 576,  576 };
    for (int i = 0; i < 8; i++) ta.d[11 + i] = { exp_pw_w + i * 4096, q_epw + i * 4096, 4096 };
    ta.d[19] = { ref1_w, q_r1, 81 };
    ta.d[20] = { ref2_w, q_r2, 81 };
    ternarize_kernel<<<21, 256, 0, stream>>>(ta);

    shallow_router_kernel<<<dim3(16, 16, 4), 256, 0, stream>>>(
        x, q_sh, shallow_b, q_tdw, tex_dw_b, q_tpw, tex_pw_b, router_w, router_b,
        feat_h, top);

    for (int s = 0; s < 2; s++) {
        expert_block_kernel<false><<<dim3(16, 16, 8), 512, 0, stream>>>(
            feat_h, q_edw, exp_dw_b, q_epw, exp_pw_b,
            Apair, chans, nullptr, nullptr, nullptr, nullptr, s);
        YArgs ya; ya.layers[0] = s * 4; ya.layers[1] = s * 4 + 2;
        ya.layers[2] = 0; ya.layers[3] = 0; ya.nL = 2;
        y_kernel<<<1, 256, 0, stream>>>(chans, exp_fc1, exp_fc2, yv, ya);
        expert_block_kernel<true><<<dim3(16, 16, 8), 512, 0, stream>>>(
            Apair, q_edw, exp_dw_b, q_epw, exp_pw_b,
            Bv_sh, chans, yv, feat_h, Aap_sh, top, s);
    }
    {
        YArgs ya; ya.layers[0] = 1; ya.layers[1] = 3; ya.layers[2] = 5; ya.layers[3] = 7;
        ya.nL = 4;
        y_kernel<<<1, 256, 0, stream>>>(chans, exp_fc1, exp_fc2, yv, ya);
    }

    recon_kernel<<<dim3(16, 16, 4), 256, 0, stream>>>(Bv_sh, Aap_sh, top, yv,
                                                      recon_w, recon_b, x, sr);
    ref_conv_kernel<<<dim3(32, 32, 4), dim3(16, 16), 0, stream>>>(sr, q_r1, ref1_b, nullptr, t1, 1);
    ref_conv_kernel<<<dim3(32, 32, 4), dim3(16, 16), 0, stream>>>(t1, q_r2, ref2_b, sr, (float*)d_out, 0);
}

// Round 9
// 475.111 us; speedup vs baseline: 7.2606x; 1.0696x over previous
//
#include <hip/hip_runtime.h>
#include <hip/hip_fp16.h>
#include <math.h>

#define HW 65536            // 256*256
#define CHW 4194304         // 64*HW  (NHWC elements per batch)
#define BCHW 16777216
#define HW2 262144          // 512*512
#define TS 325              // tile pad stride (px) to break LDS conflicts

typedef _Float16 half8 __attribute__((ext_vector_type(8)));
typedef float f32x4 __attribute__((ext_vector_type(4)));

// ---------------------------------------------------------------- ternarize
struct TernDesc { const float* src; float* dst; int n; };
struct TernArgs { TernDesc d[21]; };

__global__ __launch_bounds__(256) void ternarize_kernel(TernArgs args) {
    __shared__ float red[256];
    __shared__ float bc[2];
    TernDesc td = args.d[blockIdx.x];
    const int n = td.n;
    const int t = threadIdx.x;
    float s = 0.f;
    for (int i = t; i < n; i += 256) s += fabsf(td.src[i]);
    red[t] = s; __syncthreads();
    for (int k = 128; k > 0; k >>= 1) { if (t < k) red[t] += red[t + k]; __syncthreads(); }
    if (t == 0) bc[0] = 0.75f * red[0] / (float)n;
    __syncthreads();
    const float delta = bc[0];
    float s1 = 0.f, c1 = 0.f;
    for (int i = t; i < n; i += 256) {
        float a = fabsf(td.src[i]);
        if (a > delta) { s1 += a; c1 += 1.f; }
    }
    __syncthreads();
    red[t] = s1; __syncthreads();
    for (int k = 128; k > 0; k >>= 1) { if (t < k) red[t] += red[t + k]; __syncthreads(); }
    float sum1 = red[0];
    __syncthreads();
    red[t] = c1; __syncthreads();
    for (int k = 128; k > 0; k >>= 1) { if (t < k) red[t] += red[t + k]; __syncthreads(); }
    if (t == 0) bc[1] = sum1 / fmaxf(red[0], 1.f);
    __syncthreads();
    const float alpha = bc[1];
    for (int i = t; i < n; i += 256) {
        float w = td.src[i];
        td.dst[i] = (fabsf(w) > delta) ? ((w > 0.f) ? alpha : -alpha) : 0.f;
    }
}

// ---------------------------------------------------------------- fused shallow conv + texture encoder + router (512 thr)
// Router-path fp32 math keeps the exact fmaf chains / accumulation order of
// the previous passing version (argmax stability).
__global__ __launch_bounds__(512, 6) void shallow_router_kernel(
    const float* __restrict__ x,
    const float* __restrict__ qsh,  const float* __restrict__ shb,
    const float* __restrict__ qtdw, const float* __restrict__ tdwb,
    const float* __restrict__ qtpw, const float* __restrict__ tpwb,
    const float* __restrict__ rw,   const float* __restrict__ rbias,
    __half* __restrict__ feat_h, int* __restrict__ top) {
    __shared__ float xs[1200];          // [3][20][20]
    __shared__ float feats[324 * 33];   // [halo px][ch pad33]
    const int t = threadIdx.x;
    const int b = blockIdx.z;
    const int h0 = blockIdx.y * 16, w0 = blockIdx.x * 16;
    const float* xb = x + (size_t)b * 3 * HW;

    for (int i = t; i < 1200; i += 512) {
        const int ci = i / 400, rem = i - ci * 400;
        const int ry = rem / 20, rx = rem - ry * 20;
        const int hh = h0 + ry - 2, ww = w0 + rx - 2;
        xs[i] = (hh >= 0 && hh < 256 && ww >= 0 && ww < 256) ? xb[ci * HW + hh * 256 + ww] : 0.f;
    }
    float tex[8] = {0, 0, 0, 0, 0, 0, 0, 0};
    __half* fhb = feat_h + (size_t)b * CHW;
    __syncthreads();

    for (int pass = 0; pass < 2; pass++) {
        const int c0 = pass * 32;
        if (pass) __syncthreads();          // feats rewrite vs prior readers
        // shallow: px-per-thread, single sweep (324 active threads)
        if (t < 324) {
            const int ry = t / 18, rx = t - ry * 18;
            float patch[27];
#pragma unroll
            for (int ci = 0; ci < 3; ci++)
#pragma unroll
                for (int dy = 0; dy < 3; dy++)
#pragma unroll
                    for (int dx = 0; dx < 3; dx++)
                        patch[ci * 9 + dy * 3 + dx] = xs[ci * 400 + (ry + dy) * 20 + rx + dx];
            for (int co = 0; co < 32; co++) {
                const float* wp = &qsh[(c0 + co) * 27];
                float a = shb[c0 + co];
#pragma unroll
                for (int k = 0; k < 27; k++) a = fmaf(patch[k], wp[k], a);
                feats[t * 33 + co] = fmaxf(a, 0.f);
            }
        }
        __syncthreads();
        if (t < 256) {
            // texture dw + partial pw for this thread's interior px (ch order as before)
            const int iy = t >> 4, ix = t & 15;
            for (int ch = 0; ch < 32; ch++) {
                const float* wp = &qtdw[(c0 + ch) * 9];
                float o = tdwb[c0 + ch];
#pragma unroll
                for (int dy = 0; dy < 3; dy++) {
                    const float* rowp = &feats[((iy + dy) * 18 + ix) * 33 + ch];
                    o = fmaf(rowp[0], wp[dy * 3],
                        fmaf(rowp[33], wp[dy * 3 + 1],
                            fmaf(rowp[66], wp[dy * 3 + 2], o)));
                }
                const float tc = fmaxf(o, 0.f);
#pragma unroll
                for (int j = 0; j < 8; j++) tex[j] = fmaf(qtpw[j * 64 + c0 + ch], tc, tex[j]);
            }
        } else {
            // feat_h writeout (interior 16x16, this pass's 32 ch) on threads 256-511
            for (int id = t - 256; id < 1024; id += 256) {
                const int p = id >> 2, cg = id & 3;
                const int py = p >> 4, px = p & 15;
                const float* fp = &feats[((py + 1) * 18 + px + 1) * 33 + cg * 8];
                half8 pk;
#pragma unroll
                for (int j = 0; j < 8; j++) pk[j] = (_Float16)fp[j];
                *(half8*)&fhb[((size_t)((h0 + py) * 256 + w0 + px)) * 64 + c0 + cg * 8] = pk;
            }
        }
    }
    if (t < 256) {
        const int iy = t >> 4, ix = t & 15;
        float sgm[8];
#pragma unroll
        for (int j = 0; j < 8; j++) sgm[j] = 1.f / (1.f + expf(-(tex[j] + tpwb[j])));
        float best = -1e30f; int bi = 0;
#pragma unroll
        for (int e = 0; e < 4; e++) {
            float v = rbias[e];
#pragma unroll
            for (int j = 0; j < 8; j++) v = fmaf(rw[e * 8 + j], sgm[j], v);
            if (v > best) { best = v; bi = e; }     // first max (jnp.argmax)
        }
        top[(size_t)b * HW + (h0 + iy) * 256 + w0 + ix] = bi;
    }
}

// ---------------------------------------------------------------- y_kernel: channel attention vectors from chansum
struct YArgs { int layers[4]; int nL; };
__global__ __launch_bounds__(256) void y_kernel(const float* __restrict__ chans,
                                                const float* __restrict__ fc1b,
                                                const float* __restrict__ fc2b,
                                                float* __restrict__ yv, YArgs a) {
    __shared__ float hid[16][16];
    const int t = threadIdx.x;
    const int npair = a.nL * 4;
    if (t < npair * 16) {
        const int p = t >> 4, j = t & 15;
        const int li = a.layers[p >> 2], b = p & 3;
        const float* fc1 = fc1b + li * 1024;
        const float* cs = chans + li * 256 + b * 64;
        float s = 0.f;
        for (int ci = 0; ci < 64; ci++) s = fmaf(fc1[j * 64 + ci], cs[ci], s);
        hid[p][j] = fmaxf(s, 0.f) * (1.f / 65536.f);
    }
    __syncthreads();
    for (int idx = t; idx < npair * 64; idx += 256) {
        const int p = idx >> 6, c = idx & 63;
        const int li = a.layers[p >> 2], b = p & 3;
        const float* fc2 = fc2b + li * 1024;
        float s = 0.f;
#pragma unroll
        for (int j = 0; j < 16; j++) s = fmaf(fc2[c * 16 + j], hid[p][j], s);
        yv[li * 256 + b * 64 + c] = 1.f / (1.f + expf(-s));
    }
}

// ---------------------------------------------------------------- expert block: 512 threads, unrolled staging
template <bool APPLY>
__global__ __launch_bounds__(512, 4) void expert_block_kernel(
    const __half* __restrict__ in,
    const float* __restrict__ qdw_b, const float* __restrict__ dwb_b,
    const float* __restrict__ qpw_b, const float* __restrict__ pwb_b,
    __half* __restrict__ out_b, float* __restrict__ chans_b,
    const float* __restrict__ yv,
    const __half* __restrict__ F, __half* __restrict__ Aap,
    const int* __restrict__ topg, int superstep) {
    __shared__ __half tile[8 * TS * 8];    // 41600 B; obuf aliases after compute
    __shared__ __half wT[64 * 72];         // [co][ci pad72] 9216 B
    __shared__ __half wdwh[9 * 64];        // [tap][ci] 1152 B
    __shared__ float bdw[64];
    __shared__ float bpw[64];
    __shared__ float csb[8][64];           // per-wave chansum staging
    __shared__ unsigned char topsm[256];
    const int t = threadIdx.x;
    const int z = blockIdx.z;
    const int b = z & 3, sub = z >> 2;
    const int expert = superstep * 2 + sub;
    const int layer = expert * 2 + (APPLY ? 1 : 0);
    const float* qdw = qdw_b + layer * 576;
    const float* dwb = dwb_b + layer * 64;
    const float* qpw = qpw_b + layer * 4096;
    const float* pwb = pwb_b + layer * 64;
    float* chansum = chans_b + layer * 256;
    const int h0 = blockIdx.y * 16, w0 = blockIdx.x * 16;

    for (int i = t; i < 4096; i += 512) wT[(i >> 6) * 72 + (i & 63)] = __float2half(qpw[i]);
    for (int i = t; i < 576; i += 512) {
        const int ci = i / 9, tap = i - ci * 9;
        wdwh[tap * 64 + ci] = __float2half(qdw[i]);
    }
    if (t < 64) { bdw[t] = dwb[t]; bpw[t] = pwb[t]; }
    if (APPLY && t < 256)
        topsm[t] = (unsigned char)topg[(size_t)b * HW + (h0 + (t >> 4)) * 256 + w0 + (t & 15)];

    const int scg = t & 7;
    float y8[8];
    if (APPLY) {
        const float* yp = yv + (layer - 1) * 256 + b * 64 + scg * 8;
#pragma unroll
        for (int j = 0; j < 8; j++) y8[j] = yp[j];
    }

    const __half* ib = (APPLY ? in + (size_t)sub * BCHW : in) + (size_t)b * CHW;
    const __half* Fb = APPLY ? (F + (size_t)b * CHW) : nullptr;
    __half* Ab = APPLY ? (Aap + (size_t)b * CHW) : nullptr;
    __half* ob = APPLY ? (out_b + (size_t)b * CHW)
                       : (out_b + (size_t)sub * BCHW + (size_t)b * CHW);
    const int* tb = APPLY ? (topg + (size_t)b * HW) : nullptr;

    // staging, force-unrolled: 5 full iterations + 32-thread tail
#pragma unroll
    for (int s = 0; s < 6; s++) {
        if (s < 5 || t < 32) {
            const int i = t + (s << 9);
            const int cg = i & 7;
            const int rem = i >> 3;            // 0..323
            const int ry = rem / 18, rx = rem - ry * 18;
            const int hh = h0 + ry - 1, ww = w0 + rx - 1;
            half8 v = {};
            if (hh >= 0 && hh < 256 && ww >= 0 && ww < 256) {
                const size_t off = (size_t)(hh * 256 + ww) * 64 + cg * 8;
                v = *(const half8*)&ib[off];
                if (APPLY) {
                    half8 f = *(const half8*)&Fb[off];
#pragma unroll
                    for (int j = 0; j < 8; j++)
                        v[j] = (_Float16)fmaf((float)v[j], y8[j], (float)f[j]);
                    if (ry >= 1 && ry <= 16 && rx >= 1 && rx <= 16 &&
                        tb[hh * 256 + ww] == expert)
                        *(half8*)&Ab[off] = v;
                }
            }
            *(half8*)&tile[(cg * TS + rem) * 8] = v;
        }
    }
    __syncthreads();

    const int lane = t & 63, wv = t >> 6;      // 8 waves, 2 rows each
    const int l15 = lane & 15, quad = lane >> 4;
    f32x4 acc[2][4];
#pragma unroll
    for (int i = 0; i < 2; i++)
#pragma unroll
        for (int j = 0; j < 4; j++) acc[i][j] = (f32x4){0.f, 0.f, 0.f, 0.f};

#pragma unroll
    for (int kh = 0; kh < 2; kh++) {
        const int cgk = kh * 4 + quad;
        half8 bf[4];
#pragma unroll
        for (int ct = 0; ct < 4; ct++)
            bf[ct] = *(const half8*)&wT[(ct * 16 + l15) * 72 + kh * 32 + quad * 8];
        half8 wv9[9];
#pragma unroll
        for (int tap = 0; tap < 9; tap++)
            wv9[tap] = *(const half8*)&wdwh[tap * 64 + kh * 32 + quad * 8];
        float bias8[8];
#pragma unroll
        for (int j = 0; j < 8; j++) bias8[j] = bdw[kh * 32 + quad * 8 + j];
#pragma unroll
        for (int T = 0; T < 2; T++) {
            const int py = wv * 2 + T;
            half8 xv[9];
#pragma unroll
            for (int dy = 0; dy < 3; dy++)
#pragma unroll
                for (int dx = 0; dx < 3; dx++)
                    xv[dy * 3 + dx] = *(const half8*)&tile[(cgk * TS + (py + dy) * 18 + (l15 + dx)) * 8];
            float o[8];
#pragma unroll
            for (int j = 0; j < 8; j++) o[j] = bias8[j];
#pragma unroll
            for (int tap = 0; tap < 9; tap++)
#pragma unroll
                for (int j = 0; j < 8; j++)
                    o[j] = fmaf((float)xv[tap][j], (float)wv9[tap][j], o[j]);
            half8 a;
#pragma unroll
            for (int j = 0; j < 8; j++) a[j] = (_Float16)fmaxf(o[j], 0.f);
#pragma unroll
            for (int ct = 0; ct < 4; ct++)
                acc[T][ct] = __builtin_amdgcn_mfma_f32_16x16x32_f16(a, bf[ct], acc[T][ct], 0, 0, 0);
        }
    }
    __syncthreads();   // tile reads done; alias obuf onto tile

    __half* obuf = tile;                 // 8 waves x 1088 halves = 17408 B, fits
    __half* myo = &obuf[wv * 1088];
    float cs[4] = {0.f, 0.f, 0.f, 0.f};
    const int pxa = lane >> 3;
#pragma unroll
    for (int T = 0; T < 2; T++) {
        const int py_loc = wv * 2 + T;
#pragma unroll
        for (int ct = 0; ct < 4; ct++) {
            const float bv = bpw[ct * 16 + l15];
#pragma unroll
            for (int r = 0; r < 4; r++) {
                const float v = acc[T][ct][r] + bv;
                cs[ct] += v;
                myo[(quad * 4 + r) * 68 + ct * 16 + l15] = __float2half(v);
            }
        }
        const int py = h0 + py_loc;
        const size_t base = (size_t)(py * 256 + w0) * 64;
        half8 v0 = *(const half8*)&myo[pxa * 68 + (lane & 7) * 8];
        half8 v1 = *(const half8*)&myo[(8 + pxa) * 68 + (lane & 7) * 8];
        if (!APPLY || topsm[py_loc * 16 + pxa] == expert)
            *(half8*)&ob[base + lane * 8] = v0;
        if (!APPLY || topsm[py_loc * 16 + 8 + pxa] == expert)
            *(half8*)&ob[base + (lane + 64) * 8] = v1;
    }
#pragma unroll
    for (int ct = 0; ct < 4; ct++) {
        float s = cs[ct];
        s += __shfl_xor(s, 16);
        s += __shfl_xor(s, 32);
        if (quad == 0) csb[wv][ct * 16 + l15] = s;
    }
    __syncthreads();
    if (t < 64) {
        float s = 0.f;
#pragma unroll
        for (int w = 0; w < 8; w++) s += csb[w][t];
        atomicAdd(&chansum[b * 64 + t], s);
    }
}

// ---------------------------------------------------------------- bilinear x2 upsample (jax.image.resize semantics)
__device__ __forceinline__ float bilin_up(const float* __restrict__ xb, int h, int w, int r1, int r2) {
    int hlo, hhi; float wrr;
    if (r1 == 0) { hlo = h - 1; hhi = h;     wrr = 0.25f; }
    else         { hlo = h;     hhi = h + 1; wrr = 0.75f; }
    if (hlo < 0)   { hlo = 0;   wrr = 0.f; }
    if (hhi > 255) { hhi = 255; wrr = 1.f; }
    int wlo, whi; float wcc;
    if (r2 == 0) { wlo = w - 1; whi = w;     wcc = 0.25f; }
    else         { wlo = w;     whi = w + 1; wcc = 0.75f; }
    if (wlo < 0)   { wlo = 0;   wcc = 0.f; }
    if (whi > 255) { whi = 255; wcc = 1.f; }
    const float a = xb[hlo * 256 + wlo] * wcc + xb[hlo * 256 + whi] * (1.f - wcc);
    const float b = xb[hhi * 256 + wlo] * wcc + xb[hhi * 256 + whi] * (1.f - wcc);
    return a * wrr + b * (1.f - wrr);
}

// ---------------------------------------------------------------- recon (512 thr, single-phase) with fused select
__global__ __launch_bounds__(512, 4) void recon_kernel(const __half* __restrict__ Bv,
                                                       const __half* __restrict__ Aap,
                                                       const int* __restrict__ topg,
                                                       const float* __restrict__ yv,
                                                       const float* __restrict__ rw,   // [12][64][9]
                                                       const float* __restrict__ rbias,
                                                       const float* __restrict__ x,
                                                       float* __restrict__ sr) {
    __shared__ __half tile[8 * TS * 8];     // 41600 B
    __shared__ __half Wt[9 * 16 * 72];      // 20736 B
    __shared__ float bsm12[12];
    __shared__ float ysm[4][64];
    const int t = threadIdx.x;
    const int b = blockIdx.z;
    const int h0 = blockIdx.y * 16, w0 = blockIdx.x * 16;

    for (int i = t; i < 9216; i += 512) {
        const int tap = i / 1024, rem = i - tap * 1024;
        const int n = rem >> 6, ci = rem & 63;
        Wt[(tap * 16 + n) * 72 + ci] = __float2half(n < 12 ? rw[n * 576 + ci * 9 + tap] : 0.f);
    }
    if (t < 12) bsm12[t] = rbias[t];
    if (t < 256) {
        const int e = t >> 6, c = t & 63;
        ysm[e][c] = yv[(e * 2 + 1) * 256 + b * 64 + c];
    }
    __syncthreads();    // ysm ready before staging uses it

    const __half* bb = Bv + (size_t)b * CHW;
    const __half* ab = Aap + (size_t)b * CHW;
    const int* tb = topg + (size_t)b * HW;

#pragma unroll
    for (int s = 0; s < 6; s++) {
        if (s < 5 || t < 32) {
            const int i = t + (s << 9);
            const int cg = i & 7;
            const int rem = i >> 3;
            const int ry = rem / 18, rx = rem - ry * 18;
            const int hh = h0 + ry - 1, ww = w0 + rx - 1;
            half8 v = {};
            if (hh >= 0 && hh < 256 && ww >= 0 && ww < 256) {
                const size_t off = (size_t)(hh * 256 + ww) * 64 + cg * 8;
                half8 bv8 = *(const half8*)&bb[off];
                half8 av8 = *(const half8*)&ab[off];
                const int e = tb[hh * 256 + ww];
                const float* yp = &ysm[e][cg * 8];
#pragma unroll
                for (int j = 0; j < 8; j++)
                    v[j] = (_Float16)fmaf((float)bv8[j], yp[j], (float)av8[j]);
            }
            *(half8*)&tile[(cg * TS + rem) * 8] = v;
        }
    }
    __syncthreads();

    const int lane = t & 63, wvi = t >> 6;
    const int l15 = lane & 15, quad = lane >> 4;
    f32x4 acc[2];
#pragma unroll
    for (int i = 0; i < 2; i++) acc[i] = (f32x4){0.f, 0.f, 0.f, 0.f};

#pragma unroll
    for (int kh = 0; kh < 2; kh++) {
        const int cgk = kh * 4 + quad;
        half8 bf[9];
#pragma unroll
        for (int tap = 0; tap < 9; tap++)
            bf[tap] = *(const half8*)&Wt[(tap * 16 + l15) * 72 + kh * 32 + quad * 8];
#pragma unroll
        for (int T = 0; T < 2; T++) {
            const int py = wvi * 2 + T;
#pragma unroll
            for (int dy = 0; dy < 3; dy++)
#pragma unroll
                for (int dx = 0; dx < 3; dx++) {
                    half8 a = *(const half8*)&tile[(cgk * TS + (py + dy) * 18 + (l15 + dx)) * 8];
                    acc[T] = __builtin_amdgcn_mfma_f32_16x16x32_f16(a, bf[dy * 3 + dx], acc[T], 0, 0, 0);
                }
        }
    }
    if (l15 < 12) {
        const int c = l15 >> 2, r1 = (l15 >> 1) & 1, r2 = l15 & 1;
        const float* xb = x + ((size_t)b * 3 + c) * HW;
        const float bv = bsm12[l15];
        float* sb = sr + ((size_t)b * 3 + c) * HW2;
#pragma unroll
        for (int T = 0; T < 2; T++) {
            const int py = h0 + wvi * 2 + T;
#pragma unroll
            for (int r = 0; r < 4; r++) {
                const int wglob = w0 + quad * 4 + r;
                const float xu = bilin_up(xb, py, wglob, r1, r2);
                sb[(2 * py + r1) * 512 + 2 * wglob + r2] = acc[T][r] + bv + xu;
            }
        }
    }
}

// ---------------------------------------------------------------- fused refinement: out = sr + conv2(relu(conv1(sr)))
__global__ __launch_bounds__(256) void ref_fused_kernel(const float* __restrict__ in,   // sr [4][3][512][512]
                                                        const float* __restrict__ q1,
                                                        const float* __restrict__ b1,
                                                        const float* __restrict__ q2,
                                                        const float* __restrict__ b2,
                                                        float* __restrict__ outp) {
    __shared__ float srs[1200];       // [3][20][20] halo ±2
    __shared__ float t1s[3 * 324];    // [3][18][18] halo ±1
    __shared__ float w1[81], w2[81];
    __shared__ float bb1[3], bb2[3];
    const int t = threadIdx.y * 16 + threadIdx.x;
    const int b = blockIdx.z;
    const int h0 = blockIdx.y * 16, w0 = blockIdx.x * 16;
    if (t < 81) { w1[t] = q1[t]; w2[t] = q2[t]; }
    if (t < 3)  { bb1[t] = b1[t]; bb2[t] = b2[t]; }
    for (int i = t; i < 1200; i += 256) {
        const int ci = i / 400, rem = i - ci * 400;
        const int ry = rem / 20, rx = rem - ry * 20;
        const int hh = h0 + ry - 2, ww = w0 + rx - 2;
        srs[i] = (hh >= 0 && hh < 512 && ww >= 0 && ww < 512)
                   ? in[((size_t)b * 3 + ci) * HW2 + hh * 512 + ww] : 0.f;
    }
    __syncthreads();
    for (int p = t; p < 324; p += 256) {
        const int ry = p / 18, rx = p - ry * 18;
        const int ih = h0 + ry - 1, iw = w0 + rx - 1;
        const bool valid = (ih >= 0 && ih < 512 && iw >= 0 && iw < 512);
#pragma unroll
        for (int o = 0; o < 3; o++) {
            float a = 0.f;
#pragma unroll
            for (int ci = 0; ci < 3; ci++) {
                const float* wp = &w1[o * 27 + ci * 9];
                const float* sp = &srs[ci * 400 + ry * 20 + rx];
#pragma unroll
                for (int ky = 0; ky < 3; ky++)
#pragma unroll
                    for (int kx = 0; kx < 3; kx++)
                        a = fmaf(sp[ky * 20 + kx], wp[ky * 3 + kx], a);
            }
            t1s[o * 324 + p] = valid ? fmaxf(a + bb1[o], 0.f) : 0.f;
        }
    }
    __syncthreads();
    const int ty = threadIdx.y, tx = threadIdx.x;
#pragma unroll
    for (int o = 0; o < 3; o++) {
        float a = 0.f;
#pragma unroll
        for (int ci = 0; ci < 3; ci++) {
            const float* wp = &w2[o * 27 + ci * 9];
            const float* tp = &t1s[ci * 324 + ty * 18 + tx];
#pragma unroll
            for (int ky = 0; ky < 3; ky++)
#pragma unroll
                for (int kx = 0; kx < 3; kx++)
                    a = fmaf(tp[ky * 18 + kx], wp[ky * 3 + kx], a);
        }
        const float v = a + bb2[o] + srs[o * 400 + (ty + 2) * 20 + tx + 2];
        outp[((size_t)b * 3 + o) * HW2 + (h0 + ty) * 512 + w0 + tx] = v;
    }
}

// ---------------------------------------------------------------- launcher
extern "C" void kernel_launch(void* const* d_in, const int* in_sizes, int n_in,
                              void* d_out, int out_size, void* d_ws, size_t ws_size,
                              hipStream_t stream) {
    const float* x         = (const float*)d_in[0];
    const float* shallow_w = (const float*)d_in[1];
    const float* shallow_b = (const float*)d_in[2];
    const float* tex_dw_w  = (const float*)d_in[3];
    const float* tex_dw_b  = (const float*)d_in[4];
    const float* tex_pw_w  = (const float*)d_in[5];
    const float* tex_pw_b  = (const float*)d_in[6];
    const float* router_w  = (const float*)d_in[7];
    const float* router_b  = (const float*)d_in[8];
    const float* exp_dw_w  = (const float*)d_in[9];
    const float* exp_dw_b  = (const float*)d_in[10];
    const float* exp_pw_w  = (const float*)d_in[11];
    const float* exp_pw_b  = (const float*)d_in[12];
    const float* exp_fc1   = (const float*)d_in[13];
    const float* exp_fc2   = (const float*)d_in[14];
    const float* recon_w   = (const float*)d_in[15];
    const float* recon_b   = (const float*)d_in[16];
    const float* ref1_w    = (const float*)d_in[17];
    const float* ref1_b    = (const float*)d_in[18];
    const float* ref2_w    = (const float*)d_in[19];
    const float* ref2_b    = (const float*)d_in[20];

    // workspace (~161 MB)
    __half* feat_h = (__half*)d_ws;              // 32 MB
    __half* Apair  = feat_h + BCHW;              // 64 MB (2 slots per superstep)
    __half* Bv_sh  = Apair + 2 * (size_t)BCHW;   // 32 MB, routed-shared
    __half* Aap_sh = Bv_sh + BCHW;               // 32 MB, routed-shared
    int*    top    = (int*)(Aap_sh + BCHW);      // 1 MB
    float*  qb     = (float*)(top + 262144);
    float*  q_sh   = qb;                 // 1728
    float*  q_tdw  = q_sh + 1728;        // 576
    float*  q_tpw  = q_tdw + 576;        // 512
    float*  q_edw  = q_tpw + 512;        // 8*576
    float*  q_epw  = q_edw + 4608;       // 8*4096
    float*  q_r1   = q_epw + 32768;      // 81
    float*  q_r2   = q_r1 + 81;          // 81
    float*  chans  = q_r2 + 81;          // 8*256
    float*  yv     = chans + 2048;       // 8*256
    float*  sr     = (float*)Apair;      // 12 MB (Apair dead after superstep-1 APPLY)

    hipMemsetAsync(chans, 0, 2048 * sizeof(float), stream);

    TernArgs ta;
    ta.d[0] = { shallow_w, q_sh, 1728 };
    ta.d[1] = { tex_dw_w, q_tdw, 576 };
    ta.d[2] = { tex_pw_w, q_tpw, 512 };
    for (int i = 0; i < 8; i++) ta.d[3 + i]  = { exp_dw_w + i * 576,  q_edw + i * 576,  576 };
    for (int i = 0; i < 8; i++) ta.d[11 + i] = { exp_pw_w + i * 4096, q_epw + i * 4096, 4096 };
    ta.d[19] = { ref1_w, q_r1, 81 };
    ta.d[20] = { ref2_w, q_r2, 81 };
    ternarize_kernel<<<21, 256, 0, stream>>>(ta);

    shallow_router_kernel<<<dim3(16, 16, 4), 512, 0, stream>>>(
        x, q_sh, shallow_b, q_tdw, tex_dw_b, q_tpw, tex_pw_b, router_w, router_b,
        feat_h, top);

    for (int s = 0; s < 2; s++) {
        expert_block_kernel<false><<<dim3(16, 16, 8), 512, 0, stream>>>(
            feat_h, q_edw, exp_dw_b, q_epw, exp_pw_b,
            Apair, chans, nullptr, nullptr, nullptr, nullptr, s);
        YArgs ya; ya.layers[0] = s * 4; ya.layers[1] = s * 4 + 2;
        ya.layers[2] = 0; ya.layers[3] = 0; ya.nL = 2;
        y_kernel<<<1, 256, 0, stream>>>(chans, exp_fc1, exp_fc2, yv, ya);
        expert_block_kernel<true><<<dim3(16, 16, 8), 512, 0, stream>>>(
            Apair, q_edw, exp_dw_b, q_epw, exp_pw_b,
            Bv_sh, chans, yv, feat_h, Aap_sh, top, s);
    }
    {
        YArgs ya; ya.layers[0] = 1; ya.layers[1] = 3; ya.layers[2] = 5; ya.layers[3] = 7;
        ya.nL = 4;
        y_kernel<<<1, 256, 0, stream>>>(chans, exp_fc1, exp_fc2, yv, ya);
    }

    recon_kernel<<<dim3(16, 16, 4), 512, 0, stream>>>(Bv_sh, Aap_sh, top, yv,
                                                      recon_w, recon_b, x, sr);
    ref_fused_kernel<<<dim3(32, 32, 4), dim3(16, 16), 0, stream>>>(
        sr, q_r1, ref1_b, q_r2, ref2_b, (float*)d_out);
}

// Round 10
// 427.823 us; speedup vs baseline: 8.0632x; 1.1105x over previous
//
#include <hip/hip_runtime.h>
#include <hip/hip_fp16.h>
#include <math.h>

#define HW 65536            // 256*256
#define CHW 4194304         // 64*HW  (NHWC elements per batch)
#define BCHW 16777216
#define HW2 262144          // 512*512
#define TS 325              // tile pad stride (px) to break LDS conflicts

typedef _Float16 half8 __attribute__((ext_vector_type(8)));
typedef float f32x4 __attribute__((ext_vector_type(4)));

// ---------------------------------------------------------------- ternarize (+ chans zeroing in block 21)
struct TernDesc { const float* src; float* dst; int n; };
struct TernArgs { TernDesc d[21]; };

__global__ __launch_bounds__(256) void ternarize_kernel(TernArgs args, float* __restrict__ chans) {
    const int t = threadIdx.x;
    if (blockIdx.x == 21) {
        for (int i = t; i < 2048; i += 256) chans[i] = 0.f;
        return;
    }
    __shared__ float red[256];
    __shared__ float bc[2];
    TernDesc td = args.d[blockIdx.x];
    const int n = td.n;
    float s = 0.f;
    for (int i = t; i < n; i += 256) s += fabsf(td.src[i]);
    red[t] = s; __syncthreads();
    for (int k = 128; k > 0; k >>= 1) { if (t < k) red[t] += red[t + k]; __syncthreads(); }
    if (t == 0) bc[0] = 0.75f * red[0] / (float)n;
    __syncthreads();
    const float delta = bc[0];
    float s1 = 0.f, c1 = 0.f;
    for (int i = t; i < n; i += 256) {
        float a = fabsf(td.src[i]);
        if (a > delta) { s1 += a; c1 += 1.f; }
    }
    __syncthreads();
    red[t] = s1; __syncthreads();
    for (int k = 128; k > 0; k >>= 1) { if (t < k) red[t] += red[t + k]; __syncthreads(); }
    float sum1 = red[0];
    __syncthreads();
    red[t] = c1; __syncthreads();
    for (int k = 128; k > 0; k >>= 1) { if (t < k) red[t] += red[t + k]; __syncthreads(); }
    if (t == 0) bc[1] = sum1 / fmaxf(red[0], 1.f);
    __syncthreads();
    const float alpha = bc[1];
    for (int i = t; i < n; i += 256) {
        float w = td.src[i];
        td.dst[i] = (fabsf(w) > delta) ? ((w > 0.f) ? alpha : -alpha) : 0.f;
    }
}

// ---------------------------------------------------------------- fused shallow conv + texture encoder + router (512 thr)
__global__ __launch_bounds__(512, 6) void shallow_router_kernel(
    const float* __restrict__ x,
    const float* __restrict__ qsh,  const float* __restrict__ shb,
    const float* __restrict__ qtdw, const float* __restrict__ tdwb,
    const float* __restrict__ qtpw, const float* __restrict__ tpwb,
    const float* __restrict__ rw,   const float* __restrict__ rbias,
    __half* __restrict__ feat_h, int* __restrict__ top) {
    __shared__ float xs[1200];          // [3][20][20]
    __shared__ float feats[324 * 33];   // [halo px][ch pad33]
    const int t = threadIdx.x;
    const int b = blockIdx.z;
    const int h0 = blockIdx.y * 16, w0 = blockIdx.x * 16;
    const float* xb = x + (size_t)b * 3 * HW;

    for (int i = t; i < 1200; i += 512) {
        const int ci = i / 400, rem = i - ci * 400;
        const int ry = rem / 20, rx = rem - ry * 20;
        const int hh = h0 + ry - 2, ww = w0 + rx - 2;
        xs[i] = (hh >= 0 && hh < 256 && ww >= 0 && ww < 256) ? xb[ci * HW + hh * 256 + ww] : 0.f;
    }
    float tex[8] = {0, 0, 0, 0, 0, 0, 0, 0};
    __half* fhb = feat_h + (size_t)b * CHW;
    __syncthreads();

    for (int pass = 0; pass < 2; pass++) {
        const int c0 = pass * 32;
        if (pass) __syncthreads();
        if (t < 324) {
            const int ry = t / 18, rx = t - ry * 18;
            float patch[27];
#pragma unroll
            for (int ci = 0; ci < 3; ci++)
#pragma unroll
                for (int dy = 0; dy < 3; dy++)
#pragma unroll
                    for (int dx = 0; dx < 3; dx++)
                        patch[ci * 9 + dy * 3 + dx] = xs[ci * 400 + (ry + dy) * 20 + rx + dx];
            for (int co = 0; co < 32; co++) {
                const float* wp = &qsh[(c0 + co) * 27];
                float a = shb[c0 + co];
#pragma unroll
                for (int k = 0; k < 27; k++) a = fmaf(patch[k], wp[k], a);
                feats[t * 33 + co] = fmaxf(a, 0.f);
            }
        }
        __syncthreads();
        if (t < 256) {
            const int iy = t >> 4, ix = t & 15;
            for (int ch = 0; ch < 32; ch++) {
                const float* wp = &qtdw[(c0 + ch) * 9];
                float o = tdwb[c0 + ch];
#pragma unroll
                for (int dy = 0; dy < 3; dy++) {
                    const float* rowp = &feats[((iy + dy) * 18 + ix) * 33 + ch];
                    o = fmaf(rowp[0], wp[dy * 3],
                        fmaf(rowp[33], wp[dy * 3 + 1],
                            fmaf(rowp[66], wp[dy * 3 + 2], o)));
                }
                const float tc = fmaxf(o, 0.f);
#pragma unroll
                for (int j = 0; j < 8; j++) tex[j] = fmaf(qtpw[j * 64 + c0 + ch], tc, tex[j]);
            }
        } else {
            for (int id = t - 256; id < 1024; id += 256) {
                const int p = id >> 2, cg = id & 3;
                const int py = p >> 4, px = p & 15;
                const float* fp = &feats[((py + 1) * 18 + px + 1) * 33 + cg * 8];
                half8 pk;
#pragma unroll
                for (int j = 0; j < 8; j++) pk[j] = (_Float16)fp[j];
                *(half8*)&fhb[((size_t)((h0 + py) * 256 + w0 + px)) * 64 + c0 + cg * 8] = pk;
            }
        }
    }
    if (t < 256) {
        const int iy = t >> 4, ix = t & 15;
        float sgm[8];
#pragma unroll
        for (int j = 0; j < 8; j++) sgm[j] = 1.f / (1.f + expf(-(tex[j] + tpwb[j])));
        float best = -1e30f; int bi = 0;
#pragma unroll
        for (int e = 0; e < 4; e++) {
            float v = rbias[e];
#pragma unroll
            for (int j = 0; j < 8; j++) v = fmaf(rw[e * 8 + j], sgm[j], v);
            if (v > best) { best = v; bi = e; }     // first max (jnp.argmax)
        }
        top[(size_t)b * HW + (h0 + iy) * 256 + w0 + ix] = bi;
    }
}

// ---------------------------------------------------------------- y_kernel: channel attention vectors from chansum
struct YArgs { int layers[4]; int nL; };
__global__ __launch_bounds__(256) void y_kernel(const float* __restrict__ chans,
                                                const float* __restrict__ fc1b,
                                                const float* __restrict__ fc2b,
                                                float* __restrict__ yv, YArgs a) {
    __shared__ float hid[16][16];
    const int t = threadIdx.x;
    const int npair = a.nL * 4;
    if (t < npair * 16) {
        const int p = t >> 4, j = t & 15;
        const int li = a.layers[p >> 2], b = p & 3;
        const float* fc1 = fc1b + li * 1024;
        const float* cs = chans + li * 256 + b * 64;
        float s = 0.f;
        for (int ci = 0; ci < 64; ci++) s = fmaf(fc1[j * 64 + ci], cs[ci], s);
        hid[p][j] = fmaxf(s, 0.f) * (1.f / 65536.f);
    }
    __syncthreads();
    for (int idx = t; idx < npair * 64; idx += 256) {
        const int p = idx >> 6, c = idx & 63;
        const int li = a.layers[p >> 2], b = p & 3;
        const float* fc2 = fc2b + li * 1024;
        float s = 0.f;
#pragma unroll
        for (int j = 0; j < 16; j++) s = fmaf(fc2[c * 16 + j], hid[p][j], s);
        yv[li * 256 + b * 64 + c] = 1.f / (1.f + expf(-s));
    }
}

// ---------------------------------------------------------------- expert block: 512 threads, ebase-parameterized
// grid z = 4 * nexp; b = z&3, slot/sub = z>>2, expert = ebase + sub.
template <bool APPLY>
__global__ __launch_bounds__(512, 6) void expert_block_kernel(
    const __half* __restrict__ in,
    const float* __restrict__ qdw_b, const float* __restrict__ dwb_b,
    const float* __restrict__ qpw_b, const float* __restrict__ pwb_b,
    __half* __restrict__ out_b, float* __restrict__ chans_b,
    const float* __restrict__ yv,
    const __half* __restrict__ F, __half* __restrict__ Aap,
    const int* __restrict__ topg, int ebase) {
    __shared__ __half tile[8 * TS * 8];    // 41600 B; obuf + csb alias after compute
    __shared__ __half wT[64 * 72];         // [co][ci pad72] 9216 B
    __shared__ __half wdwh[9 * 64];        // [tap][ci] 1152 B
    __shared__ float bdw[64];
    __shared__ float bpw[64];
    __shared__ unsigned char topsm[256];
    const int t = threadIdx.x;
    const int z = blockIdx.z;
    const int b = z & 3, sub = z >> 2;
    const int expert = ebase + sub;
    const int layer = expert * 2 + (APPLY ? 1 : 0);
    const float* qdw = qdw_b + layer * 576;
    const float* dwb = dwb_b + layer * 64;
    const float* qpw = qpw_b + layer * 4096;
    const float* pwb = pwb_b + layer * 64;
    float* chansum = chans_b + layer * 256;
    const int h0 = blockIdx.y * 16, w0 = blockIdx.x * 16;

    for (int i = t; i < 4096; i += 512) wT[(i >> 6) * 72 + (i & 63)] = __float2half(qpw[i]);
    for (int i = t; i < 576; i += 512) {
        const int ci = i / 9, tap = i - ci * 9;
        wdwh[tap * 64 + ci] = __float2half(qdw[i]);
    }
    if (t < 64) { bdw[t] = dwb[t]; bpw[t] = pwb[t]; }
    if (APPLY && t < 256)
        topsm[t] = (unsigned char)topg[(size_t)b * HW + (h0 + (t >> 4)) * 256 + w0 + (t & 15)];

    const int scg = t & 7;
    float y8[8];
    if (APPLY) {
        const float* yp = yv + (layer - 1) * 256 + b * 64 + scg * 8;
#pragma unroll
        for (int j = 0; j < 8; j++) y8[j] = yp[j];
    }

    const __half* ib = (APPLY ? in + (size_t)sub * BCHW : in) + (size_t)b * CHW;
    const __half* Fb = APPLY ? (F + (size_t)b * CHW) : nullptr;
    __half* Ab = APPLY ? (Aap + (size_t)b * CHW) : nullptr;
    __half* ob = APPLY ? (out_b + (size_t)b * CHW)
                       : (out_b + (size_t)sub * BCHW + (size_t)b * CHW);
    const int* tb = APPLY ? (topg + (size_t)b * HW) : nullptr;

    // staging, force-unrolled: 5 full iterations + 32-thread tail
#pragma unroll
    for (int s = 0; s < 6; s++) {
        if (s < 5 || t < 32) {
            const int i = t + (s << 9);
            const int cg = i & 7;
            const int rem = i >> 3;            // 0..323
            const int ry = rem / 18, rx = rem - ry * 18;
            const int hh = h0 + ry - 1, ww = w0 + rx - 1;
            half8 v = {};
            if (hh >= 0 && hh < 256 && ww >= 0 && ww < 256) {
                const size_t off = (size_t)(hh * 256 + ww) * 64 + cg * 8;
                v = *(const half8*)&ib[off];
                if (APPLY) {
                    half8 f = *(const half8*)&Fb[off];
#pragma unroll
                    for (int j = 0; j < 8; j++)
                        v[j] = (_Float16)fmaf((float)v[j], y8[j], (float)f[j]);
                    if (ry >= 1 && ry <= 16 && rx >= 1 && rx <= 16 &&
                        tb[hh * 256 + ww] == expert)
                        *(half8*)&Ab[off] = v;
                }
            }
            *(half8*)&tile[(cg * TS + rem) * 8] = v;
        }
    }
    __syncthreads();

    const int lane = t & 63, wv = t >> 6;      // 8 waves, 2 rows each
    const int l15 = lane & 15, quad = lane >> 4;
    f32x4 acc[2][4];
#pragma unroll
    for (int i = 0; i < 2; i++)
#pragma unroll
        for (int j = 0; j < 4; j++) acc[i][j] = (f32x4){0.f, 0.f, 0.f, 0.f};

#pragma unroll
    for (int kh = 0; kh < 2; kh++) {
        const int cgk = kh * 4 + quad;
        half8 bf[4];
#pragma unroll
        for (int ct = 0; ct < 4; ct++)
            bf[ct] = *(const half8*)&wT[(ct * 16 + l15) * 72 + kh * 32 + quad * 8];
        half8 wv9[9];
#pragma unroll
        for (int tap = 0; tap < 9; tap++)
            wv9[tap] = *(const half8*)&wdwh[tap * 64 + kh * 32 + quad * 8];
        float bias8[8];
#pragma unroll
        for (int j = 0; j < 8; j++) bias8[j] = bdw[kh * 32 + quad * 8 + j];
#pragma unroll
        for (int T = 0; T < 2; T++) {
            const int py = wv * 2 + T;
            half8 xv[9];
#pragma unroll
            for (int dy = 0; dy < 3; dy++)
#pragma unroll
                for (int dx = 0; dx < 3; dx++)
                    xv[dy * 3 + dx] = *(const half8*)&tile[(cgk * TS + (py + dy) * 18 + (l15 + dx)) * 8];
            float o[8];
#pragma unroll
            for (int j = 0; j < 8; j++) o[j] = bias8[j];
#pragma unroll
            for (int tap = 0; tap < 9; tap++)
#pragma unroll
                for (int j = 0; j < 8; j++)
                    o[j] = fmaf((float)xv[tap][j], (float)wv9[tap][j], o[j]);
            half8 a;
#pragma unroll
            for (int j = 0; j < 8; j++) a[j] = (_Float16)fmaxf(o[j], 0.f);
#pragma unroll
            for (int ct = 0; ct < 4; ct++)
                acc[T][ct] = __builtin_amdgcn_mfma_f32_16x16x32_f16(a, bf[ct], acc[T][ct], 0, 0, 0);
        }
    }
    __syncthreads();   // tile reads done; alias obuf + csb onto tile

    __half* obuf = tile;                              // bytes 0..17407
    float* csb = (float*)((char*)tile + 20480);       // [8][64] floats, bytes 20480..22527
    __half* myo = &obuf[wv * 1088];
    float cs[4] = {0.f, 0.f, 0.f, 0.f};
    const int pxa = lane >> 3;
#pragma unroll
    for (int T = 0; T < 2; T++) {
        const int py_loc = wv * 2 + T;
#pragma unroll
        for (int ct = 0; ct < 4; ct++) {
            const float bv = bpw[ct * 16 + l15];
#pragma unroll
            for (int r = 0; r < 4; r++) {
                const float v = acc[T][ct][r] + bv;
                cs[ct] += v;
                myo[(quad * 4 + r) * 68 + ct * 16 + l15] = __float2half(v);
            }
        }
        const int py = h0 + py_loc;
        const size_t base = (size_t)(py * 256 + w0) * 64;
        half8 v0 = *(const half8*)&myo[pxa * 68 + (lane & 7) * 8];
        half8 v1 = *(const half8*)&myo[(8 + pxa) * 68 + (lane & 7) * 8];
        if (!APPLY || topsm[py_loc * 16 + pxa] == expert)
            *(half8*)&ob[base + lane * 8] = v0;
        if (!APPLY || topsm[py_loc * 16 + 8 + pxa] == expert)
            *(half8*)&ob[base + (lane + 64) * 8] = v1;
    }
#pragma unroll
    for (int ct = 0; ct < 4; ct++) {
        float s = cs[ct];
        s += __shfl_xor(s, 16);
        s += __shfl_xor(s, 32);
        if (quad == 0) csb[wv * 64 + ct * 16 + l15] = s;
    }
    __syncthreads();
    if (t < 64) {
        float s = 0.f;
#pragma unroll
        for (int w = 0; w < 8; w++) s += csb[w * 64 + t];
        atomicAdd(&chansum[b * 64 + t], s);
    }
}

// ---------------------------------------------------------------- bilinear x2 upsample (jax.image.resize semantics)
__device__ __forceinline__ float bilin_up(const float* __restrict__ xb, int h, int w, int r1, int r2) {
    int hlo, hhi; float wrr;
    if (r1 == 0) { hlo = h - 1; hhi = h;     wrr = 0.25f; }
    else         { hlo = h;     hhi = h + 1; wrr = 0.75f; }
    if (hlo < 0)   { hlo = 0;   wrr = 0.f; }
    if (hhi > 255) { hhi = 255; wrr = 1.f; }
    int wlo, whi; float wcc;
    if (r2 == 0) { wlo = w - 1; whi = w;     wcc = 0.25f; }
    else         { wlo = w;     whi = w + 1; wcc = 0.75f; }
    if (wlo < 0)   { wlo = 0;   wcc = 0.f; }
    if (whi > 255) { whi = 255; wcc = 1.f; }
    const float a = xb[hlo * 256 + wlo] * wcc + xb[hlo * 256 + whi] * (1.f - wcc);
    const float b = xb[hhi * 256 + wlo] * wcc + xb[hhi * 256 + whi] * (1.f - wcc);
    return a * wrr + b * (1.f - wrr);
}

// ---------------------------------------------------------------- recon (512 thr) with fused select + in-block y1
__global__ __launch_bounds__(512, 4) void recon_kernel(const __half* __restrict__ Bv,
                                                       const __half* __restrict__ Aap,
                                                       const int* __restrict__ topg,
                                                       const float* __restrict__ chans,
                                                       const float* __restrict__ fc1b,
                                                       const float* __restrict__ fc2b,
                                                       const float* __restrict__ rw,   // [12][64][9]
                                                       const float* __restrict__ rbias,
                                                       const float* __restrict__ x,
                                                       float* __restrict__ sr) {
    __shared__ __half tile[8 * TS * 8];     // 41600 B
    __shared__ __half Wt[9 * 16 * 72];      // 20736 B
    __shared__ float bsm12[12];
    __shared__ float ysm[4][64];
    __shared__ float hid[4][16];
    const int t = threadIdx.x;
    const int b = blockIdx.z;
    const int h0 = blockIdx.y * 16, w0 = blockIdx.x * 16;

    for (int i = t; i < 9216; i += 512) {
        const int tap = i / 1024, rem = i - tap * 1024;
        const int n = rem >> 6, ci = rem & 63;
        Wt[(tap * 16 + n) * 72 + ci] = __float2half(n < 12 ? rw[n * 576 + ci * 9 + tap] : 0.f);
    }
    if (t < 12) bsm12[t] = rbias[t];
    if (t < 64) {   // y1 stage 1 (same fmaf order as y_kernel)
        const int e = t >> 4, j = t & 15, li = e * 2 + 1;
        const float* fc1 = fc1b + li * 1024;
        const float* cs = chans + li * 256 + b * 64;
        float s = 0.f;
        for (int ci = 0; ci < 64; ci++) s = fmaf(fc1[j * 64 + ci], cs[ci], s);
        hid[e][j] = fmaxf(s, 0.f) * (1.f / 65536.f);
    }
    __syncthreads();
    if (t < 256) {  // y1 stage 2
        const int e = t >> 6, c = t & 63, li = e * 2 + 1;
        const float* fc2 = fc2b + li * 1024;
        float s = 0.f;
#pragma unroll
        for (int j = 0; j < 16; j++) s = fmaf(fc2[c * 16 + j], hid[e][j], s);
        ysm[e][c] = 1.f / (1.f + expf(-s));
    }
    __syncthreads();    // ysm + Wt ready

    const __half* bb = Bv + (size_t)b * CHW;
    const __half* ab = Aap + (size_t)b * CHW;
    const int* tb = topg + (size_t)b * HW;

#pragma unroll
    for (int s = 0; s < 6; s++) {
        if (s < 5 || t < 32) {
            const int i = t + (s << 9);
            const int cg = i & 7;
            const int rem = i >> 3;
            const int ry = rem / 18, rx = rem - ry * 18;
            const int hh = h0 + ry - 1, ww = w0 + rx - 1;
            half8 v = {};
            if (hh >= 0 && hh < 256 && ww >= 0 && ww < 256) {
                const size_t off = (size_t)(hh * 256 + ww) * 64 + cg * 8;
                half8 bv8 = *(const half8*)&bb[off];
                half8 av8 = *(const half8*)&ab[off];
                const int e = tb[hh * 256 + ww];
                const float* yp = &ysm[e][cg * 8];
#pragma unroll
                for (int j = 0; j < 8; j++)
                    v[j] = (_Float16)fmaf((float)bv8[j], yp[j], (float)av8[j]);
            }
            *(half8*)&tile[(cg * TS + rem) * 8] = v;
        }
    }
    __syncthreads();

    const int lane = t & 63, wvi = t >> 6;
    const int l15 = lane & 15, quad = lane >> 4;
    f32x4 acc[2];
#pragma unroll
    for (int i = 0; i < 2; i++) acc[i] = (f32x4){0.f, 0.f, 0.f, 0.f};

#pragma unroll
    for (int kh = 0; kh < 2; kh++) {
        const int cgk = kh * 4 + quad;
        half8 bf[9];
#pragma unroll
        for (int tap = 0; tap < 9; tap++)
            bf[tap] = *(const half8*)&Wt[(tap * 16 + l15) * 72 + kh * 32 + quad * 8];
#pragma unroll
        for (int T = 0; T < 2; T++) {
            const int py = wvi * 2 + T;
#pragma unroll
            for (int dy = 0; dy < 3; dy++)
#pragma unroll
                for (int dx = 0; dx < 3; dx++) {
                    half8 a = *(const half8*)&tile[(cgk * TS + (py + dy) * 18 + (l15 + dx)) * 8];
                    acc[T] = __builtin_amdgcn_mfma_f32_16x16x32_f16(a, bf[dy * 3 + dx], acc[T], 0, 0, 0);
                }
        }
    }
    if (l15 < 12) {
        const int c = l15 >> 2, r1 = (l15 >> 1) & 1, r2 = l15 & 1;
        const float* xb = x + ((size_t)b * 3 + c) * HW;
        const float bv = bsm12[l15];
        float* sb = sr + ((size_t)b * 3 + c) * HW2;
#pragma unroll
        for (int T = 0; T < 2; T++) {
            const int py = h0 + wvi * 2 + T;
#pragma unroll
            for (int r = 0; r < 4; r++) {
                const int wglob = w0 + quad * 4 + r;
                const float xu = bilin_up(xb, py, wglob, r1, r2);
                sb[(2 * py + r1) * 512 + 2 * wglob + r2] = acc[T][r] + bv + xu;
            }
        }
    }
}

// ---------------------------------------------------------------- fused refinement: out = sr + conv2(relu(conv1(sr)))
__global__ __launch_bounds__(256) void ref_fused_kernel(const float* __restrict__ in,   // sr [4][3][512][512]
                                                        const float* __restrict__ q1,
                                                        const float* __restrict__ b1,
                                                        const float* __restrict__ q2,
                                                        const float* __restrict__ b2,
                                                        float* __restrict__ outp) {
    __shared__ float srs[1200];       // [3][20][20] halo ±2
    __shared__ float t1s[3 * 324];    // [3][18][18] halo ±1
    __shared__ float w1[81], w2[81];
    __shared__ float bb1[3], bb2[3];
    const int t = threadIdx.y * 16 + threadIdx.x;
    const int b = blockIdx.z;
    const int h0 = blockIdx.y * 16, w0 = blockIdx.x * 16;
    if (t < 81) { w1[t] = q1[t]; w2[t] = q2[t]; }
    if (t < 3)  { bb1[t] = b1[t]; bb2[t] = b2[t]; }
    for (int i = t; i < 1200; i += 256) {
        const int ci = i / 400, rem = i - ci * 400;
        const int ry = rem / 20, rx = rem - ry * 20;
        const int hh = h0 + ry - 2, ww = w0 + rx - 2;
        srs[i] = (hh >= 0 && hh < 512 && ww >= 0 && ww < 512)
                   ? in[((size_t)b * 3 + ci) * HW2 + hh * 512 + ww] : 0.f;
    }
    __syncthreads();
    for (int p = t; p < 324; p += 256) {
        const int ry = p / 18, rx = p - ry * 18;
        const int ih = h0 + ry - 1, iw = w0 + rx - 1;
        const bool valid = (ih >= 0 && ih < 512 && iw >= 0 && iw < 512);
#pragma unroll
        for (int o = 0; o < 3; o++) {
            float a = 0.f;
#pragma unroll
            for (int ci = 0; ci < 3; ci++) {
                const float* wp = &w1[o * 27 + ci * 9];
                const float* sp = &srs[ci * 400 + ry * 20 + rx];
#pragma unroll
                for (int ky = 0; ky < 3; ky++)
#pragma unroll
                    for (int kx = 0; kx < 3; kx++)
                        a = fmaf(sp[ky * 20 + kx], wp[ky * 3 + kx], a);
            }
            t1s[o * 324 + p] = valid ? fmaxf(a + bb1[o], 0.f) : 0.f;
        }
    }
    __syncthreads();
    const int ty = threadIdx.y, tx = threadIdx.x;
#pragma unroll
    for (int o = 0; o < 3; o++) {
        float a = 0.f;
#pragma unroll
        for (int ci = 0; ci < 3; ci++) {
            const float* wp = &w2[o * 27 + ci * 9];
            const float* tp = &t1s[ci * 324 + ty * 18 + tx];
#pragma unroll
            for (int ky = 0; ky < 3; ky++)
#pragma unroll
                for (int kx = 0; kx < 3; kx++)
                    a = fmaf(tp[ky * 18 + kx], wp[ky * 3 + kx], a);
        }
        const float v = a + bb2[o] + srs[o * 400 + (ty + 2) * 20 + tx + 2];
        outp[((size_t)b * 3 + o) * HW2 + (h0 + ty) * 512 + w0 + tx] = v;
    }
}

// ---------------------------------------------------------------- launcher
extern "C" void kernel_launch(void* const* d_in, const int* in_sizes, int n_in,
                              void* d_out, int out_size, void* d_ws, size_t ws_size,
                              hipStream_t stream) {
    const float* x         = (const float*)d_in[0];
    const float* shallow_w = (const float*)d_in[1];
    const float* shallow_b = (const float*)d_in[2];
    const float* tex_dw_w  = (const float*)d_in[3];
    const float* tex_dw_b  = (const float*)d_in[4];
    const float* tex_pw_w  = (const float*)d_in[5];
    const float* tex_pw_b  = (const float*)d_in[6];
    const float* router_w  = (const float*)d_in[7];
    const float* router_b  = (const float*)d_in[8];
    const float* exp_dw_w  = (const float*)d_in[9];
    const float* exp_dw_b  = (const float*)d_in[10];
    const float* exp_pw_w  = (const float*)d_in[11];
    const float* exp_pw_b  = (const float*)d_in[12];
    const float* exp_fc1   = (const float*)d_in[13];
    const float* exp_fc2   = (const float*)d_in[14];
    const float* recon_w   = (const float*)d_in[15];
    const float* recon_b   = (const float*)d_in[16];
    const float* ref1_w    = (const float*)d_in[17];
    const float* ref1_b    = (const float*)d_in[18];
    const float* ref2_w    = (const float*)d_in[19];
    const float* ref2_b    = (const float*)d_in[20];

    // mode: merged (all 4 experts per dispatch, 4 A-slots) if workspace allows
    const size_t need_merged = 237000000ULL;   // ~226 MiB
    const bool merged = (ws_size >= need_merged);
    const int nslot = merged ? 4 : 2;

    __half* feat_h = (__half*)d_ws;                      // 32 MB
    __half* A4     = feat_h + BCHW;                      // nslot x 32 MB
    __half* Bv_sh  = A4 + (size_t)nslot * BCHW;          // 32 MB, routed-shared
    __half* Aap_sh = Bv_sh + BCHW;                       // 32 MB, routed-shared
    int*    top    = (int*)(Aap_sh + BCHW);              // 1 MB
    float*  qb     = (float*)(top + 262144);
    float*  q_sh   = qb;                 // 1728
    float*  q_tdw  = q_sh + 1728;        // 576
    float*  q_tpw  = q_tdw + 576;        // 512
    float*  q_edw  = q_tpw + 512;        // 8*576
    float*  q_epw  = q_edw + 4608;       // 8*4096
    float*  q_r1   = q_epw + 32768;      // 81
    float*  q_r2   = q_r1 + 81;          // 81
    float*  chans  = q_r2 + 81;          // 8*256
    float*  yv     = chans + 2048;       // 8*256
    float*  sr     = (float*)A4;         // 12 MB (A4 dead after last APPLY)

    TernArgs ta;
    ta.d[0] = { shallow_w, q_sh, 1728 };
    ta.d[1] = { tex_dw_w, q_tdw, 576 };
    ta.d[2] = { tex_pw_w, q_tpw, 512 };
    for (int i = 0; i < 8; i++) ta.d[3 + i]  = { exp_dw_w + i * 576,  q_edw + i * 576,  576 };
    for (int i = 0; i < 8; i++) ta.d[11 + i] = { exp_pw_w + i * 4096, q_epw + i * 4096, 4096 };
    ta.d[19] = { ref1_w, q_r1, 81 };
    ta.d[20] = { ref2_w, q_r2, 81 };
    ternarize_kernel<<<22, 256, 0, stream>>>(ta, chans);   // block 21 zeroes chans

    shallow_router_kernel<<<dim3(16, 16, 4), 512, 0, stream>>>(
        x, q_sh, shallow_b, q_tdw, tex_dw_b, q_tpw, tex_pw_b, router_w, router_b,
        feat_h, top);

    if (merged) {
        expert_block_kernel<false><<<dim3(16, 16, 16), 512, 0, stream>>>(
            feat_h, q_edw, exp_dw_b, q_epw, exp_pw_b,
            A4, chans, nullptr, nullptr, nullptr, nullptr, 0);
        YArgs ya; ya.layers[0] = 0; ya.layers[1] = 2; ya.layers[2] = 4; ya.layers[3] = 6;
        ya.nL = 4;
        y_kernel<<<1, 256, 0, stream>>>(chans, exp_fc1, exp_fc2, yv, ya);
        expert_block_kernel<true><<<dim3(16, 16, 16), 512, 0, stream>>>(
            A4, q_edw, exp_dw_b, q_epw, exp_pw_b,
            Bv_sh, chans, yv, feat_h, Aap_sh, top, 0);
    } else {
        for (int s = 0; s < 2; s++) {
            expert_block_kernel<false><<<dim3(16, 16, 8), 512, 0, stream>>>(
                feat_h, q_edw, exp_dw_b, q_epw, exp_pw_b,
                A4, chans, nullptr, nullptr, nullptr, nullptr, s * 2);
            YArgs ya; ya.layers[0] = s * 4; ya.layers[1] = s * 4 + 2;
            ya.layers[2] = 0; ya.layers[3] = 0; ya.nL = 2;
            y_kernel<<<1, 256, 0, stream>>>(chans, exp_fc1, exp_fc2, yv, ya);
            expert_block_kernel<true><<<dim3(16, 16, 8), 512, 0, stream>>>(
                A4, q_edw, exp_dw_b, q_epw, exp_pw_b,
                Bv_sh, chans, yv, feat_h, Aap_sh, top, s * 2);
        }
    }

    recon_kernel<<<dim3(16, 16, 4), 512, 0, stream>>>(Bv_sh, Aap_sh, top,
                                                      chans, exp_fc1, exp_fc2,
                                                      recon_w, recon_b, x, sr);
    ref_fused_kernel<<<dim3(32, 32, 4), dim3(16, 16), 0, stream>>>(
        sr, q_r1, ref1_b, q_r2, ref2_b, (float*)d_out);
}

// Round 11
// 414.492 us; speedup vs baseline: 8.3225x; 1.0322x over previous
//
#include <hip/hip_runtime.h>
#include <hip/hip_fp16.h>
#include <math.h>

#define HW 65536            // 256*256
#define CHW 4194304         // 64*HW  (NHWC elements per batch)
#define BCHW 16777216
#define HW2 262144          // 512*512
#define TS 325              // tile pad stride (px) to break LDS conflicts

typedef _Float16 half8 __attribute__((ext_vector_type(8)));
typedef float f32x4 __attribute__((ext_vector_type(4)));

// XCD-aware tile swizzle: ids congruent mod 8 (same XCD under round-robin
// dispatch) map to a contiguous 2-tile-row band. Bijection on 16x16.
__device__ __forceinline__ void swz16(int ibx, int iby, int& ox, int& oy) {
    const int f = ibx + (iby << 4);
    const int k = f & 7, g = f >> 3;
    const int T = (k << 5) + g;
    ox = T & 15; oy = T >> 4;
}

// ---------------------------------------------------------------- ternarize (+ chans zeroing in block 21)
struct TernDesc { const float* src; float* dst; int n; };
struct TernArgs { TernDesc d[21]; };

__global__ __launch_bounds__(256) void ternarize_kernel(TernArgs args, float* __restrict__ chans) {
    const int t = threadIdx.x;
    if (blockIdx.x == 21) {
        for (int i = t; i < 2048; i += 256) chans[i] = 0.f;
        return;
    }
    __shared__ float red[256];
    __shared__ float bc[2];
    TernDesc td = args.d[blockIdx.x];
    const int n = td.n;
    float s = 0.f;
    for (int i = t; i < n; i += 256) s += fabsf(td.src[i]);
    red[t] = s; __syncthreads();
    for (int k = 128; k > 0; k >>= 1) { if (t < k) red[t] += red[t + k]; __syncthreads(); }
    if (t == 0) bc[0] = 0.75f * red[0] / (float)n;
    __syncthreads();
    const float delta = bc[0];
    float s1 = 0.f, c1 = 0.f;
    for (int i = t; i < n; i += 256) {
        float a = fabsf(td.src[i]);
        if (a > delta) { s1 += a; c1 += 1.f; }
    }
    __syncthreads();
    red[t] = s1; __syncthreads();
    for (int k = 128; k > 0; k >>= 1) { if (t < k) red[t] += red[t + k]; __syncthreads(); }
    float sum1 = red[0];
    __syncthreads();
    red[t] = c1; __syncthreads();
    for (int k = 128; k > 0; k >>= 1) { if (t < k) red[t] += red[t + k]; __syncthreads(); }
    if (t == 0) bc[1] = sum1 / fmaxf(red[0], 1.f);
    __syncthreads();
    const float alpha = bc[1];
    for (int i = t; i < n; i += 256) {
        float w = td.src[i];
        td.dst[i] = (fabsf(w) > delta) ? ((w > 0.f) ? alpha : -alpha) : 0.f;
    }
}

// ---------------------------------------------------------------- fused shallow conv + texture encoder + router (512 thr)
__global__ __launch_bounds__(512, 6) void shallow_router_kernel(
    const float* __restrict__ x,
    const float* __restrict__ qsh,  const float* __restrict__ shb,
    const float* __restrict__ qtdw, const float* __restrict__ tdwb,
    const float* __restrict__ qtpw, const float* __restrict__ tpwb,
    const float* __restrict__ rw,   const float* __restrict__ rbias,
    __half* __restrict__ feat_h, int* __restrict__ top) {
    __shared__ float xs[1200];          // [3][20][20]
    __shared__ float feats[324 * 33];   // [halo px][ch pad33]
    const int t = threadIdx.x;
    const int b = blockIdx.z;
    const int h0 = blockIdx.y * 16, w0 = blockIdx.x * 16;
    const float* xb = x + (size_t)b * 3 * HW;

    for (int i = t; i < 1200; i += 512) {
        const int ci = i / 400, rem = i - ci * 400;
        const int ry = rem / 20, rx = rem - ry * 20;
        const int hh = h0 + ry - 2, ww = w0 + rx - 2;
        xs[i] = (hh >= 0 && hh < 256 && ww >= 0 && ww < 256) ? xb[ci * HW + hh * 256 + ww] : 0.f;
    }
    float tex[8] = {0, 0, 0, 0, 0, 0, 0, 0};
    __half* fhb = feat_h + (size_t)b * CHW;
    __syncthreads();

    for (int pass = 0; pass < 2; pass++) {
        const int c0 = pass * 32;
        if (pass) __syncthreads();
        if (t < 324) {
            const int ry = t / 18, rx = t - ry * 18;
            float patch[27];
#pragma unroll
            for (int ci = 0; ci < 3; ci++)
#pragma unroll
                for (int dy = 0; dy < 3; dy++)
#pragma unroll
                    for (int dx = 0; dx < 3; dx++)
                        patch[ci * 9 + dy * 3 + dx] = xs[ci * 400 + (ry + dy) * 20 + rx + dx];
            for (int co = 0; co < 32; co++) {
                const float* wp = &qsh[(c0 + co) * 27];
                float a = shb[c0 + co];
#pragma unroll
                for (int k = 0; k < 27; k++) a = fmaf(patch[k], wp[k], a);
                feats[t * 33 + co] = fmaxf(a, 0.f);
            }
        }
        __syncthreads();
        if (t < 256) {
            const int iy = t >> 4, ix = t & 15;
            for (int ch = 0; ch < 32; ch++) {
                const float* wp = &qtdw[(c0 + ch) * 9];
                float o = tdwb[c0 + ch];
#pragma unroll
                for (int dy = 0; dy < 3; dy++) {
                    const float* rowp = &feats[((iy + dy) * 18 + ix) * 33 + ch];
                    o = fmaf(rowp[0], wp[dy * 3],
                        fmaf(rowp[33], wp[dy * 3 + 1],
                            fmaf(rowp[66], wp[dy * 3 + 2], o)));
                }
                const float tc = fmaxf(o, 0.f);
#pragma unroll
                for (int j = 0; j < 8; j++) tex[j] = fmaf(qtpw[j * 64 + c0 + ch], tc, tex[j]);
            }
        } else {
            for (int id = t - 256; id < 1024; id += 256) {
                const int p = id >> 2, cg = id & 3;
                const int py = p >> 4, px = p & 15;
                const float* fp = &feats[((py + 1) * 18 + px + 1) * 33 + cg * 8];
                half8 pk;
#pragma unroll
                for (int j = 0; j < 8; j++) pk[j] = (_Float16)fp[j];
                *(half8*)&fhb[((size_t)((h0 + py) * 256 + w0 + px)) * 64 + c0 + cg * 8] = pk;
            }
        }
    }
    if (t < 256) {
        const int iy = t >> 4, ix = t & 15;
        float sgm[8];
#pragma unroll
        for (int j = 0; j < 8; j++) sgm[j] = 1.f / (1.f + expf(-(tex[j] + tpwb[j])));
        float best = -1e30f; int bi = 0;
#pragma unroll
        for (int e = 0; e < 4; e++) {
            float v = rbias[e];
#pragma unroll
            for (int j = 0; j < 8; j++) v = fmaf(rw[e * 8 + j], sgm[j], v);
            if (v > best) { best = v; bi = e; }     // first max (jnp.argmax)
        }
        top[(size_t)b * HW + (h0 + iy) * 256 + w0 + ix] = bi;
    }
}

// ---------------------------------------------------------------- expert block: 512 threads, ebase-parameterized
// grid z = 4 * nexp; b = z&3, slot/sub = z>>2, expert = ebase + sub.
// APPLY computes its own y0 from chans (identical fmaf order to the old
// y_kernel), masks routed writes via topsm only.
template <bool APPLY>
__global__ __launch_bounds__(512, 4) void expert_block_kernel(
    const __half* __restrict__ in,
    const float* __restrict__ qdw_b, const float* __restrict__ dwb_b,
    const float* __restrict__ qpw_b, const float* __restrict__ pwb_b,
    __half* __restrict__ out_b, float* __restrict__ chans_b,
    const float* __restrict__ fc1b, const float* __restrict__ fc2b,
    const __half* __restrict__ F, __half* __restrict__ Aap,
    const int* __restrict__ topg, int ebase) {
    __shared__ __half tile[8 * TS * 8];    // 41600 B; obuf + csb alias after compute
    __shared__ __half wT[64 * 72];         // [co][ci pad72] 9216 B
    __shared__ __half wdwh[9 * 64];        // [tap][ci] 1152 B
    __shared__ float bdw[64];
    __shared__ float bpw[64];
    __shared__ unsigned char topsm[256];
    __shared__ float hid0[16];
    __shared__ float ysm0[64];
    const int t = threadIdx.x;
    const int z = blockIdx.z;
    const int b = z & 3, sub = z >> 2;
    const int expert = ebase + sub;
    const int layer = expert * 2 + (APPLY ? 1 : 0);
    const float* qdw = qdw_b + layer * 576;
    const float* dwb = dwb_b + layer * 64;
    const float* qpw = qpw_b + layer * 4096;
    const float* pwb = pwb_b + layer * 64;
    float* chansum = chans_b + layer * 256;
    int bx, by; swz16(blockIdx.x, blockIdx.y, bx, by);
    const int h0 = by * 16, w0 = bx * 16;

    for (int i = t; i < 4096; i += 512) wT[(i >> 6) * 72 + (i & 63)] = __float2half(qpw[i]);
    for (int i = t; i < 576; i += 512) {
        const int ci = i / 9, tap = i - ci * 9;
        wdwh[tap * 64 + ci] = __float2half(qdw[i]);
    }
    if (t < 64) { bdw[t] = dwb[t]; bpw[t] = pwb[t]; }

    float y8[8];
    if (APPLY) {
        if (t < 256)
            topsm[t] = (unsigned char)topg[(size_t)b * HW + (h0 + (t >> 4)) * 256 + w0 + (t & 15)];
        if (t < 16) {   // y0 stage 1 (same fmaf order as old y_kernel)
            const float* fc1 = fc1b + (expert * 2) * 1024;
            const float* cs = chans_b + (expert * 2) * 256 + b * 64;
            float s = 0.f;
            for (int ci = 0; ci < 64; ci++) s = fmaf(fc1[t * 64 + ci], cs[ci], s);
            hid0[t] = fmaxf(s, 0.f) * (1.f / 65536.f);
        }
        __syncthreads();
        if (t < 64) {   // y0 stage 2
            const float* fc2 = fc2b + (expert * 2) * 1024;
            float s = 0.f;
#pragma unroll
            for (int j = 0; j < 16; j++) s = fmaf(fc2[t * 16 + j], hid0[j], s);
            ysm0[t] = 1.f / (1.f + expf(-s));
        }
        __syncthreads();
        const int scg = t & 7;
#pragma unroll
        for (int j = 0; j < 8; j++) y8[j] = ysm0[scg * 8 + j];
    }

    const __half* ib = (APPLY ? in + (size_t)sub * BCHW : in) + (size_t)b * CHW;
    const __half* Fb = APPLY ? (F + (size_t)b * CHW) : nullptr;
    __half* Ab = APPLY ? (Aap + (size_t)b * CHW) : nullptr;
    __half* ob = APPLY ? (out_b + (size_t)b * CHW)
                       : (out_b + (size_t)sub * BCHW + (size_t)b * CHW);

    // staging, force-unrolled: 5 full iterations + 32-thread tail
#pragma unroll
    for (int s = 0; s < 6; s++) {
        if (s < 5 || t < 32) {
            const int i = t + (s << 9);
            const int cg = i & 7;
            const int rem = i >> 3;            // 0..323
            const int ry = rem / 18, rx = rem - ry * 18;
            const int hh = h0 + ry - 1, ww = w0 + rx - 1;
            half8 v = {};
            if (hh >= 0 && hh < 256 && ww >= 0 && ww < 256) {
                const size_t off = (size_t)(hh * 256 + ww) * 64 + cg * 8;
                v = *(const half8*)&ib[off];
                if (APPLY) {
                    half8 f = *(const half8*)&Fb[off];
#pragma unroll
                    for (int j = 0; j < 8; j++)
                        v[j] = (_Float16)fmaf((float)v[j], y8[j], (float)f[j]);
                    if (ry >= 1 && ry <= 16 && rx >= 1 && rx <= 16 &&
                        topsm[((ry - 1) << 4) + (rx - 1)] == expert)
                        *(half8*)&Ab[off] = v;
                }
            }
            *(half8*)&tile[(cg * TS + rem) * 8] = v;
        }
    }
    __syncthreads();

    const int lane = t & 63, wv = t >> 6;      // 8 waves, 2 rows each
    const int l15 = lane & 15, quad = lane >> 4;
    f32x4 acc[2][4];
#pragma unroll
    for (int i = 0; i < 2; i++)
#pragma unroll
        for (int j = 0; j < 4; j++) acc[i][j] = (f32x4){0.f, 0.f, 0.f, 0.f};

#pragma unroll
    for (int kh = 0; kh < 2; kh++) {
        const int cgk = kh * 4 + quad;
        half8 bf[4];
#pragma unroll
        for (int ct = 0; ct < 4; ct++)
            bf[ct] = *(const half8*)&wT[(ct * 16 + l15) * 72 + kh * 32 + quad * 8];
        half8 wv9[9];
#pragma unroll
        for (int tap = 0; tap < 9; tap++)
            wv9[tap] = *(const half8*)&wdwh[tap * 64 + kh * 32 + quad * 8];
        float bias8[8];
#pragma unroll
        for (int j = 0; j < 8; j++) bias8[j] = bdw[kh * 32 + quad * 8 + j];
        // row-shared tap loads: rows wv*2..wv*2+3 (T=0 uses 0..2, T=1 uses 1..3)
        half8 xr[9];
#pragma unroll
        for (int dy = 0; dy < 3; dy++)
#pragma unroll
            for (int dx = 0; dx < 3; dx++)
                xr[dy * 3 + dx] = *(const half8*)&tile[(cgk * TS + (wv * 2 + dy) * 18 + (l15 + dx)) * 8];
#pragma unroll
        for (int T = 0; T < 2; T++) {
            if (T) {
#pragma unroll
                for (int q2 = 0; q2 < 6; q2++) xr[q2] = xr[q2 + 3];
#pragma unroll
                for (int dx = 0; dx < 3; dx++)
                    xr[6 + dx] = *(const half8*)&tile[(cgk * TS + (wv * 2 + 3) * 18 + (l15 + dx)) * 8];
            }
            float o[8];
#pragma unroll
            for (int j = 0; j < 8; j++) o[j] = bias8[j];
#pragma unroll
            for (int tap = 0; tap < 9; tap++)
#pragma unroll
                for (int j = 0; j < 8; j++)
                    o[j] = fmaf((float)xr[tap][j], (float)wv9[tap][j], o[j]);
            half8 a;
#pragma unroll
            for (int j = 0; j < 8; j++) a[j] = (_Float16)fmaxf(o[j], 0.f);
#pragma unroll
            for (int ct = 0; ct < 4; ct++)
                acc[T][ct] = __builtin_amdgcn_mfma_f32_16x16x32_f16(a, bf[ct], acc[T][ct], 0, 0, 0);
        }
    }
    __syncthreads();   // tile reads done; alias obuf + csb onto tile

    __half* obuf = tile;                              // bytes 0..17407
    float* csb = (float*)((char*)tile + 20480);       // [8][64] floats
    __half* myo = &obuf[wv * 1088];
    float cs[4] = {0.f, 0.f, 0.f, 0.f};
    const int pxa = lane >> 3;
#pragma unroll
    for (int T = 0; T < 2; T++) {
        const int py_loc = wv * 2 + T;
#pragma unroll
        for (int ct = 0; ct < 4; ct++) {
            const float bv = bpw[ct * 16 + l15];
#pragma unroll
            for (int r = 0; r < 4; r++) {
                const float v = acc[T][ct][r] + bv;
                cs[ct] += v;
                myo[(quad * 4 + r) * 68 + ct * 16 + l15] = __float2half(v);
            }
        }
        const int py = h0 + py_loc;
        const size_t base = (size_t)(py * 256 + w0) * 64;
        half8 v0 = *(const half8*)&myo[pxa * 68 + (lane & 7) * 8];
        half8 v1 = *(const half8*)&myo[(8 + pxa) * 68 + (lane & 7) * 8];
        if (!APPLY || topsm[py_loc * 16 + pxa] == expert)
            *(half8*)&ob[base + lane * 8] = v0;
        if (!APPLY || topsm[py_loc * 16 + 8 + pxa] == expert)
            *(half8*)&ob[base + (lane + 64) * 8] = v1;
    }
#pragma unroll
    for (int ct = 0; ct < 4; ct++) {
        float s = cs[ct];
        s += __shfl_xor(s, 16);
        s += __shfl_xor(s, 32);
        if (quad == 0) csb[wv * 64 + ct * 16 + l15] = s;
    }
    __syncthreads();
    if (t < 64) {
        float s = 0.f;
#pragma unroll
        for (int w = 0; w < 8; w++) s += csb[w * 64 + t];
        atomicAdd(&chansum[b * 64 + t], s);
    }
}

// ---------------------------------------------------------------- bilinear x2 upsample (jax.image.resize semantics)
__device__ __forceinline__ float bilin_up(const float* __restrict__ xb, int h, int w, int r1, int r2) {
    int hlo, hhi; float wrr;
    if (r1 == 0) { hlo = h - 1; hhi = h;     wrr = 0.25f; }
    else         { hlo = h;     hhi = h + 1; wrr = 0.75f; }
    if (hlo < 0)   { hlo = 0;   wrr = 0.f; }
    if (hhi > 255) { hhi = 255; wrr = 1.f; }
    int wlo, whi; float wcc;
    if (r2 == 0) { wlo = w - 1; whi = w;     wcc = 0.25f; }
    else         { wlo = w;     whi = w + 1; wcc = 0.75f; }
    if (wlo < 0)   { wlo = 0;   wcc = 0.f; }
    if (whi > 255) { whi = 255; wcc = 1.f; }
    const float a = xb[hlo * 256 + wlo] * wcc + xb[hlo * 256 + whi] * (1.f - wcc);
    const float b = xb[hhi * 256 + wlo] * wcc + xb[hhi * 256 + whi] * (1.f - wcc);
    return a * wrr + b * (1.f - wrr);
}

// ---------------------------------------------------------------- recon (512 thr) fused select + in-block y1; fp16 sr out
__global__ __launch_bounds__(512, 4) void recon_kernel(const __half* __restrict__ Bv,
                                                       const __half* __restrict__ Aap,
                                                       const int* __restrict__ topg,
                                                       const float* __restrict__ chans,
                                                       const float* __restrict__ fc1b,
                                                       const float* __restrict__ fc2b,
                                                       const float* __restrict__ rw,   // [12][64][9]
                                                       const float* __restrict__ rbias,
                                                       const float* __restrict__ x,
                                                       __half* __restrict__ srh) {
    __shared__ __half tile[8 * TS * 8];     // 41600 B
    __shared__ __half Wt[9 * 16 * 72];      // 20736 B
    __shared__ float bsm12[12];
    __shared__ float ysm[4][64];
    __shared__ float hid[4][16];
    const int t = threadIdx.x;
    const int b = blockIdx.z;
    int bx, by; swz16(blockIdx.x, blockIdx.y, bx, by);
    const int h0 = by * 16, w0 = bx * 16;

    for (int i = t; i < 9216; i += 512) {
        const int tap = i / 1024, rem = i - tap * 1024;
        const int n = rem >> 6, ci = rem & 63;
        Wt[(tap * 16 + n) * 72 + ci] = __float2half(n < 12 ? rw[n * 576 + ci * 9 + tap] : 0.f);
    }
    if (t < 12) bsm12[t] = rbias[t];
    if (t < 64) {   // y1 stage 1 (same fmaf order as old y_kernel)
        const int e = t >> 4, j = t & 15, li = e * 2 + 1;
        const float* fc1 = fc1b + li * 1024;
        const float* cs = chans + li * 256 + b * 64;
        float s = 0.f;
        for (int ci = 0; ci < 64; ci++) s = fmaf(fc1[j * 64 + ci], cs[ci], s);
        hid[e][j] = fmaxf(s, 0.f) * (1.f / 65536.f);
    }
    __syncthreads();
    if (t < 256) {  // y1 stage 2
        const int e = t >> 6, c = t & 63, li = e * 2 + 1;
        const float* fc2 = fc2b + li * 1024;
        float s = 0.f;
#pragma unroll
        for (int j = 0; j < 16; j++) s = fmaf(fc2[c * 16 + j], hid[e][j], s);
        ysm[e][c] = 1.f / (1.f + expf(-s));
    }
    __syncthreads();    // ysm + Wt ready

    const __half* bb = Bv + (size_t)b * CHW;
    const __half* ab = Aap + (size_t)b * CHW;
    const int* tb = topg + (size_t)b * HW;

#pragma unroll
    for (int s = 0; s < 6; s++) {
        if (s < 5 || t < 32) {
            const int i = t + (s << 9);
            const int cg = i & 7;
            const int rem = i >> 3;
            const int ry = rem / 18, rx = rem - ry * 18;
            const int hh = h0 + ry - 1, ww = w0 + rx - 1;
            half8 v = {};
            if (hh >= 0 && hh < 256 && ww >= 0 && ww < 256) {
                const size_t off = (size_t)(hh * 256 + ww) * 64 + cg * 8;
                half8 bv8 = *(const half8*)&bb[off];
                half8 av8 = *(const half8*)&ab[off];
                const int e = tb[hh * 256 + ww];
                const float* yp = &ysm[e][cg * 8];
#pragma unroll
                for (int j = 0; j < 8; j++)
                    v[j] = (_Float16)fmaf((float)bv8[j], yp[j], (float)av8[j]);
            }
            *(half8*)&tile[(cg * TS + rem) * 8] = v;
        }
    }
    __syncthreads();

    const int lane = t & 63, wvi = t >> 6;
    const int l15 = lane & 15, quad = lane >> 4;
    f32x4 acc[2];
#pragma unroll
    for (int i = 0; i < 2; i++) acc[i] = (f32x4){0.f, 0.f, 0.f, 0.f};

#pragma unroll
    for (int kh = 0; kh < 2; kh++) {
        const int cgk = kh * 4 + quad;
        half8 bf[9];
#pragma unroll
        for (int tap = 0; tap < 9; tap++)
            bf[tap] = *(const half8*)&Wt[(tap * 16 + l15) * 72 + kh * 32 + quad * 8];
        // row-shared tap loads
        half8 xr[9];
#pragma unroll
        for (int dy = 0; dy < 3; dy++)
#pragma unroll
            for (int dx = 0; dx < 3; dx++)
                xr[dy * 3 + dx] = *(const half8*)&tile[(cgk * TS + (wvi * 2 + dy) * 18 + (l15 + dx)) * 8];
#pragma unroll
        for (int T = 0; T < 2; T++) {
            if (T) {
#pragma unroll
                for (int q2 = 0; q2 < 6; q2++) xr[q2] = xr[q2 + 3];
#pragma unroll
                for (int dx = 0; dx < 3; dx++)
                    xr[6 + dx] = *(const half8*)&tile[(cgk * TS + (wvi * 2 + 3) * 18 + (l15 + dx)) * 8];
            }
#pragma unroll
            for (int tap = 0; tap < 9; tap++)
                acc[T] = __builtin_amdgcn_mfma_f32_16x16x32_f16(xr[tap], bf[tap], acc[T], 0, 0, 0);
        }
    }
    if (l15 < 12) {
        const int c = l15 >> 2, r1 = (l15 >> 1) & 1, r2 = l15 & 1;
        const float* xb = x + ((size_t)b * 3 + c) * HW;
        const float bv = bsm12[l15];
        __half* sb = srh + ((size_t)b * 3 + c) * HW2;
#pragma unroll
        for (int T = 0; T < 2; T++) {
            const int py = h0 + wvi * 2 + T;
#pragma unroll
            for (int r = 0; r < 4; r++) {
                const int wglob = w0 + quad * 4 + r;
                const float xu = bilin_up(xb, py, wglob, r1, r2);
                sb[(2 * py + r1) * 512 + 2 * wglob + r2] = __float2half(acc[T][r] + bv + xu);
            }
        }
    }
}

// ---------------------------------------------------------------- fused refinement: out = sr + conv2(relu(conv1(sr))); fp16 sr in
__global__ __launch_bounds__(256) void ref_fused_kernel(const __half* __restrict__ in,  // sr half [4][3][512][512]
                                                        const float* __restrict__ q1,
                                                        const float* __restrict__ b1,
                                                        const float* __restrict__ q2,
                                                        const float* __restrict__ b2,
                                                        float* __restrict__ outp) {
    __shared__ float srs[1200];       // [3][20][20] halo ±2
    __shared__ float t1s[3 * 324];    // [3][18][18] halo ±1
    __shared__ float w1[81], w2[81];
    __shared__ float bb1[3], bb2[3];
    const int t = threadIdx.y * 16 + threadIdx.x;
    const int b = blockIdx.z;
    const int h0 = blockIdx.y * 16, w0 = blockIdx.x * 16;
    if (t < 81) { w1[t] = q1[t]; w2[t] = q2[t]; }
    if (t < 3)  { bb1[t] = b1[t]; bb2[t] = b2[t]; }
    for (int i = t; i < 1200; i += 256) {
        const int ci = i / 400, rem = i - ci * 400;
        const int ry = rem / 20, rx = rem - ry * 20;
        const int hh = h0 + ry - 2, ww = w0 + rx - 2;
        srs[i] = (hh >= 0 && hh < 512 && ww >= 0 && ww < 512)
                   ? __half2float(in[((size_t)b * 3 + ci) * HW2 + hh * 512 + ww]) : 0.f;
    }
    __syncthreads();
    for (int p = t; p < 324; p += 256) {
        const int ry = p / 18, rx = p - ry * 18;
        const int ih = h0 + ry - 1, iw = w0 + rx - 1;
        const bool valid = (ih >= 0 && ih < 512 && iw >= 0 && iw < 512);
#pragma unroll
        for (int o = 0; o < 3; o++) {
            float a = 0.f;
#pragma unroll
            for (int ci = 0; ci < 3; ci++) {
                const float* wp = &w1[o * 27 + ci * 9];
                const float* sp = &srs[ci * 400 + ry * 20 + rx];
#pragma unroll
                for (int ky = 0; ky < 3; ky++)
#pragma unroll
                    for (int kx = 0; kx < 3; kx++)
                        a = fmaf(sp[ky * 20 + kx], wp[ky * 3 + kx], a);
            }
            t1s[o * 324 + p] = valid ? fmaxf(a + bb1[o], 0.f) : 0.f;
        }
    }
    __syncthreads();
    const int ty = threadIdx.y, tx = threadIdx.x;
#pragma unroll
    for (int o = 0; o < 3; o++) {
        float a = 0.f;
#pragma unroll
        for (int ci = 0; ci < 3; ci++) {
            const float* wp = &w2[o * 27 + ci * 9];
            const float* tp = &t1s[ci * 324 + ty * 18 + tx];
#pragma unroll
            for (int ky = 0; ky < 3; ky++)
#pragma unroll
                for (int kx = 0; kx < 3; kx++)
                    a = fmaf(tp[ky * 18 + kx], wp[ky * 3 + kx], a);
        }
        const float v = a + bb2[o] + srs[o * 400 + (ty + 2) * 20 + tx + 2];
        outp[((size_t)b * 3 + o) * HW2 + (h0 + ty) * 512 + w0 + tx] = v;
    }
}

// ---------------------------------------------------------------- launcher
extern "C" void kernel_launch(void* const* d_in, const int* in_sizes, int n_in,
                              void* d_out, int out_size, void* d_ws, size_t ws_size,
                              hipStream_t stream) {
    const float* x         = (const float*)d_in[0];
    const float* shallow_w = (const float*)d_in[1];
    const float* shallow_b = (const float*)d_in[2];
    const float* tex_dw_w  = (const float*)d_in[3];
    const float* tex_dw_b  = (const float*)d_in[4];
    const float* tex_pw_w  = (const float*)d_in[5];
    const float* tex_pw_b  = (const float*)d_in[6];
    const float* router_w  = (const float*)d_in[7];
    const float* router_b  = (const float*)d_in[8];
    const float* exp_dw_w  = (const float*)d_in[9];
    const float* exp_dw_b  = (const float*)d_in[10];
    const float* exp_pw_w  = (const float*)d_in[11];
    const float* exp_pw_b  = (const float*)d_in[12];
    const float* exp_fc1   = (const float*)d_in[13];
    const float* exp_fc2   = (const float*)d_in[14];
    const float* recon_w   = (const float*)d_in[15];
    const float* recon_b   = (const float*)d_in[16];
    const float* ref1_w    = (const float*)d_in[17];
    const float* ref1_b    = (const float*)d_in[18];
    const float* ref2_w    = (const float*)d_in[19];
    const float* ref2_b    = (const float*)d_in[20];

    // mode: merged (all 4 experts per dispatch, 4 A-slots) if workspace allows
    const size_t need_merged = 237000000ULL;
    const bool merged = (ws_size >= need_merged);
    const int nslot = merged ? 4 : 2;

    __half* feat_h = (__half*)d_ws;                      // 32 MB
    __half* A4     = feat_h + BCHW;                      // nslot x 32 MB
    __half* Bv_sh  = A4 + (size_t)nslot * BCHW;          // 32 MB, routed-shared
    __half* Aap_sh = Bv_sh + BCHW;                       // 32 MB, routed-shared
    int*    top    = (int*)(Aap_sh + BCHW);              // 1 MB
    float*  qb     = (float*)(top + 262144);
    float*  q_sh   = qb;                 // 1728
    float*  q_tdw  = q_sh + 1728;        // 576
    float*  q_tpw  = q_tdw + 576;        // 512
    float*  q_edw  = q_tpw + 512;        // 8*576
    float*  q_epw  = q_edw + 4608;       // 8*4096
    float*  q_r1   = q_epw + 32768;      // 81
    float*  q_r2   = q_r1 + 81;          // 81
    float*  chans  = q_r2 + 81;          // 8*256
    __half* srh    = (__half*)A4;        // 25 MB as half (A4 dead after last APPLY)

    TernArgs ta;
    ta.d[0] = { shallow_w, q_sh, 1728 };
    ta.d[1] = { tex_dw_w, q_tdw, 576 };
    ta.d[2] = { tex_pw_w, q_tpw, 512 };
    for (int i = 0; i < 8; i++) ta.d[3 + i]  = { exp_dw_w + i * 576,  q_edw + i * 576,  576 };
    for (int i = 0; i < 8; i++) ta.d[11 + i] = { exp_pw_w + i * 4096, q_epw + i * 4096, 4096 };
    ta.d[19] = { ref1_w, q_r1, 81 };
    ta.d[20] = { ref2_w, q_r2, 81 };
    ternarize_kernel<<<22, 256, 0, stream>>>(ta, chans);   // block 21 zeroes chans

    shallow_router_kernel<<<dim3(16, 16, 4), 512, 0, stream>>>(
        x, q_sh, shallow_b, q_tdw, tex_dw_b, q_tpw, tex_pw_b, router_w, router_b,
        feat_h, top);

    if (merged) {
        expert_block_kernel<false><<<dim3(16, 16, 16), 512, 0, stream>>>(
            feat_h, q_edw, exp_dw_b, q_epw, exp_pw_b,
            A4, chans, nullptr, nullptr, nullptr, nullptr, nullptr, 0);
        expert_block_kernel<true><<<dim3(16, 16, 16), 512, 0, stream>>>(
            A4, q_edw, exp_dw_b, q_epw, exp_pw_b,
            Bv_sh, chans, exp_fc1, exp_fc2, feat_h, Aap_sh, top, 0);
    } else {
        for (int s = 0; s < 2; s++) {
            expert_block_kernel<false><<<dim3(16, 16, 8), 512, 0, stream>>>(
                feat_h, q_edw, exp_dw_b, q_epw, exp_pw_b,
                A4, chans, nullptr, nullptr, nullptr, nullptr, nullptr, s * 2);
            expert_block_kernel<true><<<dim3(16, 16, 8), 512, 0, stream>>>(
                A4, q_edw, exp_dw_b, q_epw, exp_pw_b,
                Bv_sh, chans, exp_fc1, exp_fc2, feat_h, Aap_sh, top, s * 2);
        }
    }

    recon_kernel<<<dim3(16, 16, 4), 512, 0, stream>>>(Bv_sh, Aap_sh, top,
                                                      chans, exp_fc1, exp_fc2,
                                                      recon_w, recon_b, x, srh);
    ref_fused_kernel<<<dim3(32, 32, 4), dim3(16, 16), 0, stream>>>(
        srh, q_r1, ref1_b, q_r2, ref2_b, (float*)d_out);
}